// Round 4
// baseline (402.398 us; speedup 1.0000x reference)
//
#include <hip/hip_runtime.h>
#include <cstdint>
#include <cstddef>

#define HEADS   8
#define NFEAT   256
#define NOUT    128
#define NEG     0.2f
#define EPSV    1e-5f

typedef unsigned short ushort_t;
typedef __attribute__((ext_vector_type(8))) short s8v;   // 8 bf16 = 4 VGPR
typedef __attribute__((ext_vector_type(4))) float f4v;   // MFMA accum

static __device__ __forceinline__ float lrelu(float x) { return x > 0.f ? x : NEG * x; }

static __device__ __forceinline__ float bf2f(ushort_t u) {
    union { unsigned int i; float f; } v; v.i = ((unsigned int)u) << 16; return v.f;
}
static __device__ __forceinline__ ushort_t f2bf(float f) {
    union { float f; unsigned int i; } v; v.f = f;
    unsigned int x = v.i;
    return (ushort_t)((x + 0x7fff + ((x >> 16) & 1)) >> 16);   // RNE
}

// wave-local int64-vs-int32 detection: sample 64 odd 32-bit words; all zero
// => int64 layout. Every wave computes the identical value (deterministic).
static __device__ __forceinline__ int detect64(const int* __restrict__ ei, int E) {
    int lane = threadIdx.x & 63;
    long idx = 2L * ((long)lane * (E / 64)) + 1;
    int v = ei[idx];
    unsigned long long ball = __ballot(v == 0);
    return (ball == ~0ull) ? 1 : 0;
}

// ---------------------------------------------------------------------------
// CSR build
__global__ void k_count(const int* __restrict__ ei, int* __restrict__ counts,
                        int E, int n) {
    int is64 = detect64(ei, E);
    int i = blockIdx.x * blockDim.x + threadIdx.x;
    if (i < E) {
        int d = ei[(size_t)(E + i) << is64];
        atomicAdd(&counts[d], 1);
    } else if (i < E + n) {
        atomicAdd(&counts[i - E], 1);
    }
}

__global__ __launch_bounds__(1024) void k_scan1(const int* __restrict__ counts,
                                                int* __restrict__ incl,
                                                int* __restrict__ bsum, int n) {
    int t = threadIdx.x, i = blockIdx.x * 1024 + t;
    int lane = t & 63, w = t >> 6;
    int v = (i < n) ? counts[i] : 0;
    int sv = v;
#pragma unroll
    for (int o = 1; o < 64; o <<= 1) { int u = __shfl_up(sv, o, 64); if (lane >= o) sv += u; }
    __shared__ int wsum[16];
    if (lane == 63) wsum[w] = sv;
    __syncthreads();
    if (w == 0) {
        int bs = (lane < 16) ? wsum[lane] : 0;
#pragma unroll
        for (int o = 1; o < 16; o <<= 1) { int u = __shfl_up(bs, o, 64); if (lane >= o) bs += u; }
        if (lane < 16) wsum[lane] = bs;
    }
    __syncthreads();
    int pre = (w > 0) ? wsum[w - 1] : 0;
    sv += pre;
    if (i < n) incl[i] = sv;
    if (t == 1023) bsum[blockIdx.x] = sv;
}

__global__ void k_scan2(int* __restrict__ bsum, int nb) {
    int lane = threadIdx.x;
    int v = (lane < nb) ? bsum[lane] : 0;
    int sv = v;
#pragma unroll
    for (int o = 1; o < 64; o <<= 1) { int u = __shfl_up(sv, o, 64); if (lane >= o) sv += u; }
    if (lane < nb) bsum[lane] = sv - v;
}

__global__ void k_scan3(const int* __restrict__ incl, const int* __restrict__ bsum,
                        const int* __restrict__ counts,
                        int* __restrict__ offs, int* __restrict__ cursor, int n) {
    int i = blockIdx.x * blockDim.x + threadIdx.x;
    if (i < n) {
        int v = incl[i] + bsum[i >> 10];
        offs[i + 1] = v;
        cursor[i] = v - counts[i];
    }
    if (i == 0) offs[0] = 0;
}

__global__ void k_fill(const int* __restrict__ ei, int* __restrict__ cursor,
                       int* __restrict__ esrc, int E, int n) {
    int is64 = detect64(ei, E);
    int i = blockIdx.x * blockDim.x + threadIdx.x;
    if (i >= E + n) return;
    int s, d;
    if (i < E) { s = ei[(size_t)i << is64]; d = ei[(size_t)(E + i) << is64]; }
    else       { s = i - E; d = s; }
    int p = atomicAdd(&cursor[d], 1);
    esrc[p] = s;
}

// ---------------------------------------------------------------------------
// pack W[K,M] f32 -> hi/lo bf16 in per-lane B-fragment order
__global__ void k_prepw(const float* __restrict__ W, ushort_t* __restrict__ Wh,
                        ushort_t* __restrict__ Wl, int K, int M) {
    int gid = blockIdx.x * 256 + threadIdx.x;
    if (gid >= K * M) return;
    int k = gid / M, nn = gid - k * M;
    int ntile = nn >> 4, j = nn & 15, kc = k >> 3, e = k & 7;
    int p = ((ntile * (K >> 3) + kc) * 16 + j) * 8 + e;
    float v = W[gid];
    ushort_t hi = f2bf(v);
    float r = v - bf2f(hi);
    Wh[p] = hi;
    Wl[p] = f2bf(r);
}

// ---------------------------------------------------------------------------
// MFMA GEMM, bf16x3 split precision: C[n,Mout](bf16) = A[n,256](f32) @ W
__global__ __launch_bounds__(256) void k_mm(const float* __restrict__ A,
                                            const ushort_t* __restrict__ Wh,
                                            const ushort_t* __restrict__ Wl,
                                            ushort_t* __restrict__ C, int n, int Mout) {
    __shared__ ushort_t Ah[128][40];
    __shared__ ushort_t Al[128][40];
    const int t = threadIdx.x;
    const int lane = t & 63, w = t >> 6;
    const int wr = w >> 1, wc = w & 1;
    const int r0 = blockIdx.x * 128;
    const int srow = t >> 1;
    const int kh = (t & 1) * 16;
    const int arow = r0 + srow;
    const bool rowok = arow < n;

    f4v acc[4][4];
#pragma unroll
    for (int a = 0; a < 4; ++a)
#pragma unroll
        for (int b = 0; b < 4; ++b) { f4v z = {0.f, 0.f, 0.f, 0.f}; acc[a][b] = z; }

    float pre[16];
    const float* abase = &A[(size_t)arow * 256 + kh];
#pragma unroll
    for (int q = 0; q < 4; ++q) {
        float4 v = rowok ? *reinterpret_cast<const float4*>(abase + q * 4)
                         : float4{0.f, 0.f, 0.f, 0.f};
        pre[q * 4 + 0] = v.x; pre[q * 4 + 1] = v.y;
        pre[q * 4 + 2] = v.z; pre[q * 4 + 3] = v.w;
    }

    const int lj = lane & 15, lk = lane >> 4;

    for (int kb = 0; kb < 256; kb += 32) {
        __syncthreads();
#pragma unroll
        for (int q = 0; q < 2; ++q) {
            unsigned int hw[4], lw[4];
#pragma unroll
            for (int p = 0; p < 4; ++p) {
                float v0 = pre[q * 8 + p * 2], v1 = pre[q * 8 + p * 2 + 1];
                ushort_t h0 = f2bf(v0), h1 = f2bf(v1);
                ushort_t l0 = f2bf(v0 - bf2f(h0)), l1 = f2bf(v1 - bf2f(h1));
                hw[p] = (unsigned int)h0 | ((unsigned int)h1 << 16);
                lw[p] = (unsigned int)l0 | ((unsigned int)l1 << 16);
            }
            uint4 hv = {hw[0], hw[1], hw[2], hw[3]};
            uint4 lv = {lw[0], lw[1], lw[2], lw[3]};
            *reinterpret_cast<uint4*>(&Ah[srow][kh + q * 8]) = hv;
            *reinterpret_cast<uint4*>(&Al[srow][kh + q * 8]) = lv;
        }
        __syncthreads();
        if (kb < 224) {
            const float* ap = abase + kb + 32;
#pragma unroll
            for (int q = 0; q < 4; ++q) {
                float4 v = rowok ? *reinterpret_cast<const float4*>(ap + q * 4)
                                 : float4{0.f, 0.f, 0.f, 0.f};
                pre[q * 4 + 0] = v.x; pre[q * 4 + 1] = v.y;
                pre[q * 4 + 2] = v.z; pre[q * 4 + 3] = v.w;
            }
        }
        const int kc0 = kb >> 3;
        s8v ah[4], al[4];
#pragma unroll
        for (int mf = 0; mf < 4; ++mf) {
            ah[mf] = *reinterpret_cast<const s8v*>(&Ah[wr * 64 + mf * 16 + lj][lk * 8]);
            al[mf] = *reinterpret_cast<const s8v*>(&Al[wr * 64 + mf * 16 + lj][lk * 8]);
        }
#pragma unroll
        for (int nf = 0; nf < 4; ++nf) {
            int ntile = blockIdx.y * 8 + wc * 4 + nf;
            size_t boff = ((size_t)(ntile * 32 + kc0 + lk) * 16 + lj) * 8;
            s8v bh = *reinterpret_cast<const s8v*>(&Wh[boff]);
            s8v bl = *reinterpret_cast<const s8v*>(&Wl[boff]);
#pragma unroll
            for (int mf = 0; mf < 4; ++mf) {
                acc[mf][nf] = __builtin_amdgcn_mfma_f32_16x16x32_bf16(ah[mf], bh, acc[mf][nf], 0, 0, 0);
                acc[mf][nf] = __builtin_amdgcn_mfma_f32_16x16x32_bf16(ah[mf], bl, acc[mf][nf], 0, 0, 0);
                acc[mf][nf] = __builtin_amdgcn_mfma_f32_16x16x32_bf16(al[mf], bh, acc[mf][nf], 0, 0, 0);
            }
        }
    }

#pragma unroll
    for (int mf = 0; mf < 4; ++mf) {
        int rr = r0 + wr * 64 + mf * 16 + lk * 4;
#pragma unroll
        for (int nf = 0; nf < 4; ++nf) {
            int cc = blockIdx.y * 128 + wc * 64 + nf * 16 + lj;
#pragma unroll
            for (int r = 0; r < 4; ++r) {
                if (rr + r < n) C[(size_t)(rr + r) * Mout + cc] = f2bf(acc[mf][nf][r]);
            }
        }
    }
}

// ---------------------------------------------------------------------------
// attention logit dot products
__global__ __launch_bounds__(256) void k_att1(const ushort_t* __restrict__ h1,
                                              const float* __restrict__ att_s,
                                              const float* __restrict__ att_d,
                                              float* __restrict__ as1,
                                              float* __restrict__ ad1, int n) {
    int wid = (blockIdx.x * blockDim.x + threadIdx.x) >> 6;
    int lane = threadIdx.x & 63;
    if (wid >= n) return;
    int head = lane >> 3;
    int co = (lane & 7) * 4;
    ushort4 hu = *reinterpret_cast<const ushort4*>(&h1[(size_t)wid * 256 + head * 32 + co]);
    float4 vs = *reinterpret_cast<const float4*>(&att_s[head * 32 + co]);
    float4 vd = *reinterpret_cast<const float4*>(&att_d[head * 32 + co]);
    float hx = bf2f(hu.x), hy = bf2f(hu.y), hz = bf2f(hu.z), hw = bf2f(hu.w);
    float ss = hx * vs.x + hy * vs.y + hz * vs.z + hw * vs.w;
    float sd = hx * vd.x + hy * vd.y + hz * vd.z + hw * vd.w;
#pragma unroll
    for (int o = 1; o < 8; o <<= 1) { ss += __shfl_xor(ss, o, 64); sd += __shfl_xor(sd, o, 64); }
    if ((lane & 7) == 0) {
        as1[(size_t)wid * 8 + head] = ss;
        ad1[(size_t)wid * 8 + head] = sd;
    }
}

__global__ __launch_bounds__(256) void k_att2(const ushort_t* __restrict__ h2,
                                              const float* __restrict__ att_s,
                                              const float* __restrict__ att_d,
                                              float* __restrict__ as2,
                                              float* __restrict__ ad2, int n) {
    int wid = (blockIdx.x * blockDim.x + threadIdx.x) >> 6;
    int lane = threadIdx.x & 63;
    if (wid >= n) return;
    ushort2 hu = *reinterpret_cast<const ushort2*>(&h2[(size_t)wid * 128 + lane * 2]);
    float2 vs = *reinterpret_cast<const float2*>(&att_s[lane * 2]);
    float2 vd = *reinterpret_cast<const float2*>(&att_d[lane * 2]);
    float hx = bf2f(hu.x), hy = bf2f(hu.y);
    float ss = hx * vs.x + hy * vs.y;
    float sd = hx * vd.x + hy * vd.y;
#pragma unroll
    for (int o = 1; o < 64; o <<= 1) { ss += __shfl_xor(ss, o, 64); sd += __shfl_xor(sd, o, 64); }
    if (lane == 0) { as2[wid] = ss; ad2[wid] = sd; }
}

// ---------------------------------------------------------------------------
// layer-1 aggregation, two-phase exact softmax.
// Phase A: lane-parallel segment max of as1 (lrelu is monotonic =>
//          m = lrelu(max_s as1[s] + adn)). Phase B: p = exp(ea-m), plain FMAs,
//          no serial dependency.
__global__ __launch_bounds__(256) void k_agg1(const ushort_t* __restrict__ h1,
                                              const float* __restrict__ as1,
                                              const float* __restrict__ ad1,
                                              const int* __restrict__ offs,
                                              const int* __restrict__ esrc,
                                              const float* __restrict__ b1,
                                              float* __restrict__ out1, int n) {
    int wid = (blockIdx.x * blockDim.x + threadIdx.x) >> 6;
    int lane = threadIdx.x & 63;
    if (wid >= n) return;
    int head = lane >> 3;
    int g = lane & 7;
    int cb = lane * 4;
    float adn = ad1[(size_t)wid * 8 + head];
    int e0 = offs[wid], e1 = offs[wid + 1];

    // phase A: segment max (8 lanes of the head group split the edges)
    float mx = -1e30f;
    for (int e = e0 + g; e < e1; e += 8)
        mx = fmaxf(mx, as1[(size_t)esrc[e] * 8 + head]);
#pragma unroll
    for (int o = 1; o < 8; o <<= 1) mx = fmaxf(mx, __shfl_xor(mx, o, 64));
    float m = lrelu(mx + adn);

    // phase B: unnormalized accumulation, unroll 2
    float d = 0.f, ax = 0.f, ay = 0.f, az = 0.f, aw = 0.f;
    int e = e0;
    for (; e + 1 < e1; e += 2) {
        int sA = esrc[e], sB = esrc[e + 1];
        float pA = __expf(lrelu(as1[(size_t)sA * 8 + head] + adn) - m);
        float pB = __expf(lrelu(as1[(size_t)sB * 8 + head] + adn) - m);
        ushort4 hA = *reinterpret_cast<const ushort4*>(&h1[(size_t)sA * 256 + cb]);
        ushort4 hB = *reinterpret_cast<const ushort4*>(&h1[(size_t)sB * 256 + cb]);
        d += pA + pB;
        ax += pA * bf2f(hA.x) + pB * bf2f(hB.x);
        ay += pA * bf2f(hA.y) + pB * bf2f(hB.y);
        az += pA * bf2f(hA.z) + pB * bf2f(hB.z);
        aw += pA * bf2f(hA.w) + pB * bf2f(hB.w);
    }
    if (e < e1) {
        int s = esrc[e];
        float p = __expf(lrelu(as1[(size_t)s * 8 + head] + adn) - m);
        ushort4 hv = *reinterpret_cast<const ushort4*>(&h1[(size_t)s * 256 + cb]);
        d += p;
        ax += p * bf2f(hv.x);
        ay += p * bf2f(hv.y);
        az += p * bf2f(hv.z);
        aw += p * bf2f(hv.w);
    }
    float inv = 1.f / (d + 1e-16f);
    float4 bb = *reinterpret_cast<const float4*>(&b1[cb]);
    float4 o;
    o.x = fmaxf(ax * inv + bb.x, 0.f);
    o.y = fmaxf(ay * inv + bb.y, 0.f);
    o.z = fmaxf(az * inv + bb.z, 0.f);
    o.w = fmaxf(aw * inv + bb.w, 0.f);
    *reinterpret_cast<float4*>(&out1[(size_t)wid * 256 + cb]) = o;
}

// layer-2 aggregation, two-phase exact softmax
__global__ __launch_bounds__(256) void k_agg2(const ushort_t* __restrict__ h2,
                                              const float* __restrict__ as2,
                                              const float* __restrict__ ad2,
                                              const int* __restrict__ offs,
                                              const int* __restrict__ esrc,
                                              const float* __restrict__ b2,
                                              float* __restrict__ out2, int n) {
    int wid = (blockIdx.x * blockDim.x + threadIdx.x) >> 6;
    int lane = threadIdx.x & 63;
    if (wid >= n) return;
    int cb = lane * 2;
    float adn = ad2[wid];
    int e0 = offs[wid], e1 = offs[wid + 1];

    // phase A: full-wave segment max
    float mx = -1e30f;
    for (int e = e0 + lane; e < e1; e += 64)
        mx = fmaxf(mx, as2[esrc[e]]);
#pragma unroll
    for (int o = 1; o < 64; o <<= 1) mx = fmaxf(mx, __shfl_xor(mx, o, 64));
    float m = lrelu(mx + adn);

    // phase B
    float d = 0.f, ax = 0.f, ay = 0.f;
    int e = e0;
    for (; e + 1 < e1; e += 2) {
        int sA = esrc[e], sB = esrc[e + 1];
        float pA = __expf(lrelu(as2[sA] + adn) - m);
        float pB = __expf(lrelu(as2[sB] + adn) - m);
        ushort2 hA = *reinterpret_cast<const ushort2*>(&h2[(size_t)sA * 128 + cb]);
        ushort2 hB = *reinterpret_cast<const ushort2*>(&h2[(size_t)sB * 128 + cb]);
        d += pA + pB;
        ax += pA * bf2f(hA.x) + pB * bf2f(hB.x);
        ay += pA * bf2f(hA.y) + pB * bf2f(hB.y);
    }
    if (e < e1) {
        int s = esrc[e];
        float p = __expf(lrelu(as2[s] + adn) - m);
        ushort2 hv = *reinterpret_cast<const ushort2*>(&h2[(size_t)s * 128 + cb]);
        d += p;
        ax += p * bf2f(hv.x);
        ay += p * bf2f(hv.y);
    }
    float inv = 1.f / (d + 1e-16f);
    float o0 = fmaxf(ax * inv + b2[cb], 0.f);
    float o1 = fmaxf(ay * inv + b2[cb + 1], 0.f);
    float2 o = {o0, o1};
    *reinterpret_cast<float2*>(&out2[(size_t)wid * 128 + cb]) = o;
}

// ---------------------------------------------------------------------------
__global__ __launch_bounds__(128) void k_bnstat(const float* __restrict__ out2,
                                                float* __restrict__ bnsum,
                                                float* __restrict__ bnsq, int n) {
    int c = threadIdx.x;
    float s = 0.f, q = 0.f;
    for (int r = blockIdx.x; r < n; r += gridDim.x) {
        float v = out2[(size_t)r * 128 + c];
        s += v;
        q += v * v;
    }
    atomicAdd(&bnsum[c], s);
    atomicAdd(&bnsq[c], q);
}

__global__ __launch_bounds__(256) void k_final(const float* __restrict__ out2,
                                               const float* __restrict__ bnsum,
                                               const float* __restrict__ bnsq,
                                               const float* __restrict__ bng,
                                               const float* __restrict__ bnb,
                                               const float* __restrict__ lng,
                                               const float* __restrict__ lnb,
                                               float* __restrict__ out, int n) {
    int wid = (blockIdx.x * blockDim.x + threadIdx.x) >> 6;
    int lane = threadIdx.x & 63;
    if (wid >= n) return;
    int c0 = lane, c1 = lane + 64;
    float invn = 1.f / (float)n;
    float mu0 = bnsum[c0] * invn, mu1 = bnsum[c1] * invn;
    float v0 = bnsq[c0] * invn - mu0 * mu0;
    float v1 = bnsq[c1] * invn - mu1 * mu1;
    float r0 = rsqrtf(v0 + EPSV), r1 = rsqrtf(v1 + EPSV);
    float x0 = out2[(size_t)wid * 128 + c0];
    float x1 = out2[(size_t)wid * 128 + c1];
    float y0 = (x0 - mu0) * r0 * bng[c0] + bnb[c0];
    float y1 = (x1 - mu1) * r1 * bng[c1] + bnb[c1];
    float s = y0 + y1, q = y0 * y0 + y1 * y1;
#pragma unroll
    for (int o = 1; o < 64; o <<= 1) { s += __shfl_xor(s, o, 64); q += __shfl_xor(q, o, 64); }
    float mu = s * (1.f / 128.f);
    float var = q * (1.f / 128.f) - mu * mu;
    float rr = rsqrtf(var + EPSV);
    out[(size_t)wid * 128 + c0] = (y0 - mu) * rr * lng[c0] + lnb[c0];
    out[(size_t)wid * 128 + c1] = (y1 - mu) * rr * lng[c1] + lnb[c1];
}

// ---------------------------------------------------------------------------
extern "C" void kernel_launch(void* const* d_in, const int* in_sizes, int n_in,
                              void* d_out, int out_size, void* d_ws, size_t ws_size,
                              hipStream_t stream) {
    const float* x    = (const float*)d_in[0];
    const int*   ei   = (const int*)d_in[1];
    const float* W1   = (const float*)d_in[2];
    const float* ats1 = (const float*)d_in[3];
    const float* atd1 = (const float*)d_in[4];
    const float* b1   = (const float*)d_in[5];
    const float* W2   = (const float*)d_in[6];
    const float* ats2 = (const float*)d_in[7];
    const float* atd2 = (const float*)d_in[8];
    const float* b2   = (const float*)d_in[9];
    const float* bng  = (const float*)d_in[10];
    const float* bnb  = (const float*)d_in[11];
    const float* lng  = (const float*)d_in[12];
    const float* lnb  = (const float*)d_in[13];

    const int n = in_sizes[0] / NFEAT;   // 50000
    const int E = in_sizes[1] / 2;       // 800000
    const int tot = E + n;

    auto align = [](size_t v) { return (v + 255) & ~(size_t)255; };
    char* ws = (char*)d_ws;
    size_t off = 0;
    ushort_t* h1 = (ushort_t*)(ws + off); off += align((size_t)n * 256 * 2);
    float* out1 = (float*)(ws + off); off += align((size_t)n * 256 * 4);
    ushort_t* h2 = h1;
    float* out2 = out1;
    float* as1 = (float*)(ws + off); off += align((size_t)n * 8 * 4);
    float* ad1 = (float*)(ws + off); off += align((size_t)n * 8 * 4);
    float* as2 = (float*)(ws + off); off += align((size_t)n * 4);
    float* ad2 = (float*)(ws + off); off += align((size_t)n * 4);
    int* counts = (int*)(ws + off); off += align((size_t)n * 4);
    int* offs   = (int*)(ws + off); off += align((size_t)(n + 1) * 4);
    int* cursor = (int*)(ws + off); off += align((size_t)n * 4);
    int* esrc   = (int*)(ws + off); off += align((size_t)tot * 4);
    int* incl   = (int*)(ws + off); off += align((size_t)n * 4);
    int* bsum   = (int*)(ws + off); off += align(64 * 4);
    float* bnsum = (float*)(ws + off); off += align(128 * 4);
    float* bnsq  = (float*)(ws + off); off += align(128 * 4);
    ushort_t* Wh1 = (ushort_t*)(ws + off); off += align((size_t)256 * 256 * 2);
    ushort_t* Wl1 = (ushort_t*)(ws + off); off += align((size_t)256 * 256 * 2);
    ushort_t* Wh2 = (ushort_t*)(ws + off); off += align((size_t)256 * 128 * 2);
    ushort_t* Wl2 = (ushort_t*)(ws + off); off += align((size_t)256 * 128 * 2);

    hipMemsetAsync(counts, 0, (size_t)n * 4, stream);
    hipMemsetAsync(bnsum, 0, 128 * 4, stream);
    hipMemsetAsync(bnsq, 0, 128 * 4, stream);

    // W packing (tiny, overlaps CSR build)
    k_prepw<<<(256 * 256 + 255) / 256, 256, 0, stream>>>(W1, Wh1, Wl1, 256, 256);
    k_prepw<<<(256 * 128 + 255) / 256, 256, 0, stream>>>(W2, Wh2, Wl2, 256, 128);

    // CSR build (edge dtype detected inline per wave)
    k_count<<<(tot + 255) / 256, 256, 0, stream>>>(ei, counts, E, n);
    int nsb = (n + 1023) / 1024;
    k_scan1<<<nsb, 1024, 0, stream>>>(counts, incl, bsum, n);
    k_scan2<<<1, 64, 0, stream>>>(bsum, nsb);
    k_scan3<<<(n + 255) / 256, 256, 0, stream>>>(incl, bsum, counts, offs, cursor, n);
    k_fill<<<(tot + 255) / 256, 256, 0, stream>>>(ei, cursor, esrc, E, n);

    const int gx = (n + 127) / 128;
    // layer 1
    k_mm<<<dim3(gx, 2), 256, 0, stream>>>(x, Wh1, Wl1, h1, n, 256);
    k_att1<<<(n + 3) / 4, 256, 0, stream>>>(h1, ats1, atd1, as1, ad1, n);
    k_agg1<<<(n + 3) / 4, 256, 0, stream>>>(h1, as1, ad1, offs, esrc, b1, out1, n);

    // layer 2
    k_mm<<<dim3(gx, 1), 256, 0, stream>>>(out1, Wh2, Wl2, h2, n, 128);
    k_att2<<<(n + 3) / 4, 256, 0, stream>>>(h2, ats2, atd2, as2, ad2, n);
    k_agg2<<<(n + 3) / 4, 256, 0, stream>>>(h2, as2, ad2, offs, esrc, b2, out2, n);

    // BN + LN
    k_bnstat<<<512, 128, 0, stream>>>(out2, bnsum, bnsq, n);
    k_final<<<(n + 3) / 4, 256, 0, stream>>>(out2, bnsum, bnsq, bng, bnb, lng, lnb,
                                             (float*)d_out, n);
}

// Round 5
// 401.440 us; speedup vs baseline: 1.0024x; 1.0024x over previous
//
#include <hip/hip_runtime.h>
#include <cstdint>
#include <cstddef>

#define HEADS   8
#define NFEAT   256
#define NOUT    128
#define NEG     0.2f
#define EPSV    1e-5f

typedef unsigned short ushort_t;
typedef __attribute__((ext_vector_type(8))) short s8v;   // 8 bf16 = 4 VGPR
typedef __attribute__((ext_vector_type(4))) float f4v;   // MFMA accum

static __device__ __forceinline__ float lrelu(float x) { return x > 0.f ? x : NEG * x; }

static __device__ __forceinline__ float bf2f(ushort_t u) {
    union { unsigned int i; float f; } v; v.i = ((unsigned int)u) << 16; return v.f;
}
static __device__ __forceinline__ ushort_t f2bf(float f) {
    union { float f; unsigned int i; } v; v.f = f;
    unsigned int x = v.i;
    return (ushort_t)((x + 0x7fff + ((x >> 16) & 1)) >> 16);   // RNE
}

// wave-local int64-vs-int32 detection (deterministic, identical in every wave)
static __device__ __forceinline__ int detect64(const int* __restrict__ ei, int E) {
    int lane = threadIdx.x & 63;
    long idx = 2L * ((long)lane * (E / 64)) + 1;
    int v = ei[idx];
    unsigned long long ball = __ballot(v == 0);
    return (ball == ~0ull) ? 1 : 0;
}

// ---------------------------------------------------------------------------
// CSR build
__global__ void k_count(const int* __restrict__ ei, int* __restrict__ counts,
                        int E, int n) {
    int is64 = detect64(ei, E);
    int i = blockIdx.x * blockDim.x + threadIdx.x;
    if (i < E) {
        int d = ei[(size_t)(E + i) << is64];
        atomicAdd(&counts[d], 1);
    } else if (i < E + n) {
        atomicAdd(&counts[i - E], 1);
    }
}

__global__ __launch_bounds__(1024) void k_scan1(const int* __restrict__ counts,
                                                int* __restrict__ incl,
                                                int* __restrict__ bsum, int n) {
    int t = threadIdx.x, i = blockIdx.x * 1024 + t;
    int lane = t & 63, w = t >> 6;
    int v = (i < n) ? counts[i] : 0;
    int sv = v;
#pragma unroll
    for (int o = 1; o < 64; o <<= 1) { int u = __shfl_up(sv, o, 64); if (lane >= o) sv += u; }
    __shared__ int wsum[16];
    if (lane == 63) wsum[w] = sv;
    __syncthreads();
    if (w == 0) {
        int bs = (lane < 16) ? wsum[lane] : 0;
#pragma unroll
        for (int o = 1; o < 16; o <<= 1) { int u = __shfl_up(bs, o, 64); if (lane >= o) bs += u; }
        if (lane < 16) wsum[lane] = bs;
    }
    __syncthreads();
    int pre = (w > 0) ? wsum[w - 1] : 0;
    sv += pre;
    if (i < n) incl[i] = sv;
    if (t == 1023) bsum[blockIdx.x] = sv;
}

__global__ void k_scan2(int* __restrict__ bsum, int nb) {
    int lane = threadIdx.x;
    int v = (lane < nb) ? bsum[lane] : 0;
    int sv = v;
#pragma unroll
    for (int o = 1; o < 64; o <<= 1) { int u = __shfl_up(sv, o, 64); if (lane >= o) sv += u; }
    if (lane < nb) bsum[lane] = sv - v;
}

__global__ void k_scan3(const int* __restrict__ incl, const int* __restrict__ bsum,
                        const int* __restrict__ counts,
                        int* __restrict__ offs, int* __restrict__ cursor, int n) {
    int i = blockIdx.x * blockDim.x + threadIdx.x;
    if (i < n) {
        int v = incl[i] + bsum[i >> 10];
        offs[i + 1] = v;
        cursor[i] = v - counts[i];
    }
    if (i == 0) offs[0] = 0;
}

__global__ void k_fill(const int* __restrict__ ei, int* __restrict__ cursor,
                       int* __restrict__ esrc, int E, int n) {
    int is64 = detect64(ei, E);
    int i = blockIdx.x * blockDim.x + threadIdx.x;
    if (i >= E + n) return;
    int s, d;
    if (i < E) { s = ei[(size_t)i << is64]; d = ei[(size_t)(E + i) << is64]; }
    else       { s = i - E; d = s; }
    int p = atomicAdd(&cursor[d], 1);
    esrc[p] = s;
}

// ---------------------------------------------------------------------------
// pack W[K,M] f32 -> hi/lo bf16 in per-lane B-fragment order
__global__ void k_prepw(const float* __restrict__ W, ushort_t* __restrict__ Wh,
                        ushort_t* __restrict__ Wl, int K, int M) {
    int gid = blockIdx.x * 256 + threadIdx.x;
    if (gid >= K * M) return;
    int k = gid / M, nn = gid - k * M;
    int ntile = nn >> 4, j = nn & 15, kc = k >> 3, e = k & 7;
    int p = ((ntile * (K >> 3) + kc) * 16 + j) * 8 + e;
    float v = W[gid];
    ushort_t hi = f2bf(v);
    float r = v - bf2f(hi);
    Wh[p] = hi;
    Wl[p] = f2bf(r);
}

// ---------------------------------------------------------------------------
// MFMA GEMM, bf16x3 split precision: C[n,Mout](bf16) = A[n,256](f32) @ W
__global__ __launch_bounds__(256) void k_mm(const float* __restrict__ A,
                                            const ushort_t* __restrict__ Wh,
                                            const ushort_t* __restrict__ Wl,
                                            ushort_t* __restrict__ C, int n, int Mout) {
    __shared__ ushort_t Ah[128][40];
    __shared__ ushort_t Al[128][40];
    const int t = threadIdx.x;
    const int lane = t & 63, w = t >> 6;
    const int wr = w >> 1, wc = w & 1;
    const int r0 = blockIdx.x * 128;
    const int srow = t >> 1;
    const int kh = (t & 1) * 16;
    const int arow = r0 + srow;
    const bool rowok = arow < n;

    f4v acc[4][4];
#pragma unroll
    for (int a = 0; a < 4; ++a)
#pragma unroll
        for (int b = 0; b < 4; ++b) { f4v z = {0.f, 0.f, 0.f, 0.f}; acc[a][b] = z; }

    float pre[16];
    const float* abase = &A[(size_t)arow * 256 + kh];
#pragma unroll
    for (int q = 0; q < 4; ++q) {
        float4 v = rowok ? *reinterpret_cast<const float4*>(abase + q * 4)
                         : float4{0.f, 0.f, 0.f, 0.f};
        pre[q * 4 + 0] = v.x; pre[q * 4 + 1] = v.y;
        pre[q * 4 + 2] = v.z; pre[q * 4 + 3] = v.w;
    }

    const int lj = lane & 15, lk = lane >> 4;

    for (int kb = 0; kb < 256; kb += 32) {
        __syncthreads();
#pragma unroll
        for (int q = 0; q < 2; ++q) {
            unsigned int hw[4], lw[4];
#pragma unroll
            for (int p = 0; p < 4; ++p) {
                float v0 = pre[q * 8 + p * 2], v1 = pre[q * 8 + p * 2 + 1];
                ushort_t h0 = f2bf(v0), h1 = f2bf(v1);
                ushort_t l0 = f2bf(v0 - bf2f(h0)), l1 = f2bf(v1 - bf2f(h1));
                hw[p] = (unsigned int)h0 | ((unsigned int)h1 << 16);
                lw[p] = (unsigned int)l0 | ((unsigned int)l1 << 16);
            }
            uint4 hv = {hw[0], hw[1], hw[2], hw[3]};
            uint4 lv = {lw[0], lw[1], lw[2], lw[3]};
            *reinterpret_cast<uint4*>(&Ah[srow][kh + q * 8]) = hv;
            *reinterpret_cast<uint4*>(&Al[srow][kh + q * 8]) = lv;
        }
        __syncthreads();
        if (kb < 224) {
            const float* ap = abase + kb + 32;
#pragma unroll
            for (int q = 0; q < 4; ++q) {
                float4 v = rowok ? *reinterpret_cast<const float4*>(ap + q * 4)
                                 : float4{0.f, 0.f, 0.f, 0.f};
                pre[q * 4 + 0] = v.x; pre[q * 4 + 1] = v.y;
                pre[q * 4 + 2] = v.z; pre[q * 4 + 3] = v.w;
            }
        }
        const int kc0 = kb >> 3;
        s8v ah[4], al[4];
#pragma unroll
        for (int mf = 0; mf < 4; ++mf) {
            ah[mf] = *reinterpret_cast<const s8v*>(&Ah[wr * 64 + mf * 16 + lj][lk * 8]);
            al[mf] = *reinterpret_cast<const s8v*>(&Al[wr * 64 + mf * 16 + lj][lk * 8]);
        }
#pragma unroll
        for (int nf = 0; nf < 4; ++nf) {
            int ntile = blockIdx.y * 8 + wc * 4 + nf;
            size_t boff = ((size_t)(ntile * 32 + kc0 + lk) * 16 + lj) * 8;
            s8v bh = *reinterpret_cast<const s8v*>(&Wh[boff]);
            s8v bl = *reinterpret_cast<const s8v*>(&Wl[boff]);
#pragma unroll
            for (int mf = 0; mf < 4; ++mf) {
                acc[mf][nf] = __builtin_amdgcn_mfma_f32_16x16x32_bf16(ah[mf], bh, acc[mf][nf], 0, 0, 0);
                acc[mf][nf] = __builtin_amdgcn_mfma_f32_16x16x32_bf16(ah[mf], bl, acc[mf][nf], 0, 0, 0);
                acc[mf][nf] = __builtin_amdgcn_mfma_f32_16x16x32_bf16(al[mf], bh, acc[mf][nf], 0, 0, 0);
            }
        }
    }

#pragma unroll
    for (int mf = 0; mf < 4; ++mf) {
        int rr = r0 + wr * 64 + mf * 16 + lk * 4;
#pragma unroll
        for (int nf = 0; nf < 4; ++nf) {
            int cc = blockIdx.y * 128 + wc * 64 + nf * 16 + lj;
#pragma unroll
            for (int r = 0; r < 4; ++r) {
                if (rr + r < n) C[(size_t)(rr + r) * Mout + cc] = f2bf(acc[mf][nf][r]);
            }
        }
    }
}

// ---------------------------------------------------------------------------
// attention logit dot products
__global__ __launch_bounds__(256) void k_att1(const ushort_t* __restrict__ h1,
                                              const float* __restrict__ att_s,
                                              const float* __restrict__ att_d,
                                              float* __restrict__ as1,
                                              float* __restrict__ ad1, int n) {
    int wid = (blockIdx.x * blockDim.x + threadIdx.x) >> 6;
    int lane = threadIdx.x & 63;
    if (wid >= n) return;
    int head = lane >> 3;
    int co = (lane & 7) * 4;
    ushort4 hu = *reinterpret_cast<const ushort4*>(&h1[(size_t)wid * 256 + head * 32 + co]);
    float4 vs = *reinterpret_cast<const float4*>(&att_s[head * 32 + co]);
    float4 vd = *reinterpret_cast<const float4*>(&att_d[head * 32 + co]);
    float hx = bf2f(hu.x), hy = bf2f(hu.y), hz = bf2f(hu.z), hw = bf2f(hu.w);
    float ss = hx * vs.x + hy * vs.y + hz * vs.z + hw * vs.w;
    float sd = hx * vd.x + hy * vd.y + hz * vd.z + hw * vd.w;
#pragma unroll
    for (int o = 1; o < 8; o <<= 1) { ss += __shfl_xor(ss, o, 64); sd += __shfl_xor(sd, o, 64); }
    if ((lane & 7) == 0) {
        as1[(size_t)wid * 8 + head] = ss;
        ad1[(size_t)wid * 8 + head] = sd;
    }
}

__global__ __launch_bounds__(256) void k_att2(const ushort_t* __restrict__ h2,
                                              const float* __restrict__ att_s,
                                              const float* __restrict__ att_d,
                                              float* __restrict__ as2,
                                              float* __restrict__ ad2, int n) {
    int wid = (blockIdx.x * blockDim.x + threadIdx.x) >> 6;
    int lane = threadIdx.x & 63;
    if (wid >= n) return;
    ushort2 hu = *reinterpret_cast<const ushort2*>(&h2[(size_t)wid * 128 + lane * 2]);
    float2 vs = *reinterpret_cast<const float2*>(&att_s[lane * 2]);
    float2 vd = *reinterpret_cast<const float2*>(&att_d[lane * 2]);
    float hx = bf2f(hu.x), hy = bf2f(hu.y);
    float ss = hx * vs.x + hy * vs.y;
    float sd = hx * vd.x + hy * vd.y;
#pragma unroll
    for (int o = 1; o < 64; o <<= 1) { ss += __shfl_xor(ss, o, 64); sd += __shfl_xor(sd, o, 64); }
    if (lane == 0) { as2[wid] = ss; ad2[wid] = sd; }
}

// ---------------------------------------------------------------------------
// layer-1 aggregation v3: MLP-oriented two-phase exact softmax.
// Fast path (deg<=64): one coalesced esrc chunk load; phase-A as1 gathers all
// independent into regs a[0..7]; phase-B attention values via shfl from a[]
// (no re-gather), h1 gathers fully independent. Uniform guards only.
__global__ __launch_bounds__(256) void k_agg1(const ushort_t* __restrict__ h1,
                                              const float* __restrict__ as1,
                                              const float* __restrict__ ad1,
                                              const int* __restrict__ offs,
                                              const int* __restrict__ esrc,
                                              const float* __restrict__ b1,
                                              float* __restrict__ out1, int n, int tot) {
    int wid = (blockIdx.x * blockDim.x + threadIdx.x) >> 6;
    int lane = threadIdx.x & 63;
    if (wid >= n) return;
    int head = lane >> 3;
    int g = lane & 7;
    int cb = lane * 4;
    float adn = ad1[(size_t)wid * 8 + head];
    int e0 = offs[wid], e1 = offs[wid + 1];
    int deg = e1 - e0;

    float d = 0.f, ax = 0.f, ay = 0.f, az = 0.f, aw = 0.f;

    if (deg <= 64) {
        int ei_idx = e0 + lane;
        int es = esrc[ei_idx < tot ? ei_idx : (tot - 1)];
        // phase A: lane (head,g) holds as1 of edges i = g+8k
        float a[8];
#pragma unroll
        for (int k = 0; k < 8; ++k) {
            int i = g + 8 * k;
            int s = __shfl(es, i, 64);
            a[k] = (i < deg) ? as1[(size_t)s * 8 + head] : -1e30f;
        }
        float mx = a[0];
#pragma unroll
        for (int k = 1; k < 8; ++k) mx = fmaxf(mx, a[k]);
#pragma unroll
        for (int o = 1; o < 8; o <<= 1) mx = fmaxf(mx, __shfl_xor(mx, o, 64));
        float m = lrelu(mx + adn);
        // phase B: edge i's attention value lives in lane head*8+(i&7), reg i>>3
#pragma unroll
        for (int k = 0; k < 8; ++k) {
            if (8 * k < deg) {
#pragma unroll
                for (int j = 0; j < 8; ++j) {
                    int i = 8 * k + j;
                    if (i < deg) {
                        int s = __shfl(es, i, 64);
                        float av = __shfl(a[k], head * 8 + j, 64);
                        float p = __expf(lrelu(av + adn) - m);
                        ushort4 hv = *reinterpret_cast<const ushort4*>(&h1[(size_t)s * 256 + cb]);
                        d += p;
                        ax += p * bf2f(hv.x);
                        ay += p * bf2f(hv.y);
                        az += p * bf2f(hv.z);
                        aw += p * bf2f(hv.w);
                    }
                }
            }
        }
    } else {
        // rare slow path
        float mx = -1e30f;
        for (int e = e0 + g; e < e1; e += 8)
            mx = fmaxf(mx, as1[(size_t)esrc[e] * 8 + head]);
#pragma unroll
        for (int o = 1; o < 8; o <<= 1) mx = fmaxf(mx, __shfl_xor(mx, o, 64));
        float m = lrelu(mx + adn);
        for (int e = e0; e < e1; ++e) {
            int s = esrc[e];
            float p = __expf(lrelu(as1[(size_t)s * 8 + head] + adn) - m);
            ushort4 hv = *reinterpret_cast<const ushort4*>(&h1[(size_t)s * 256 + cb]);
            d += p;
            ax += p * bf2f(hv.x);
            ay += p * bf2f(hv.y);
            az += p * bf2f(hv.z);
            aw += p * bf2f(hv.w);
        }
    }

    float inv = 1.f / (d + 1e-16f);
    float4 bb = *reinterpret_cast<const float4*>(&b1[cb]);
    float4 o;
    o.x = fmaxf(ax * inv + bb.x, 0.f);
    o.y = fmaxf(ay * inv + bb.y, 0.f);
    o.z = fmaxf(az * inv + bb.z, 0.f);
    o.w = fmaxf(aw * inv + bb.w, 0.f);
    *reinterpret_cast<float4*>(&out1[(size_t)wid * 256 + cb]) = o;
}

// layer-2 aggregation v3, same structure (1 head, attention value per lane)
__global__ __launch_bounds__(256) void k_agg2(const ushort_t* __restrict__ h2,
                                              const float* __restrict__ as2,
                                              const float* __restrict__ ad2,
                                              const int* __restrict__ offs,
                                              const int* __restrict__ esrc,
                                              const float* __restrict__ b2,
                                              float* __restrict__ out2, int n, int tot) {
    int wid = (blockIdx.x * blockDim.x + threadIdx.x) >> 6;
    int lane = threadIdx.x & 63;
    if (wid >= n) return;
    int cb = lane * 2;
    float adn = ad2[wid];
    int e0 = offs[wid], e1 = offs[wid + 1];
    int deg = e1 - e0;

    float d = 0.f, ax = 0.f, ay = 0.f;

    if (deg <= 64) {
        int ei_idx = e0 + lane;
        int es = esrc[ei_idx < tot ? ei_idx : (tot - 1)];
        float av = (lane < deg) ? as2[es] : -1e30f;
        float mx = av;
#pragma unroll
        for (int o = 1; o < 64; o <<= 1) mx = fmaxf(mx, __shfl_xor(mx, o, 64));
        float m = lrelu(mx + adn);
#pragma unroll
        for (int k = 0; k < 8; ++k) {
            if (8 * k < deg) {
#pragma unroll
                for (int j = 0; j < 8; ++j) {
                    int i = 8 * k + j;
                    if (i < deg) {
                        int s = __shfl(es, i, 64);
                        float avi = __shfl(av, i, 64);
                        float p = __expf(lrelu(avi + adn) - m);
                        ushort2 hv = *reinterpret_cast<const ushort2*>(&h2[(size_t)s * 128 + cb]);
                        d += p;
                        ax += p * bf2f(hv.x);
                        ay += p * bf2f(hv.y);
                    }
                }
            }
        }
    } else {
        float mx = -1e30f;
        for (int e = e0 + lane; e < e1; e += 64)
            mx = fmaxf(mx, as2[esrc[e]]);
#pragma unroll
        for (int o = 1; o < 64; o <<= 1) mx = fmaxf(mx, __shfl_xor(mx, o, 64));
        float m = lrelu(mx + adn);
        for (int e = e0; e < e1; ++e) {
            int s = esrc[e];
            float p = __expf(lrelu(as2[s] + adn) - m);
            ushort2 hv = *reinterpret_cast<const ushort2*>(&h2[(size_t)s * 128 + cb]);
            d += p;
            ax += p * bf2f(hv.x);
            ay += p * bf2f(hv.y);
        }
    }

    float inv = 1.f / (d + 1e-16f);
    float o0 = fmaxf(ax * inv + b2[cb], 0.f);
    float o1 = fmaxf(ay * inv + b2[cb + 1], 0.f);
    float2 o = {o0, o1};
    *reinterpret_cast<float2*>(&out2[(size_t)wid * 128 + cb]) = o;
}

// ---------------------------------------------------------------------------
__global__ __launch_bounds__(128) void k_bnstat(const float* __restrict__ out2,
                                                float* __restrict__ bnsum,
                                                float* __restrict__ bnsq, int n) {
    int c = threadIdx.x;
    float s = 0.f, q = 0.f;
    for (int r = blockIdx.x; r < n; r += gridDim.x) {
        float v = out2[(size_t)r * 128 + c];
        s += v;
        q += v * v;
    }
    atomicAdd(&bnsum[c], s);
    atomicAdd(&bnsq[c], q);
}

__global__ __launch_bounds__(256) void k_final(const float* __restrict__ out2,
                                               const float* __restrict__ bnsum,
                                               const float* __restrict__ bnsq,
                                               const float* __restrict__ bng,
                                               const float* __restrict__ bnb,
                                               const float* __restrict__ lng,
                                               const float* __restrict__ lnb,
                                               float* __restrict__ out, int n) {
    int wid = (blockIdx.x * blockDim.x + threadIdx.x) >> 6;
    int lane = threadIdx.x & 63;
    if (wid >= n) return;
    int c0 = lane, c1 = lane + 64;
    float invn = 1.f / (float)n;
    float mu0 = bnsum[c0] * invn, mu1 = bnsum[c1] * invn;
    float v0 = bnsq[c0] * invn - mu0 * mu0;
    float v1 = bnsq[c1] * invn - mu1 * mu1;
    float r0 = rsqrtf(v0 + EPSV), r1 = rsqrtf(v1 + EPSV);
    float x0 = out2[(size_t)wid * 128 + c0];
    float x1 = out2[(size_t)wid * 128 + c1];
    float y0 = (x0 - mu0) * r0 * bng[c0] + bnb[c0];
    float y1 = (x1 - mu1) * r1 * bng[c1] + bnb[c1];
    float s = y0 + y1, q = y0 * y0 + y1 * y1;
#pragma unroll
    for (int o = 1; o < 64; o <<= 1) { s += __shfl_xor(s, o, 64); q += __shfl_xor(q, o, 64); }
    float mu = s * (1.f / 128.f);
    float var = q * (1.f / 128.f) - mu * mu;
    float rr = rsqrtf(var + EPSV);
    out[(size_t)wid * 128 + c0] = (y0 - mu) * rr * lng[c0] + lnb[c0];
    out[(size_t)wid * 128 + c1] = (y1 - mu) * rr * lng[c1] + lnb[c1];
}

// ---------------------------------------------------------------------------
extern "C" void kernel_launch(void* const* d_in, const int* in_sizes, int n_in,
                              void* d_out, int out_size, void* d_ws, size_t ws_size,
                              hipStream_t stream) {
    const float* x    = (const float*)d_in[0];
    const int*   ei   = (const int*)d_in[1];
    const float* W1   = (const float*)d_in[2];
    const float* ats1 = (const float*)d_in[3];
    const float* atd1 = (const float*)d_in[4];
    const float* b1   = (const float*)d_in[5];
    const float* W2   = (const float*)d_in[6];
    const float* ats2 = (const float*)d_in[7];
    const float* atd2 = (const float*)d_in[8];
    const float* b2   = (const float*)d_in[9];
    const float* bng  = (const float*)d_in[10];
    const float* bnb  = (const float*)d_in[11];
    const float* lng  = (const float*)d_in[12];
    const float* lnb  = (const float*)d_in[13];

    const int n = in_sizes[0] / NFEAT;   // 50000
    const int E = in_sizes[1] / 2;       // 800000
    const int tot = E + n;

    auto align = [](size_t v) { return (v + 255) & ~(size_t)255; };
    char* ws = (char*)d_ws;
    size_t off = 0;
    ushort_t* h1 = (ushort_t*)(ws + off); off += align((size_t)n * 256 * 2);
    float* out1 = (float*)(ws + off); off += align((size_t)n * 256 * 4);
    ushort_t* h2 = h1;
    float* out2 = out1;
    float* as1 = (float*)(ws + off); off += align((size_t)n * 8 * 4);
    float* ad1 = (float*)(ws + off); off += align((size_t)n * 8 * 4);
    float* as2 = (float*)(ws + off); off += align((size_t)n * 4);
    float* ad2 = (float*)(ws + off); off += align((size_t)n * 4);
    int* counts = (int*)(ws + off); off += align((size_t)n * 4);
    int* offs   = (int*)(ws + off); off += align((size_t)(n + 1) * 4);
    int* cursor = (int*)(ws + off); off += align((size_t)n * 4);
    int* esrc   = (int*)(ws + off); off += align((size_t)tot * 4);
    int* incl   = (int*)(ws + off); off += align((size_t)n * 4);
    int* bsum   = (int*)(ws + off); off += align(64 * 4);
    float* bnsum = (float*)(ws + off); off += align(128 * 4);
    float* bnsq  = (float*)(ws + off); off += align(128 * 4);
    ushort_t* Wh1 = (ushort_t*)(ws + off); off += align((size_t)256 * 256 * 2);
    ushort_t* Wl1 = (ushort_t*)(ws + off); off += align((size_t)256 * 256 * 2);
    ushort_t* Wh2 = (ushort_t*)(ws + off); off += align((size_t)256 * 128 * 2);
    ushort_t* Wl2 = (ushort_t*)(ws + off); off += align((size_t)256 * 128 * 2);

    hipMemsetAsync(counts, 0, (size_t)n * 4, stream);
    hipMemsetAsync(bnsum, 0, 128 * 4, stream);
    hipMemsetAsync(bnsq, 0, 128 * 4, stream);

    // W packing (tiny, overlaps CSR build)
    k_prepw<<<(256 * 256 + 255) / 256, 256, 0, stream>>>(W1, Wh1, Wl1, 256, 256);
    k_prepw<<<(256 * 128 + 255) / 256, 256, 0, stream>>>(W2, Wh2, Wl2, 256, 128);

    // CSR build
    k_count<<<(tot + 255) / 256, 256, 0, stream>>>(ei, counts, E, n);
    int nsb = (n + 1023) / 1024;
    k_scan1<<<nsb, 1024, 0, stream>>>(counts, incl, bsum, n);
    k_scan2<<<1, 64, 0, stream>>>(bsum, nsb);
    k_scan3<<<(n + 255) / 256, 256, 0, stream>>>(incl, bsum, counts, offs, cursor, n);
    k_fill<<<(tot + 255) / 256, 256, 0, stream>>>(ei, cursor, esrc, E, n);

    const int gx = (n + 127) / 128;
    // layer 1
    k_mm<<<dim3(gx, 2), 256, 0, stream>>>(x, Wh1, Wl1, h1, n, 256);
    k_att1<<<(n + 3) / 4, 256, 0, stream>>>(h1, ats1, atd1, as1, ad1, n);
    k_agg1<<<(n + 3) / 4, 256, 0, stream>>>(h1, as1, ad1, offs, esrc, b1, out1, n, tot);

    // layer 2
    k_mm<<<dim3(gx, 1), 256, 0, stream>>>(out1, Wh2, Wl2, h2, n, 128);
    k_att2<<<(n + 3) / 4, 256, 0, stream>>>(h2, ats2, atd2, as2, ad2, n);
    k_agg2<<<(n + 3) / 4, 256, 0, stream>>>(h2, as2, ad2, offs, esrc, b2, out2, n, tot);

    // BN + LN
    k_bnstat<<<512, 128, 0, stream>>>(out2, bnsum, bnsq, n);
    k_final<<<(n + 3) / 4, 256, 0, stream>>>(out2, bnsum, bnsq, bng, bnb, lng, lnb,
                                             (float*)d_out, n);
}

// Round 6
// 363.919 us; speedup vs baseline: 1.1057x; 1.1031x over previous
//
#include <hip/hip_runtime.h>
#include <cstdint>
#include <cstddef>

#define HEADS   8
#define NFEAT   256
#define NOUT    128
#define NEG     0.2f
#define EPSV    1e-5f

typedef unsigned short ushort_t;
typedef __attribute__((ext_vector_type(8))) short s8v;   // 8 bf16 = 4 VGPR
typedef __attribute__((ext_vector_type(4))) float f4v;   // MFMA accum

static __device__ __forceinline__ float lrelu(float x) { return x > 0.f ? x : NEG * x; }

static __device__ __forceinline__ float bf2f(ushort_t u) {
    union { unsigned int i; float f; } v; v.i = ((unsigned int)u) << 16; return v.f;
}
static __device__ __forceinline__ ushort_t f2bf(float f) {
    union { float f; unsigned int i; } v; v.f = f;
    unsigned int x = v.i;
    return (ushort_t)((x + 0x7fff + ((x >> 16) & 1)) >> 16);   // RNE
}
static __device__ __forceinline__ float bits2f(unsigned int u) {
    union { unsigned int i; float f; } v; v.i = u; return v.f;
}

// wave-local int64-vs-int32 detection (deterministic, identical in every wave)
static __device__ __forceinline__ int detect64(const int* __restrict__ ei, int E) {
    int lane = threadIdx.x & 63;
    long idx = 2L * ((long)lane * (E / 64)) + 1;
    int v = ei[idx];
    unsigned long long ball = __ballot(v == 0);
    return (ball == ~0ull) ? 1 : 0;
}

// ---------------------------------------------------------------------------
// CSR build
__global__ void k_count(const int* __restrict__ ei, int* __restrict__ counts,
                        int E, int n) {
    int is64 = detect64(ei, E);
    int i = blockIdx.x * blockDim.x + threadIdx.x;
    if (i < E) {
        int d = ei[(size_t)(E + i) << is64];
        atomicAdd(&counts[d], 1);
    } else if (i < E + n) {
        atomicAdd(&counts[i - E], 1);
    }
}

__global__ __launch_bounds__(1024) void k_scan1(const int* __restrict__ counts,
                                                int* __restrict__ incl,
                                                int* __restrict__ bsum, int n) {
    int t = threadIdx.x, i = blockIdx.x * 1024 + t;
    int lane = t & 63, w = t >> 6;
    int v = (i < n) ? counts[i] : 0;
    int sv = v;
#pragma unroll
    for (int o = 1; o < 64; o <<= 1) { int u = __shfl_up(sv, o, 64); if (lane >= o) sv += u; }
    __shared__ int wsum[16];
    if (lane == 63) wsum[w] = sv;
    __syncthreads();
    if (w == 0) {
        int bs = (lane < 16) ? wsum[lane] : 0;
#pragma unroll
        for (int o = 1; o < 16; o <<= 1) { int u = __shfl_up(bs, o, 64); if (lane >= o) bs += u; }
        if (lane < 16) wsum[lane] = bs;
    }
    __syncthreads();
    int pre = (w > 0) ? wsum[w - 1] : 0;
    sv += pre;
    if (i < n) incl[i] = sv;
    if (t == 1023) bsum[blockIdx.x] = sv;
}

__global__ void k_scan2(int* __restrict__ bsum, int nb) {
    int lane = threadIdx.x;
    int v = (lane < nb) ? bsum[lane] : 0;
    int sv = v;
#pragma unroll
    for (int o = 1; o < 64; o <<= 1) { int u = __shfl_up(sv, o, 64); if (lane >= o) sv += u; }
    if (lane < nb) bsum[lane] = sv - v;
}

__global__ void k_scan3(const int* __restrict__ incl, const int* __restrict__ bsum,
                        const int* __restrict__ counts,
                        int* __restrict__ offs, int* __restrict__ cursor, int n) {
    int i = blockIdx.x * blockDim.x + threadIdx.x;
    if (i < n) {
        int v = incl[i] + bsum[i >> 10];
        offs[i + 1] = v;
        cursor[i] = v - counts[i];
    }
    if (i == 0) offs[0] = 0;
}

__global__ void k_fill(const int* __restrict__ ei, int* __restrict__ cursor,
                       int* __restrict__ esrc, int E, int n) {
    int is64 = detect64(ei, E);
    int i = blockIdx.x * blockDim.x + threadIdx.x;
    if (i >= E + n) return;
    int s, d;
    if (i < E) { s = ei[(size_t)i << is64]; d = ei[(size_t)(E + i) << is64]; }
    else       { s = i - E; d = s; }
    int p = atomicAdd(&cursor[d], 1);
    esrc[p] = s;
}

// ---------------------------------------------------------------------------
// pack W1 and W2 f32 -> hi/lo bf16 in per-lane B-fragment order (one launch)
__global__ void k_prepw(const float* __restrict__ W1, const float* __restrict__ W2,
                        ushort_t* __restrict__ Wh1, ushort_t* __restrict__ Wl1,
                        ushort_t* __restrict__ Wh2, ushort_t* __restrict__ Wl2) {
    int gid = blockIdx.x * 256 + threadIdx.x;
    const float* W; ushort_t* Wh; ushort_t* Wl; int M;
    if (gid < 256 * 256) { W = W1; Wh = Wh1; Wl = Wl1; M = 256; }
    else { gid -= 256 * 256; if (gid >= 256 * 128) return; W = W2; Wh = Wh2; Wl = Wl2; M = 128; }
    int k = gid / M, nn = gid - k * M;
    int ntile = nn >> 4, j = nn & 15, kc = k >> 3, e = k & 7;
    int p = ((ntile * 32 + kc) * 16 + j) * 8 + e;     // K=256 -> K/8=32
    float v = W[(size_t)k * M + nn];
    ushort_t hi = f2bf(v);
    float r = v - bf2f(hi);
    Wh[p] = hi;
    Wl[p] = f2bf(r);
}

// ---------------------------------------------------------------------------
// MFMA GEMM, bf16x3 split precision: C[n,Mout](bf16) = A[n,256](f32) @ W
__global__ __launch_bounds__(256) void k_mm(const float* __restrict__ A,
                                            const ushort_t* __restrict__ Wh,
                                            const ushort_t* __restrict__ Wl,
                                            ushort_t* __restrict__ C, int n, int Mout) {
    __shared__ ushort_t Ah[128][40];
    __shared__ ushort_t Al[128][40];
    const int t = threadIdx.x;
    const int lane = t & 63, w = t >> 6;
    const int wr = w >> 1, wc = w & 1;
    const int r0 = blockIdx.x * 128;
    const int srow = t >> 1;
    const int kh = (t & 1) * 16;
    const int arow = r0 + srow;
    const bool rowok = arow < n;

    f4v acc[4][4];
#pragma unroll
    for (int a = 0; a < 4; ++a)
#pragma unroll
        for (int b = 0; b < 4; ++b) { f4v z = {0.f, 0.f, 0.f, 0.f}; acc[a][b] = z; }

    float pre[16];
    const float* abase = &A[(size_t)arow * 256 + kh];
#pragma unroll
    for (int q = 0; q < 4; ++q) {
        float4 v = rowok ? *reinterpret_cast<const float4*>(abase + q * 4)
                         : float4{0.f, 0.f, 0.f, 0.f};
        pre[q * 4 + 0] = v.x; pre[q * 4 + 1] = v.y;
        pre[q * 4 + 2] = v.z; pre[q * 4 + 3] = v.w;
    }

    const int lj = lane & 15, lk = lane >> 4;

    for (int kb = 0; kb < 256; kb += 32) {
        __syncthreads();
#pragma unroll
        for (int q = 0; q < 2; ++q) {
            unsigned int hw[4], lw[4];
#pragma unroll
            for (int p = 0; p < 4; ++p) {
                float v0 = pre[q * 8 + p * 2], v1 = pre[q * 8 + p * 2 + 1];
                ushort_t h0 = f2bf(v0), h1 = f2bf(v1);
                ushort_t l0 = f2bf(v0 - bf2f(h0)), l1 = f2bf(v1 - bf2f(h1));
                hw[p] = (unsigned int)h0 | ((unsigned int)h1 << 16);
                lw[p] = (unsigned int)l0 | ((unsigned int)l1 << 16);
            }
            uint4 hv = {hw[0], hw[1], hw[2], hw[3]};
            uint4 lv = {lw[0], lw[1], lw[2], lw[3]};
            *reinterpret_cast<uint4*>(&Ah[srow][kh + q * 8]) = hv;
            *reinterpret_cast<uint4*>(&Al[srow][kh + q * 8]) = lv;
        }
        __syncthreads();
        if (kb < 224) {
            const float* ap = abase + kb + 32;
#pragma unroll
            for (int q = 0; q < 4; ++q) {
                float4 v = rowok ? *reinterpret_cast<const float4*>(ap + q * 4)
                                 : float4{0.f, 0.f, 0.f, 0.f};
                pre[q * 4 + 0] = v.x; pre[q * 4 + 1] = v.y;
                pre[q * 4 + 2] = v.z; pre[q * 4 + 3] = v.w;
            }
        }
        const int kc0 = kb >> 3;
        s8v ah[4], al[4];
#pragma unroll
        for (int mf = 0; mf < 4; ++mf) {
            ah[mf] = *reinterpret_cast<const s8v*>(&Ah[wr * 64 + mf * 16 + lj][lk * 8]);
            al[mf] = *reinterpret_cast<const s8v*>(&Al[wr * 64 + mf * 16 + lj][lk * 8]);
        }
#pragma unroll
        for (int nf = 0; nf < 4; ++nf) {
            int ntile = blockIdx.y * 8 + wc * 4 + nf;
            size_t boff = ((size_t)(ntile * 32 + kc0 + lk) * 16 + lj) * 8;
            s8v bh = *reinterpret_cast<const s8v*>(&Wh[boff]);
            s8v bl = *reinterpret_cast<const s8v*>(&Wl[boff]);
#pragma unroll
            for (int mf = 0; mf < 4; ++mf) {
                acc[mf][nf] = __builtin_amdgcn_mfma_f32_16x16x32_bf16(ah[mf], bh, acc[mf][nf], 0, 0, 0);
                acc[mf][nf] = __builtin_amdgcn_mfma_f32_16x16x32_bf16(ah[mf], bl, acc[mf][nf], 0, 0, 0);
                acc[mf][nf] = __builtin_amdgcn_mfma_f32_16x16x32_bf16(al[mf], bh, acc[mf][nf], 0, 0, 0);
            }
        }
    }

#pragma unroll
    for (int mf = 0; mf < 4; ++mf) {
        int rr = r0 + wr * 64 + mf * 16 + lk * 4;
#pragma unroll
        for (int nf = 0; nf < 4; ++nf) {
            int cc = blockIdx.y * 128 + wc * 64 + nf * 16 + lj;
#pragma unroll
            for (int r = 0; r < 4; ++r) {
                if (rr + r < n) C[(size_t)(rr + r) * Mout + cc] = f2bf(acc[mf][nf][r]);
            }
        }
    }
}

// ---------------------------------------------------------------------------
// attention logit dot products
__global__ __launch_bounds__(256) void k_att1(const ushort_t* __restrict__ h1,
                                              const float* __restrict__ att_s,
                                              const float* __restrict__ att_d,
                                              float* __restrict__ as1,
                                              float* __restrict__ ad1, int n) {
    int wid = (blockIdx.x * blockDim.x + threadIdx.x) >> 6;
    int lane = threadIdx.x & 63;
    if (wid >= n) return;
    int head = lane >> 3;
    int co = (lane & 7) * 4;
    ushort4 hu = *reinterpret_cast<const ushort4*>(&h1[(size_t)wid * 256 + head * 32 + co]);
    float4 vs = *reinterpret_cast<const float4*>(&att_s[head * 32 + co]);
    float4 vd = *reinterpret_cast<const float4*>(&att_d[head * 32 + co]);
    float hx = bf2f(hu.x), hy = bf2f(hu.y), hz = bf2f(hu.z), hw = bf2f(hu.w);
    float ss = hx * vs.x + hy * vs.y + hz * vs.z + hw * vs.w;
    float sd = hx * vd.x + hy * vd.y + hz * vd.z + hw * vd.w;
#pragma unroll
    for (int o = 1; o < 8; o <<= 1) { ss += __shfl_xor(ss, o, 64); sd += __shfl_xor(sd, o, 64); }
    if ((lane & 7) == 0) {
        as1[(size_t)wid * 8 + head] = ss;
        ad1[(size_t)wid * 8 + head] = sd;
    }
}

__global__ __launch_bounds__(256) void k_att2(const ushort_t* __restrict__ h2,
                                              const float* __restrict__ att_s,
                                              const float* __restrict__ att_d,
                                              float* __restrict__ as2,
                                              float* __restrict__ ad2, int n) {
    int wid = (blockIdx.x * blockDim.x + threadIdx.x) >> 6;
    int lane = threadIdx.x & 63;
    if (wid >= n) return;
    ushort2 hu = *reinterpret_cast<const ushort2*>(&h2[(size_t)wid * 128 + lane * 2]);
    float2 vs = *reinterpret_cast<const float2*>(&att_s[lane * 2]);
    float2 vd = *reinterpret_cast<const float2*>(&att_d[lane * 2]);
    float hx = bf2f(hu.x), hy = bf2f(hu.y);
    float ss = hx * vs.x + hy * vs.y;
    float sd = hx * vd.x + hy * vd.y;
#pragma unroll
    for (int o = 1; o < 64; o <<= 1) { ss += __shfl_xor(ss, o, 64); sd += __shfl_xor(sd, o, 64); }
    if (lane == 0) { as2[wid] = ss; ad2[wid] = sd; }
}

// ---------------------------------------------------------------------------
// layer-1 aggregation v4: half-wave per edge. Lane owns 8 channels
// ((lane&31)*8); halves (lane>>5) process even/odd edges concurrently with
// 16B row loads. Exact softmax max computed full-wave, attention values
// shfl'd from phase-A registers (static indices only).
__global__ __launch_bounds__(256) void k_agg1(const ushort_t* __restrict__ h1,
                                              const float* __restrict__ as1,
                                              const float* __restrict__ ad1,
                                              const int* __restrict__ offs,
                                              const int* __restrict__ esrc,
                                              const float* __restrict__ b1,
                                              float* __restrict__ out1, int n, int tot) {
    int wid = (blockIdx.x * blockDim.x + threadIdx.x) >> 6;
    int lane = threadIdx.x & 63;
    if (wid >= n) return;
    int e0 = offs[wid], e1 = offs[wid + 1];
    int deg = e1 - e0;

    if (deg <= 64) {
        const int l = lane & 31;          // channel-group lane
        const int h = lane >> 5;          // half: edge parity
        const int hd = l >> 2;            // head owning channels l*8..l*8+7
        const int cb = l * 8;
        float adn = ad1[(size_t)wid * 8 + hd];

        int ei_idx = e0 + lane;
        int es = esrc[ei_idx < tot ? ei_idx : (tot - 1)];

        // phase A: lane = headA*8+g holds a[k] = as1[edge g+8k, headA]
        const int headA = lane >> 3, g = lane & 7;
        float adnA = ad1[(size_t)wid * 8 + headA];
        float a[8];
#pragma unroll
        for (int k = 0; k < 8; ++k) {
            int i = g + 8 * k;
            int s = __shfl(es, i, 64);
            a[k] = (i < deg) ? as1[(size_t)s * 8 + headA] : -1e30f;
        }
        float mx = a[0];
#pragma unroll
        for (int k = 1; k < 8; ++k) mx = fmaxf(mx, a[k]);
#pragma unroll
        for (int o = 1; o < 8; o <<= 1) mx = fmaxf(mx, __shfl_xor(mx, o, 64));
        (void)adnA;
        // broadcast per-head max to the lanes that own that head's channels
        float m = lrelu(__shfl(mx, hd * 8, 64) + adn);

        // phase B: half h handles edges i = 8u + 2v + h (k-index = u, static)
        float d = 0.f;
        float ac0 = 0.f, ac1 = 0.f, ac2 = 0.f, ac3 = 0.f;
        float ac4 = 0.f, ac5 = 0.f, ac6 = 0.f, ac7 = 0.f;
#pragma unroll
        for (int u = 0; u < 8; ++u) {
            if (8 * u < deg) {
#pragma unroll
                for (int v = 0; v < 4; ++v) {
                    int i = 8 * u + 2 * v + h;
                    int s = __shfl(es, i, 64);
                    float av = __shfl(a[u], hd * 8 + 2 * v + h, 64);
                    if (i < deg) {
                        float p = __expf(lrelu(av + adn) - m);
                        uint4 hv = *reinterpret_cast<const uint4*>(&h1[(size_t)s * 256 + cb]);
                        d += p;
                        ac0 += p * bits2f(hv.x << 16);
                        ac1 += p * bits2f(hv.x & 0xffff0000u);
                        ac2 += p * bits2f(hv.y << 16);
                        ac3 += p * bits2f(hv.y & 0xffff0000u);
                        ac4 += p * bits2f(hv.z << 16);
                        ac5 += p * bits2f(hv.z & 0xffff0000u);
                        ac6 += p * bits2f(hv.w << 16);
                        ac7 += p * bits2f(hv.w & 0xffff0000u);
                    }
                }
            }
        }
        // merge halves
        d   += __shfl_xor(d, 32, 64);
        ac0 += __shfl_xor(ac0, 32, 64); ac1 += __shfl_xor(ac1, 32, 64);
        ac2 += __shfl_xor(ac2, 32, 64); ac3 += __shfl_xor(ac3, 32, 64);
        ac4 += __shfl_xor(ac4, 32, 64); ac5 += __shfl_xor(ac5, 32, 64);
        ac6 += __shfl_xor(ac6, 32, 64); ac7 += __shfl_xor(ac7, 32, 64);
        if (lane < 32) {
            float inv = 1.f / (d + 1e-16f);
            float4 b0 = *reinterpret_cast<const float4*>(&b1[cb]);
            float4 b4 = *reinterpret_cast<const float4*>(&b1[cb + 4]);
            float4 o0, o1;
            o0.x = fmaxf(ac0 * inv + b0.x, 0.f);
            o0.y = fmaxf(ac1 * inv + b0.y, 0.f);
            o0.z = fmaxf(ac2 * inv + b0.z, 0.f);
            o0.w = fmaxf(ac3 * inv + b0.w, 0.f);
            o1.x = fmaxf(ac4 * inv + b4.x, 0.f);
            o1.y = fmaxf(ac5 * inv + b4.y, 0.f);
            o1.z = fmaxf(ac6 * inv + b4.z, 0.f);
            o1.w = fmaxf(ac7 * inv + b4.w, 0.f);
            *reinterpret_cast<float4*>(&out1[(size_t)wid * 256 + cb]) = o0;
            *reinterpret_cast<float4*>(&out1[(size_t)wid * 256 + cb + 4]) = o1;
        }
    } else {
        // rare slow path (old layout: lane owns 4 channels)
        int head = lane >> 3;
        int g = lane & 7;
        int cb = lane * 4;
        float adn = ad1[(size_t)wid * 8 + head];
        float mx = -1e30f;
        for (int e = e0 + g; e < e1; e += 8)
            mx = fmaxf(mx, as1[(size_t)esrc[e] * 8 + head]);
#pragma unroll
        for (int o = 1; o < 8; o <<= 1) mx = fmaxf(mx, __shfl_xor(mx, o, 64));
        float m = lrelu(mx + adn);
        float d = 0.f, ax = 0.f, ay = 0.f, az = 0.f, aw = 0.f;
        for (int e = e0; e < e1; ++e) {
            int s = esrc[e];
            float p = __expf(lrelu(as1[(size_t)s * 8 + head] + adn) - m);
            ushort4 hv = *reinterpret_cast<const ushort4*>(&h1[(size_t)s * 256 + cb]);
            d += p;
            ax += p * bf2f(hv.x);
            ay += p * bf2f(hv.y);
            az += p * bf2f(hv.z);
            aw += p * bf2f(hv.w);
        }
        float inv = 1.f / (d + 1e-16f);
        float4 bb = *reinterpret_cast<const float4*>(&b1[cb]);
        float4 o;
        o.x = fmaxf(ax * inv + bb.x, 0.f);
        o.y = fmaxf(ay * inv + bb.y, 0.f);
        o.z = fmaxf(az * inv + bb.z, 0.f);
        o.w = fmaxf(aw * inv + bb.w, 0.f);
        *reinterpret_cast<float4*>(&out1[(size_t)wid * 256 + cb]) = o;
    }
}

// layer-2 aggregation v4: quarter-wave per edge. Lane owns 8 of 128 channels;
// quarters (lane>>4) process edges i = 16u+4v+q; 16B row loads.
__global__ __launch_bounds__(256) void k_agg2(const ushort_t* __restrict__ h2,
                                              const float* __restrict__ as2,
                                              const float* __restrict__ ad2,
                                              const int* __restrict__ offs,
                                              const int* __restrict__ esrc,
                                              const float* __restrict__ b2,
                                              float* __restrict__ out2, int n, int tot) {
    int wid = (blockIdx.x * blockDim.x + threadIdx.x) >> 6;
    int lane = threadIdx.x & 63;
    if (wid >= n) return;
    float adn = ad2[wid];
    int e0 = offs[wid], e1 = offs[wid + 1];
    int deg = e1 - e0;

    if (deg <= 64) {
        const int l = lane & 15;
        const int q = lane >> 4;
        const int cb = l * 8;

        int ei_idx = e0 + lane;
        int es = esrc[ei_idx < tot ? ei_idx : (tot - 1)];
        float av0 = (lane < deg) ? as2[es] : -1e30f;
        float mx = av0;
#pragma unroll
        for (int o = 1; o < 64; o <<= 1) mx = fmaxf(mx, __shfl_xor(mx, o, 64));
        float m = lrelu(mx + adn);

        float d = 0.f;
        float ac0 = 0.f, ac1 = 0.f, ac2 = 0.f, ac3 = 0.f;
        float ac4 = 0.f, ac5 = 0.f, ac6 = 0.f, ac7 = 0.f;
#pragma unroll
        for (int u = 0; u < 4; ++u) {
            if (16 * u < deg) {
#pragma unroll
                for (int v = 0; v < 4; ++v) {
                    int i = 16 * u + 4 * v + q;
                    int s = __shfl(es, i, 64);
                    float av = __shfl(av0, i, 64);
                    if (i < deg) {
                        float p = __expf(lrelu(av + adn) - m);
                        uint4 hv = *reinterpret_cast<const uint4*>(&h2[(size_t)s * 128 + cb]);
                        d += p;
                        ac0 += p * bits2f(hv.x << 16);
                        ac1 += p * bits2f(hv.x & 0xffff0000u);
                        ac2 += p * bits2f(hv.y << 16);
                        ac3 += p * bits2f(hv.y & 0xffff0000u);
                        ac4 += p * bits2f(hv.z << 16);
                        ac5 += p * bits2f(hv.z & 0xffff0000u);
                        ac6 += p * bits2f(hv.w << 16);
                        ac7 += p * bits2f(hv.w & 0xffff0000u);
                    }
                }
            }
        }
        // merge quarters (butterfly over 16 and 32)
#pragma unroll
        for (int o = 16; o <= 32; o <<= 1) {
            d   += __shfl_xor(d, o, 64);
            ac0 += __shfl_xor(ac0, o, 64); ac1 += __shfl_xor(ac1, o, 64);
            ac2 += __shfl_xor(ac2, o, 64); ac3 += __shfl_xor(ac3, o, 64);
            ac4 += __shfl_xor(ac4, o, 64); ac5 += __shfl_xor(ac5, o, 64);
            ac6 += __shfl_xor(ac6, o, 64); ac7 += __shfl_xor(ac7, o, 64);
        }
        if (lane < 16) {
            float inv = 1.f / (d + 1e-16f);
            float4 b0 = *reinterpret_cast<const float4*>(&b2[cb]);
            float4 b4 = *reinterpret_cast<const float4*>(&b2[cb + 4]);
            float4 o0, o1;
            o0.x = fmaxf(ac0 * inv + b0.x, 0.f);
            o0.y = fmaxf(ac1 * inv + b0.y, 0.f);
            o0.z = fmaxf(ac2 * inv + b0.z, 0.f);
            o0.w = fmaxf(ac3 * inv + b0.w, 0.f);
            o1.x = fmaxf(ac4 * inv + b4.x, 0.f);
            o1.y = fmaxf(ac5 * inv + b4.y, 0.f);
            o1.z = fmaxf(ac6 * inv + b4.z, 0.f);
            o1.w = fmaxf(ac7 * inv + b4.w, 0.f);
            *reinterpret_cast<float4*>(&out2[(size_t)wid * 128 + cb]) = o0;
            *reinterpret_cast<float4*>(&out2[(size_t)wid * 128 + cb + 4]) = o1;
        }
    } else {
        int cb = lane * 2;
        float mx = -1e30f;
        for (int e = e0 + lane; e < e1; e += 64)
            mx = fmaxf(mx, as2[esrc[e]]);
#pragma unroll
        for (int o = 1; o < 64; o <<= 1) mx = fmaxf(mx, __shfl_xor(mx, o, 64));
        float m = lrelu(mx + adn);
        float d = 0.f, ax = 0.f, ay = 0.f;
        for (int e = e0; e < e1; ++e) {
            int s = esrc[e];
            float p = __expf(lrelu(as2[s] + adn) - m);
            ushort2 hv = *reinterpret_cast<const ushort2*>(&h2[(size_t)s * 128 + cb]);
            d += p;
            ax += p * bf2f(hv.x);
            ay += p * bf2f(hv.y);
        }
        float inv = 1.f / (d + 1e-16f);
        float o0 = fmaxf(ax * inv + b2[cb], 0.f);
        float o1 = fmaxf(ay * inv + b2[cb + 1], 0.f);
        float2 o = {o0, o1};
        *reinterpret_cast<float2*>(&out2[(size_t)wid * 128 + cb]) = o;
    }
}

// ---------------------------------------------------------------------------
__global__ __launch_bounds__(128) void k_bnstat(const float* __restrict__ out2,
                                                float* __restrict__ bnsum,
                                                float* __restrict__ bnsq, int n) {
    int c = threadIdx.x;
    float s = 0.f, q = 0.f;
    for (int r = blockIdx.x; r < n; r += gridDim.x) {
        float v = out2[(size_t)r * 128 + c];
        s += v;
        q += v * v;
    }
    atomicAdd(&bnsum[c], s);
    atomicAdd(&bnsq[c], q);
}

__global__ __launch_bounds__(256) void k_final(const float* __restrict__ out2,
                                               const float* __restrict__ bnsum,
                                               const float* __restrict__ bnsq,
                                               const float* __restrict__ bng,
                                               const float* __restrict__ bnb,
                                               const float* __restrict__ lng,
                                               const float* __restrict__ lnb,
                                               float* __restrict__ out, int n) {
    int wid = (blockIdx.x * blockDim.x + threadIdx.x) >> 6;
    int lane = threadIdx.x & 63;
    if (wid >= n) return;
    int c0 = lane, c1 = lane + 64;
    float invn = 1.f / (float)n;
    float mu0 = bnsum[c0] * invn, mu1 = bnsum[c1] * invn;
    float v0 = bnsq[c0] * invn - mu0 * mu0;
    float v1 = bnsq[c1] * invn - mu1 * mu1;
    float r0 = rsqrtf(v0 + EPSV), r1 = rsqrtf(v1 + EPSV);
    float x0 = out2[(size_t)wid * 128 + c0];
    float x1 = out2[(size_t)wid * 128 + c1];
    float y0 = (x0 - mu0) * r0 * bng[c0] + bnb[c0];
    float y1 = (x1 - mu1) * r1 * bng[c1] + bnb[c1];
    float s = y0 + y1, q = y0 * y0 + y1 * y1;
#pragma unroll
    for (int o = 1; o < 64; o <<= 1) { s += __shfl_xor(s, o, 64); q += __shfl_xor(q, o, 64); }
    float mu = s * (1.f / 128.f);
    float var = q * (1.f / 128.f) - mu * mu;
    float rr = rsqrtf(var + EPSV);
    out[(size_t)wid * 128 + c0] = (y0 - mu) * rr * lng[c0] + lnb[c0];
    out[(size_t)wid * 128 + c1] = (y1 - mu) * rr * lng[c1] + lnb[c1];
}

// ---------------------------------------------------------------------------
extern "C" void kernel_launch(void* const* d_in, const int* in_sizes, int n_in,
                              void* d_out, int out_size, void* d_ws, size_t ws_size,
                              hipStream_t stream) {
    const float* x    = (const float*)d_in[0];
    const int*   ei   = (const int*)d_in[1];
    const float* W1   = (const float*)d_in[2];
    const float* ats1 = (const float*)d_in[3];
    const float* atd1 = (const float*)d_in[4];
    const float* b1   = (const float*)d_in[5];
    const float* W2   = (const float*)d_in[6];
    const float* ats2 = (const float*)d_in[7];
    const float* atd2 = (const float*)d_in[8];
    const float* b2   = (const float*)d_in[9];
    const float* bng  = (const float*)d_in[10];
    const float* bnb  = (const float*)d_in[11];
    const float* lng  = (const float*)d_in[12];
    const float* lnb  = (const float*)d_in[13];

    const int n = in_sizes[0] / NFEAT;   // 50000
    const int E = in_sizes[1] / 2;       // 800000
    const int tot = E + n;

    auto align = [](size_t v) { return (v + 255) & ~(size_t)255; };
    char* ws = (char*)d_ws;
    size_t off = 0;
    ushort_t* h1 = (ushort_t*)(ws + off); off += align((size_t)n * 256 * 2);
    float* out1 = (float*)(ws + off); off += align((size_t)n * 256 * 4);
    ushort_t* h2 = h1;
    float* out2 = out1;
    float* as1 = (float*)(ws + off); off += align((size_t)n * 8 * 4);
    float* ad1 = (float*)(ws + off); off += align((size_t)n * 8 * 4);
    float* as2 = (float*)(ws + off); off += align((size_t)n * 4);
    float* ad2 = (float*)(ws + off); off += align((size_t)n * 4);
    int* counts = (int*)(ws + off); off += align((size_t)n * 4);
    int* offs   = (int*)(ws + off); off += align((size_t)(n + 1) * 4);
    int* cursor = (int*)(ws + off); off += align((size_t)n * 4);
    int* esrc   = (int*)(ws + off); off += align((size_t)tot * 4);
    int* incl   = (int*)(ws + off); off += align((size_t)n * 4);
    int* bsum   = (int*)(ws + off); off += align(64 * 4);
    float* bnsum = (float*)(ws + off); off += align(256 * 4);   // bnsum[128] + bnsq[128]
    float* bnsq  = bnsum + 128;
    ushort_t* Wh1 = (ushort_t*)(ws + off); off += align((size_t)256 * 256 * 2);
    ushort_t* Wl1 = (ushort_t*)(ws + off); off += align((size_t)256 * 256 * 2);
    ushort_t* Wh2 = (ushort_t*)(ws + off); off += align((size_t)256 * 128 * 2);
    ushort_t* Wl2 = (ushort_t*)(ws + off); off += align((size_t)256 * 128 * 2);

    hipMemsetAsync(counts, 0, (size_t)n * 4, stream);
    hipMemsetAsync(bnsum, 0, 256 * 4, stream);

    // W packing (tiny, overlaps CSR build)
    k_prepw<<<(256 * 256 + 256 * 128 + 255) / 256, 256, 0, stream>>>(W1, W2, Wh1, Wl1, Wh2, Wl2);

    // CSR build
    k_count<<<(tot + 255) / 256, 256, 0, stream>>>(ei, counts, E, n);
    int nsb = (n + 1023) / 1024;
    k_scan1<<<nsb, 1024, 0, stream>>>(counts, incl, bsum, n);
    k_scan2<<<1, 64, 0, stream>>>(bsum, nsb);
    k_scan3<<<(n + 255) / 256, 256, 0, stream>>>(incl, bsum, counts, offs, cursor, n);
    k_fill<<<(tot + 255) / 256, 256, 0, stream>>>(ei, cursor, esrc, E, n);

    const int gx = (n + 127) / 128;
    // layer 1
    k_mm<<<dim3(gx, 2), 256, 0, stream>>>(x, Wh1, Wl1, h1, n, 256);
    k_att1<<<(n + 3) / 4, 256, 0, stream>>>(h1, ats1, atd1, as1, ad1, n);
    k_agg1<<<(n + 3) / 4, 256, 0, stream>>>(h1, as1, ad1, offs, esrc, b1, out1, n, tot);

    // layer 2
    k_mm<<<dim3(gx, 1), 256, 0, stream>>>(out1, Wh2, Wl2, h2, n, 128);
    k_att2<<<(n + 3) / 4, 256, 0, stream>>>(h2, ats2, atd2, as2, ad2, n);
    k_agg2<<<(n + 3) / 4, 256, 0, stream>>>(h2, as2, ad2, offs, esrc, b2, out2, n, tot);

    // BN + LN
    k_bnstat<<<512, 128, 0, stream>>>(out2, bnsum, bnsq, n);
    k_final<<<(n + 3) / 4, 256, 0, stream>>>(out2, bnsum, bnsq, bng, bnb, lng, lnb,
                                             (float*)d_out, n);
}

// Round 7
// 354.375 us; speedup vs baseline: 1.1355x; 1.0269x over previous
//
#include <hip/hip_runtime.h>
#include <cstdint>
#include <cstddef>

#define HEADS   8
#define NFEAT   256
#define NOUT    128
#define NEG     0.2f
#define EPSV    1e-5f

typedef unsigned short ushort_t;
typedef __attribute__((ext_vector_type(8))) short s8v;   // 8 bf16 = 4 VGPR
typedef __attribute__((ext_vector_type(4))) float f4v;   // MFMA accum

static __device__ __forceinline__ float lrelu(float x) { return x > 0.f ? x : NEG * x; }

static __device__ __forceinline__ float bf2f(ushort_t u) {
    union { unsigned int i; float f; } v; v.i = ((unsigned int)u) << 16; return v.f;
}
static __device__ __forceinline__ ushort_t f2bf(float f) {
    union { float f; unsigned int i; } v; v.f = f;
    unsigned int x = v.i;
    return (ushort_t)((x + 0x7fff + ((x >> 16) & 1)) >> 16);   // RNE
}
static __device__ __forceinline__ float bits2f(unsigned int u) {
    union { unsigned int i; float f; } v; v.i = u; return v.f;
}
static __device__ __forceinline__ unsigned int f2bits(float f) {
    union { float f; unsigned int i; } v; v.f = f; return v.i;
}

// wave-local int64-vs-int32 detection (deterministic, identical in every wave)
static __device__ __forceinline__ int detect64(const int* __restrict__ ei, int E) {
    int lane = threadIdx.x & 63;
    long idx = 2L * ((long)lane * (E / 64)) + 1;
    int v = ei[idx];
    unsigned long long ball = __ballot(v == 0);
    return (ball == ~0ull) ? 1 : 0;
}

// ---------------------------------------------------------------------------
// CSR build
__global__ void k_count(const int* __restrict__ ei, int* __restrict__ counts,
                        int E, int n) {
    int is64 = detect64(ei, E);
    int i = blockIdx.x * blockDim.x + threadIdx.x;
    if (i < E) {
        int d = ei[(size_t)(E + i) << is64];
        atomicAdd(&counts[d], 1);
    } else if (i < E + n) {
        atomicAdd(&counts[i - E], 1);
    }
}

__global__ __launch_bounds__(1024) void k_scan1(const int* __restrict__ counts,
                                                int* __restrict__ incl,
                                                int* __restrict__ bsum, int n) {
    int t = threadIdx.x, i = blockIdx.x * 1024 + t;
    int lane = t & 63, w = t >> 6;
    int v = (i < n) ? counts[i] : 0;
    int sv = v;
#pragma unroll
    for (int o = 1; o < 64; o <<= 1) { int u = __shfl_up(sv, o, 64); if (lane >= o) sv += u; }
    __shared__ int wsum[16];
    if (lane == 63) wsum[w] = sv;
    __syncthreads();
    if (w == 0) {
        int bs = (lane < 16) ? wsum[lane] : 0;
#pragma unroll
        for (int o = 1; o < 16; o <<= 1) { int u = __shfl_up(bs, o, 64); if (lane >= o) bs += u; }
        if (lane < 16) wsum[lane] = bs;
    }
    __syncthreads();
    int pre = (w > 0) ? wsum[w - 1] : 0;
    sv += pre;
    if (i < n) incl[i] = sv;
    if (t == 1023) bsum[blockIdx.x] = sv;   // raw block total
}

// scan3 with folded block-sum prefix (bsum holds raw totals; chunk<=49)
__global__ void k_scan3(const int* __restrict__ incl, const int* __restrict__ bsum,
                        const int* __restrict__ counts,
                        int* __restrict__ offs, int* __restrict__ cursor, int n) {
    __shared__ int pre_s;
    int chunk = blockIdx.x >> 2;            // 256-thr blocks, scan1 blocks = 1024
    if (threadIdx.x == 0) {
        int s = 0;
        for (int j = 0; j < chunk; ++j) s += bsum[j];
        pre_s = s;
    }
    __syncthreads();
    int i = blockIdx.x * 256 + threadIdx.x;
    if (i < n) {
        int v = incl[i] + pre_s;
        offs[i + 1] = v;
        cursor[i] = v - counts[i];
    }
    if (i == 0) offs[0] = 0;
}

__global__ void k_fill(const int* __restrict__ ei, int* __restrict__ cursor,
                       int* __restrict__ esrc, int E, int n) {
    int is64 = detect64(ei, E);
    int i = blockIdx.x * blockDim.x + threadIdx.x;
    if (i >= E + n) return;
    int s, d;
    if (i < E) { s = ei[(size_t)i << is64]; d = ei[(size_t)(E + i) << is64]; }
    else       { s = i - E; d = s; }
    int p = atomicAdd(&cursor[d], 1);
    esrc[p] = s;
}

// ---------------------------------------------------------------------------
// pack W1 and W2 f32 -> hi/lo bf16 in per-lane B-fragment order (one launch)
__global__ void k_prepw(const float* __restrict__ W1, const float* __restrict__ W2,
                        ushort_t* __restrict__ Wh1, ushort_t* __restrict__ Wl1,
                        ushort_t* __restrict__ Wh2, ushort_t* __restrict__ Wl2) {
    int gid = blockIdx.x * 256 + threadIdx.x;
    const float* W; ushort_t* Wh; ushort_t* Wl; int M;
    if (gid < 256 * 256) { W = W1; Wh = Wh1; Wl = Wl1; M = 256; }
    else { gid -= 256 * 256; if (gid >= 256 * 128) return; W = W2; Wh = Wh2; Wl = Wl2; M = 128; }
    int k = gid / M, nn = gid - k * M;
    int ntile = nn >> 4, j = nn & 15, kc = k >> 3, e = k & 7;
    int p = ((ntile * 32 + kc) * 16 + j) * 8 + e;     // K=256 -> K/8=32
    float v = W[(size_t)k * M + nn];
    ushort_t hi = f2bf(v);
    float r = v - bf2f(hi);
    Wh[p] = hi;
    Wl[p] = f2bf(r);
}

// ---------------------------------------------------------------------------
// MFMA GEMM, bf16x3 split precision: C[n,Mout](bf16) = A[n,256](f32) @ W
// A-split via truncation (exact subtraction; ~4.5 VALU/value vs ~15 RNE)
__global__ __launch_bounds__(256) void k_mm(const float* __restrict__ A,
                                            const ushort_t* __restrict__ Wh,
                                            const ushort_t* __restrict__ Wl,
                                            ushort_t* __restrict__ C, int n, int Mout) {
    __shared__ ushort_t Ah[128][40];
    __shared__ ushort_t Al[128][40];
    const int t = threadIdx.x;
    const int lane = t & 63, w = t >> 6;
    const int wr = w >> 1, wc = w & 1;
    const int r0 = blockIdx.x * 128;
    const int srow = t >> 1;
    const int kh = (t & 1) * 16;
    const int arow = r0 + srow;
    const bool rowok = arow < n;

    f4v acc[4][4];
#pragma unroll
    for (int a = 0; a < 4; ++a)
#pragma unroll
        for (int b = 0; b < 4; ++b) { f4v z = {0.f, 0.f, 0.f, 0.f}; acc[a][b] = z; }

    float pre[16];
    const float* abase = &A[(size_t)arow * 256 + kh];
#pragma unroll
    for (int q = 0; q < 4; ++q) {
        float4 v = rowok ? *reinterpret_cast<const float4*>(abase + q * 4)
                         : float4{0.f, 0.f, 0.f, 0.f};
        pre[q * 4 + 0] = v.x; pre[q * 4 + 1] = v.y;
        pre[q * 4 + 2] = v.z; pre[q * 4 + 3] = v.w;
    }

    const int lj = lane & 15, lk = lane >> 4;

    for (int kb = 0; kb < 256; kb += 32) {
        __syncthreads();
#pragma unroll
        for (int q = 0; q < 2; ++q) {
            unsigned int hw[4], lw[4];
#pragma unroll
            for (int p = 0; p < 4; ++p) {
                unsigned int x0 = f2bits(pre[q * 8 + p * 2]);
                unsigned int x1 = f2bits(pre[q * 8 + p * 2 + 1]);
                unsigned int h1b = x1 & 0xffff0000u;
                float lo0 = bits2f(f2bits(pre[q * 8 + p * 2])) - bits2f(x0 & 0xffff0000u);
                float lo1 = pre[q * 8 + p * 2 + 1] - bits2f(h1b);
                hw[p] = (x0 >> 16) | h1b;
                lw[p] = (f2bits(lo0) >> 16) | (f2bits(lo1) & 0xffff0000u);
            }
            uint4 hv = {hw[0], hw[1], hw[2], hw[3]};
            uint4 lv = {lw[0], lw[1], lw[2], lw[3]};
            *reinterpret_cast<uint4*>(&Ah[srow][kh + q * 8]) = hv;
            *reinterpret_cast<uint4*>(&Al[srow][kh + q * 8]) = lv;
        }
        __syncthreads();
        if (kb < 224) {
            const float* ap = abase + kb + 32;
#pragma unroll
            for (int q = 0; q < 4; ++q) {
                float4 v = rowok ? *reinterpret_cast<const float4*>(ap + q * 4)
                                 : float4{0.f, 0.f, 0.f, 0.f};
                pre[q * 4 + 0] = v.x; pre[q * 4 + 1] = v.y;
                pre[q * 4 + 2] = v.z; pre[q * 4 + 3] = v.w;
            }
        }
        const int kc0 = kb >> 3;
        s8v ah[4], al[4];
#pragma unroll
        for (int mf = 0; mf < 4; ++mf) {
            ah[mf] = *reinterpret_cast<const s8v*>(&Ah[wr * 64 + mf * 16 + lj][lk * 8]);
            al[mf] = *reinterpret_cast<const s8v*>(&Al[wr * 64 + mf * 16 + lj][lk * 8]);
        }
#pragma unroll
        for (int nf = 0; nf < 4; ++nf) {
            int ntile = blockIdx.y * 8 + wc * 4 + nf;
            size_t boff = ((size_t)(ntile * 32 + kc0 + lk) * 16 + lj) * 8;
            s8v bh = *reinterpret_cast<const s8v*>(&Wh[boff]);
            s8v bl = *reinterpret_cast<const s8v*>(&Wl[boff]);
#pragma unroll
            for (int mf = 0; mf < 4; ++mf) {
                acc[mf][nf] = __builtin_amdgcn_mfma_f32_16x16x32_bf16(ah[mf], bh, acc[mf][nf], 0, 0, 0);
                acc[mf][nf] = __builtin_amdgcn_mfma_f32_16x16x32_bf16(ah[mf], bl, acc[mf][nf], 0, 0, 0);
                acc[mf][nf] = __builtin_amdgcn_mfma_f32_16x16x32_bf16(al[mf], bh, acc[mf][nf], 0, 0, 0);
            }
        }
    }

#pragma unroll
    for (int mf = 0; mf < 4; ++mf) {
        int rr = r0 + wr * 64 + mf * 16 + lk * 4;
#pragma unroll
        for (int nf = 0; nf < 4; ++nf) {
            int cc = blockIdx.y * 128 + wc * 64 + nf * 16 + lj;
#pragma unroll
            for (int r = 0; r < 4; ++r) {
                if (rr + r < n) C[(size_t)(rr + r) * Mout + cc] = f2bf(acc[mf][nf][r]);
            }
        }
    }
}

// ---------------------------------------------------------------------------
// attention logit dot products
__global__ __launch_bounds__(256) void k_att1(const ushort_t* __restrict__ h1,
                                              const float* __restrict__ att_s,
                                              const float* __restrict__ att_d,
                                              float* __restrict__ as1,
                                              float* __restrict__ ad1, int n) {
    int wid = (blockIdx.x * blockDim.x + threadIdx.x) >> 6;
    int lane = threadIdx.x & 63;
    if (wid >= n) return;
    int head = lane >> 3;
    int co = (lane & 7) * 4;
    ushort4 hu = *reinterpret_cast<const ushort4*>(&h1[(size_t)wid * 256 + head * 32 + co]);
    float4 vs = *reinterpret_cast<const float4*>(&att_s[head * 32 + co]);
    float4 vd = *reinterpret_cast<const float4*>(&att_d[head * 32 + co]);
    float hx = bf2f(hu.x), hy = bf2f(hu.y), hz = bf2f(hu.z), hw = bf2f(hu.w);
    float ss = hx * vs.x + hy * vs.y + hz * vs.z + hw * vs.w;
    float sd = hx * vd.x + hy * vd.y + hz * vd.z + hw * vd.w;
#pragma unroll
    for (int o = 1; o < 8; o <<= 1) { ss += __shfl_xor(ss, o, 64); sd += __shfl_xor(sd, o, 64); }
    if ((lane & 7) == 0) {
        as1[(size_t)wid * 8 + head] = ss;
        ad1[(size_t)wid * 8 + head] = sd;
    }
}

__global__ __launch_bounds__(256) void k_att2(const ushort_t* __restrict__ h2,
                                              const float* __restrict__ att_s,
                                              const float* __restrict__ att_d,
                                              float* __restrict__ as2,
                                              float* __restrict__ ad2, int n) {
    int wid = (blockIdx.x * blockDim.x + threadIdx.x) >> 6;
    int lane = threadIdx.x & 63;
    if (wid >= n) return;
    ushort2 hu = *reinterpret_cast<const ushort2*>(&h2[(size_t)wid * 128 + lane * 2]);
    float2 vs = *reinterpret_cast<const float2*>(&att_s[lane * 2]);
    float2 vd = *reinterpret_cast<const float2*>(&att_d[lane * 2]);
    float hx = bf2f(hu.x), hy = bf2f(hu.y);
    float ss = hx * vs.x + hy * vs.y;
    float sd = hx * vd.x + hy * vd.y;
#pragma unroll
    for (int o = 1; o < 64; o <<= 1) { ss += __shfl_xor(ss, o, 64); sd += __shfl_xor(sd, o, 64); }
    if (lane == 0) { as2[wid] = ss; ad2[wid] = sd; }
}

// ---------------------------------------------------------------------------
// layer-1 aggregation v5: half-wave per edge; exp computed ONCE per
// (edge,head) in phase A (lane = headA*8+g holds p of edges g+8k); phase B
// shfl's the precomputed p (no lrelu/exp in the gather loop).
__global__ __launch_bounds__(256) void k_agg1(const ushort_t* __restrict__ h1,
                                              const float* __restrict__ as1,
                                              const float* __restrict__ ad1,
                                              const int* __restrict__ offs,
                                              const int* __restrict__ esrc,
                                              const float* __restrict__ b1,
                                              float* __restrict__ out1, int n, int tot) {
    int wid = (blockIdx.x * blockDim.x + threadIdx.x) >> 6;
    int lane = threadIdx.x & 63;
    if (wid >= n) return;
    int e0 = offs[wid], e1 = offs[wid + 1];
    int deg = e1 - e0;

    if (deg <= 64) {
        const int l = lane & 31;          // channel-group lane
        const int h = lane >> 5;          // half: edge parity
        const int hd = l >> 2;            // head owning channels l*8..l*8+7
        const int cb = l * 8;

        int ei_idx = e0 + lane;
        int es = esrc[ei_idx < tot ? ei_idx : (tot - 1)];

        // phase A: lane = headA*8+g gathers logits of edges i = g+8k, then
        // converts to unnormalized softmax weights p.
        const int headA = lane >> 3, g = lane & 7;
        float adnA = ad1[(size_t)wid * 8 + headA];
        float a[8];
#pragma unroll
        for (int k = 0; k < 8; ++k) {
            int i = g + 8 * k;
            int s = __shfl(es, i, 64);
            a[k] = (i < deg) ? as1[(size_t)s * 8 + headA] : -1e30f;
        }
        float mx = a[0];
#pragma unroll
        for (int k = 1; k < 8; ++k) mx = fmaxf(mx, a[k]);
#pragma unroll
        for (int o = 1; o < 8; o <<= 1) mx = fmaxf(mx, __shfl_xor(mx, o, 64));
        float mA = lrelu(mx + adnA);
#pragma unroll
        for (int k = 0; k < 8; ++k)
            a[k] = __expf(lrelu(a[k] + adnA) - mA);   // p, 0 for padding

        // phase B: half h handles edges i = 8u + 2v + h; p via shfl
        float d = 0.f;
        float ac0 = 0.f, ac1 = 0.f, ac2 = 0.f, ac3 = 0.f;
        float ac4 = 0.f, ac5 = 0.f, ac6 = 0.f, ac7 = 0.f;
#pragma unroll
        for (int u = 0; u < 8; ++u) {
            if (8 * u < deg) {
#pragma unroll
                for (int v = 0; v < 4; ++v) {
                    int i = 8 * u + 2 * v + h;
                    int s = __shfl(es, i, 64);
                    float p = __shfl(a[u], hd * 8 + 2 * v + h, 64);
                    if (i < deg) {
                        uint4 hv = *reinterpret_cast<const uint4*>(&h1[(size_t)s * 256 + cb]);
                        d += p;
                        ac0 += p * bits2f(hv.x << 16);
                        ac1 += p * bits2f(hv.x & 0xffff0000u);
                        ac2 += p * bits2f(hv.y << 16);
                        ac3 += p * bits2f(hv.y & 0xffff0000u);
                        ac4 += p * bits2f(hv.z << 16);
                        ac5 += p * bits2f(hv.z & 0xffff0000u);
                        ac6 += p * bits2f(hv.w << 16);
                        ac7 += p * bits2f(hv.w & 0xffff0000u);
                    }
                }
            }
        }
        // merge halves
        d   += __shfl_xor(d, 32, 64);
        ac0 += __shfl_xor(ac0, 32, 64); ac1 += __shfl_xor(ac1, 32, 64);
        ac2 += __shfl_xor(ac2, 32, 64); ac3 += __shfl_xor(ac3, 32, 64);
        ac4 += __shfl_xor(ac4, 32, 64); ac5 += __shfl_xor(ac5, 32, 64);
        ac6 += __shfl_xor(ac6, 32, 64); ac7 += __shfl_xor(ac7, 32, 64);
        if (lane < 32) {
            float inv = 1.f / (d + 1e-16f);
            float4 b0 = *reinterpret_cast<const float4*>(&b1[cb]);
            float4 b4 = *reinterpret_cast<const float4*>(&b1[cb + 4]);
            float4 o0, o1;
            o0.x = fmaxf(ac0 * inv + b0.x, 0.f);
            o0.y = fmaxf(ac1 * inv + b0.y, 0.f);
            o0.z = fmaxf(ac2 * inv + b0.z, 0.f);
            o0.w = fmaxf(ac3 * inv + b0.w, 0.f);
            o1.x = fmaxf(ac4 * inv + b4.x, 0.f);
            o1.y = fmaxf(ac5 * inv + b4.y, 0.f);
            o1.z = fmaxf(ac6 * inv + b4.z, 0.f);
            o1.w = fmaxf(ac7 * inv + b4.w, 0.f);
            *reinterpret_cast<float4*>(&out1[(size_t)wid * 256 + cb]) = o0;
            *reinterpret_cast<float4*>(&out1[(size_t)wid * 256 + cb + 4]) = o1;
        }
    } else {
        // rare slow path (old layout: lane owns 4 channels)
        int head = lane >> 3;
        int g = lane & 7;
        int cb = lane * 4;
        float adn = ad1[(size_t)wid * 8 + head];
        float mx = -1e30f;
        for (int e = e0 + g; e < e1; e += 8)
            mx = fmaxf(mx, as1[(size_t)esrc[e] * 8 + head]);
#pragma unroll
        for (int o = 1; o < 8; o <<= 1) mx = fmaxf(mx, __shfl_xor(mx, o, 64));
        float m = lrelu(mx + adn);
        float d = 0.f, ax = 0.f, ay = 0.f, az = 0.f, aw = 0.f;
        for (int e = e0; e < e1; ++e) {
            int s = esrc[e];
            float p = __expf(lrelu(as1[(size_t)s * 8 + head] + adn) - m);
            ushort4 hv = *reinterpret_cast<const ushort4*>(&h1[(size_t)s * 256 + cb]);
            d += p;
            ax += p * bf2f(hv.x);
            ay += p * bf2f(hv.y);
            az += p * bf2f(hv.z);
            aw += p * bf2f(hv.w);
        }
        float inv = 1.f / (d + 1e-16f);
        float4 bb = *reinterpret_cast<const float4*>(&b1[cb]);
        float4 o;
        o.x = fmaxf(ax * inv + bb.x, 0.f);
        o.y = fmaxf(ay * inv + bb.y, 0.f);
        o.z = fmaxf(az * inv + bb.z, 0.f);
        o.w = fmaxf(aw * inv + bb.w, 0.f);
        *reinterpret_cast<float4*>(&out1[(size_t)wid * 256 + cb]) = o;
    }
}

// layer-2 aggregation v5: quarter-wave per edge; exp once per edge (lane i),
// phase B shfl's p.
__global__ __launch_bounds__(256) void k_agg2(const ushort_t* __restrict__ h2,
                                              const float* __restrict__ as2,
                                              const float* __restrict__ ad2,
                                              const int* __restrict__ offs,
                                              const int* __restrict__ esrc,
                                              const float* __restrict__ b2,
                                              float* __restrict__ out2, int n, int tot) {
    int wid = (blockIdx.x * blockDim.x + threadIdx.x) >> 6;
    int lane = threadIdx.x & 63;
    if (wid >= n) return;
    float adn = ad2[wid];
    int e0 = offs[wid], e1 = offs[wid + 1];
    int deg = e1 - e0;

    if (deg <= 64) {
        const int l = lane & 15;
        const int q = lane >> 4;
        const int cb = l * 8;

        int ei_idx = e0 + lane;
        int es = esrc[ei_idx < tot ? ei_idx : (tot - 1)];
        float av0 = (lane < deg) ? as2[es] : -1e30f;
        float mx = av0;
#pragma unroll
        for (int o = 1; o < 64; o <<= 1) mx = fmaxf(mx, __shfl_xor(mx, o, 64));
        float m = lrelu(mx + adn);
        float p0 = __expf(lrelu(av0 + adn) - m);   // one exp per edge

        float d = 0.f;
        float ac0 = 0.f, ac1 = 0.f, ac2 = 0.f, ac3 = 0.f;
        float ac4 = 0.f, ac5 = 0.f, ac6 = 0.f, ac7 = 0.f;
#pragma unroll
        for (int u = 0; u < 4; ++u) {
            if (16 * u < deg) {
#pragma unroll
                for (int v = 0; v < 4; ++v) {
                    int i = 16 * u + 4 * v + q;
                    int s = __shfl(es, i, 64);
                    float p = __shfl(p0, i, 64);
                    if (i < deg) {
                        uint4 hv = *reinterpret_cast<const uint4*>(&h2[(size_t)s * 128 + cb]);
                        d += p;
                        ac0 += p * bits2f(hv.x << 16);
                        ac1 += p * bits2f(hv.x & 0xffff0000u);
                        ac2 += p * bits2f(hv.y << 16);
                        ac3 += p * bits2f(hv.y & 0xffff0000u);
                        ac4 += p * bits2f(hv.z << 16);
                        ac5 += p * bits2f(hv.z & 0xffff0000u);
                        ac6 += p * bits2f(hv.w << 16);
                        ac7 += p * bits2f(hv.w & 0xffff0000u);
                    }
                }
            }
        }
#pragma unroll
        for (int o = 16; o <= 32; o <<= 1) {
            d   += __shfl_xor(d, o, 64);
            ac0 += __shfl_xor(ac0, o, 64); ac1 += __shfl_xor(ac1, o, 64);
            ac2 += __shfl_xor(ac2, o, 64); ac3 += __shfl_xor(ac3, o, 64);
            ac4 += __shfl_xor(ac4, o, 64); ac5 += __shfl_xor(ac5, o, 64);
            ac6 += __shfl_xor(ac6, o, 64); ac7 += __shfl_xor(ac7, o, 64);
        }
        if (lane < 16) {
            float inv = 1.f / (d + 1e-16f);
            float4 b0 = *reinterpret_cast<const float4*>(&b2[cb]);
            float4 b4 = *reinterpret_cast<const float4*>(&b2[cb + 4]);
            float4 o0, o1;
            o0.x = fmaxf(ac0 * inv + b0.x, 0.f);
            o0.y = fmaxf(ac1 * inv + b0.y, 0.f);
            o0.z = fmaxf(ac2 * inv + b0.z, 0.f);
            o0.w = fmaxf(ac3 * inv + b0.w, 0.f);
            o1.x = fmaxf(ac4 * inv + b4.x, 0.f);
            o1.y = fmaxf(ac5 * inv + b4.y, 0.f);
            o1.z = fmaxf(ac6 * inv + b4.z, 0.f);
            o1.w = fmaxf(ac7 * inv + b4.w, 0.f);
            *reinterpret_cast<float4*>(&out2[(size_t)wid * 128 + cb]) = o0;
            *reinterpret_cast<float4*>(&out2[(size_t)wid * 128 + cb + 4]) = o1;
        }
    } else {
        int cb = lane * 2;
        float mx = -1e30f;
        for (int e = e0 + lane; e < e1; e += 64)
            mx = fmaxf(mx, as2[esrc[e]]);
#pragma unroll
        for (int o = 1; o < 64; o <<= 1) mx = fmaxf(mx, __shfl_xor(mx, o, 64));
        float m = lrelu(mx + adn);
        float d = 0.f, ax = 0.f, ay = 0.f;
        for (int e = e0; e < e1; ++e) {
            int s = esrc[e];
            float p = __expf(lrelu(as2[s] + adn) - m);
            ushort2 hv = *reinterpret_cast<const ushort2*>(&h2[(size_t)s * 128 + cb]);
            d += p;
            ax += p * bf2f(hv.x);
            ay += p * bf2f(hv.y);
        }
        float inv = 1.f / (d + 1e-16f);
        float o0 = fmaxf(ax * inv + b2[cb], 0.f);
        float o1 = fmaxf(ay * inv + b2[cb + 1], 0.f);
        float2 o = {o0, o1};
        *reinterpret_cast<float2*>(&out2[(size_t)wid * 128 + cb]) = o;
    }
}

// ---------------------------------------------------------------------------
__global__ __launch_bounds__(128) void k_bnstat(const float* __restrict__ out2,
                                                float* __restrict__ bnsum,
                                                float* __restrict__ bnsq, int n) {
    int c = threadIdx.x;
    float s = 0.f, q = 0.f;
    for (int r = blockIdx.x; r < n; r += gridDim.x) {
        float v = out2[(size_t)r * 128 + c];
        s += v;
        q += v * v;
    }
    atomicAdd(&bnsum[c], s);
    atomicAdd(&bnsq[c], q);
}

__global__ __launch_bounds__(256) void k_final(const float* __restrict__ out2,
                                               const float* __restrict__ bnsum,
                                               const float* __restrict__ bnsq,
                                               const float* __restrict__ bng,
                                               const float* __restrict__ bnb,
                                               const float* __restrict__ lng,
                                               const float* __restrict__ lnb,
                                               float* __restrict__ out, int n) {
    int wid = (blockIdx.x * blockDim.x + threadIdx.x) >> 6;
    int lane = threadIdx.x & 63;
    if (wid >= n) return;
    int c0 = lane, c1 = lane + 64;
    float invn = 1.f / (float)n;
    float mu0 = bnsum[c0] * invn, mu1 = bnsum[c1] * invn;
    float v0 = bnsq[c0] * invn - mu0 * mu0;
    float v1 = bnsq[c1] * invn - mu1 * mu1;
    float r0 = rsqrtf(v0 + EPSV), r1 = rsqrtf(v1 + EPSV);
    float x0 = out2[(size_t)wid * 128 + c0];
    float x1 = out2[(size_t)wid * 128 + c1];
    float y0 = (x0 - mu0) * r0 * bng[c0] + bnb[c0];
    float y1 = (x1 - mu1) * r1 * bng[c1] + bnb[c1];
    float s = y0 + y1, q = y0 * y0 + y1 * y1;
#pragma unroll
    for (int o = 1; o < 64; o <<= 1) { s += __shfl_xor(s, o, 64); q += __shfl_xor(q, o, 64); }
    float mu = s * (1.f / 128.f);
    float var = q * (1.f / 128.f) - mu * mu;
    float rr = rsqrtf(var + EPSV);
    out[(size_t)wid * 128 + c0] = (y0 - mu) * rr * lng[c0] + lnb[c0];
    out[(size_t)wid * 128 + c1] = (y1 - mu) * rr * lng[c1] + lnb[c1];
}

// ---------------------------------------------------------------------------
extern "C" void kernel_launch(void* const* d_in, const int* in_sizes, int n_in,
                              void* d_out, int out_size, void* d_ws, size_t ws_size,
                              hipStream_t stream) {
    const float* x    = (const float*)d_in[0];
    const int*   ei   = (const int*)d_in[1];
    const float* W1   = (const float*)d_in[2];
    const float* ats1 = (const float*)d_in[3];
    const float* atd1 = (const float*)d_in[4];
    const float* b1   = (const float*)d_in[5];
    const float* W2   = (const float*)d_in[6];
    const float* ats2 = (const float*)d_in[7];
    const float* atd2 = (const float*)d_in[8];
    const float* b2   = (const float*)d_in[9];
    const float* bng  = (const float*)d_in[10];
    const float* bnb  = (const float*)d_in[11];
    const float* lng  = (const float*)d_in[12];
    const float* lnb  = (const float*)d_in[13];

    const int n = in_sizes[0] / NFEAT;   // 50000
    const int E = in_sizes[1] / 2;       // 800000
    const int tot = E + n;

    auto align = [](size_t v) { return (v + 255) & ~(size_t)255; };
    char* ws = (char*)d_ws;
    size_t off = 0;
    ushort_t* h1 = (ushort_t*)(ws + off); off += align((size_t)n * 256 * 2);
    float* out1 = (float*)(ws + off); off += align((size_t)n * 256 * 4);
    ushort_t* h2 = h1;
    float* out2 = out1;
    float* as1 = (float*)(ws + off); off += align((size_t)n * 8 * 4);
    float* ad1 = (float*)(ws + off); off += align((size_t)n * 8 * 4);
    float* as2 = (float*)(ws + off); off += align((size_t)n * 4);
    float* ad2 = (float*)(ws + off); off += align((size_t)n * 4);
    int* counts = (int*)(ws + off); off += align((size_t)n * 4 + 1024);
    float* bnsum = (float*)(counts + n);       // 128 floats, zeroed with counts
    float* bnsq  = bnsum + 128;
    int* offs   = (int*)(ws + off); off += align((size_t)(n + 1) * 4);
    int* cursor = (int*)(ws + off); off += align((size_t)n * 4);
    int* esrc   = (int*)(ws + off); off += align((size_t)tot * 4);
    int* incl   = (int*)(ws + off); off += align((size_t)n * 4);
    int* bsum   = (int*)(ws + off); off += align(64 * 4);
    ushort_t* Wh1 = (ushort_t*)(ws + off); off += align((size_t)256 * 256 * 2);
    ushort_t* Wl1 = (ushort_t*)(ws + off); off += align((size_t)256 * 256 * 2);
    ushort_t* Wh2 = (ushort_t*)(ws + off); off += align((size_t)256 * 128 * 2);
    ushort_t* Wl2 = (ushort_t*)(ws + off); off += align((size_t)256 * 128 * 2);

    hipMemsetAsync(counts, 0, (size_t)n * 4 + 1024, stream);

    // W packing (tiny)
    k_prepw<<<(256 * 256 + 256 * 128 + 255) / 256, 256, 0, stream>>>(W1, W2, Wh1, Wl1, Wh2, Wl2);

    // CSR build
    k_count<<<(tot + 255) / 256, 256, 0, stream>>>(ei, counts, E, n);
    int nsb = (n + 1023) / 1024;
    k_scan1<<<nsb, 1024, 0, stream>>>(counts, incl, bsum, n);
    k_scan3<<<(n + 255) / 256, 256, 0, stream>>>(incl, bsum, counts, offs, cursor, n);
    k_fill<<<(tot + 255) / 256, 256, 0, stream>>>(ei, cursor, esrc, E, n);

    const int gx = (n + 127) / 128;
    // layer 1
    k_mm<<<dim3(gx, 2), 256, 0, stream>>>(x, Wh1, Wl1, h1, n, 256);
    k_att1<<<(n + 3) / 4, 256, 0, stream>>>(h1, ats1, atd1, as1, ad1, n);
    k_agg1<<<(n + 3) / 4, 256, 0, stream>>>(h1, as1, ad1, offs, esrc, b1, out1, n, tot);

    // layer 2
    k_mm<<<dim3(gx, 1), 256, 0, stream>>>(out1, Wh2, Wl2, h2, n, 128);
    k_att2<<<(n + 3) / 4, 256, 0, stream>>>(h2, ats2, atd2, as2, ad2, n);
    k_agg2<<<(n + 3) / 4, 256, 0, stream>>>(h2, as2, ad2, offs, esrc, b2, out2, n, tot);

    // BN + LN
    k_bnstat<<<512, 128, 0, stream>>>(out2, bnsum, bnsq, n);
    k_final<<<(n + 3) / 4, 256, 0, stream>>>(out2, bnsum, bnsq, bng, bnb, lng, lnb,
                                             (float*)d_out, n);
}

// Round 8
// 350.705 us; speedup vs baseline: 1.1474x; 1.0105x over previous
//
#include <hip/hip_runtime.h>
#include <cstdint>
#include <cstddef>

#define HEADS   8
#define NFEAT   256
#define NOUT    128
#define NEG     0.2f
#define EPSV    1e-5f

typedef unsigned short ushort_t;
typedef __attribute__((ext_vector_type(8))) short s8v;   // 8 bf16 = 4 VGPR
typedef __attribute__((ext_vector_type(4))) float f4v;   // MFMA accum

static __device__ __forceinline__ float lrelu(float x) { return x > 0.f ? x : NEG * x; }

static __device__ __forceinline__ float bf2f(ushort_t u) {
    union { unsigned int i; float f; } v; v.i = ((unsigned int)u) << 16; return v.f;
}
static __device__ __forceinline__ ushort_t f2bf(float f) {
    union { float f; unsigned int i; } v; v.f = f;
    unsigned int x = v.i;
    return (ushort_t)((x + 0x7fff + ((x >> 16) & 1)) >> 16);   // RNE
}
static __device__ __forceinline__ float bits2f(unsigned int u) {
    union { unsigned int i; float f; } v; v.i = u; return v.f;
}
static __device__ __forceinline__ unsigned int f2bits(float f) {
    union { float f; unsigned int i; } v; v.f = f; return v.i;
}

// wave-local int64-vs-int32 detection (deterministic, identical in every wave)
static __device__ __forceinline__ int detect64(const int* __restrict__ ei, int E) {
    int lane = threadIdx.x & 63;
    long idx = 2L * ((long)lane * (E / 64)) + 1;
    int v = ei[idx];
    unsigned long long ball = __ballot(v == 0);
    return (ball == ~0ull) ? 1 : 0;
}

// ---------------------------------------------------------------------------
// fused: edge-count (CSR histogram) + W hi/lo packing (disjoint block ranges)
__global__ void k_prep(const int* __restrict__ ei, int* __restrict__ counts,
                       int E, int n, int cblocks,
                       const float* __restrict__ W1, const float* __restrict__ W2,
                       ushort_t* __restrict__ Wh1, ushort_t* __restrict__ Wl1,
                       ushort_t* __restrict__ Wh2, ushort_t* __restrict__ Wl2) {
    if (blockIdx.x < (unsigned)cblocks) {
        int is64 = detect64(ei, E);
        int i = blockIdx.x * 256 + threadIdx.x;
        if (i < E) {
            int d = ei[(size_t)(E + i) << is64];
            atomicAdd(&counts[d], 1);
        } else if (i < E + n) {
            atomicAdd(&counts[i - E], 1);
        }
    } else {
        int gid = (blockIdx.x - cblocks) * 256 + threadIdx.x;
        const float* W; ushort_t* Wh; ushort_t* Wl; int M;
        if (gid < 256 * 256) { W = W1; Wh = Wh1; Wl = Wl1; M = 256; }
        else { gid -= 256 * 256; if (gid >= 256 * 128) return; W = W2; Wh = Wh2; Wl = Wl2; M = 128; }
        int k = gid / M, nn = gid - k * M;
        int ntile = nn >> 4, j = nn & 15, kc = k >> 3, e = k & 7;
        int p = ((ntile * 32 + kc) * 16 + j) * 8 + e;     // K=256 -> K/8=32
        float v = W[(size_t)k * M + nn];
        ushort_t hi = f2bf(v);
        float r = v - bf2f(hi);
        Wh[p] = hi;
        Wl[p] = f2bf(r);
    }
}

__global__ __launch_bounds__(1024) void k_scan1(const int* __restrict__ counts,
                                                int* __restrict__ incl,
                                                int* __restrict__ bsum, int n) {
    int t = threadIdx.x, i = blockIdx.x * 1024 + t;
    int lane = t & 63, w = t >> 6;
    int v = (i < n) ? counts[i] : 0;
    int sv = v;
#pragma unroll
    for (int o = 1; o < 64; o <<= 1) { int u = __shfl_up(sv, o, 64); if (lane >= o) sv += u; }
    __shared__ int wsum[16];
    if (lane == 63) wsum[w] = sv;
    __syncthreads();
    if (w == 0) {
        int bs = (lane < 16) ? wsum[lane] : 0;
#pragma unroll
        for (int o = 1; o < 16; o <<= 1) { int u = __shfl_up(bs, o, 64); if (lane >= o) bs += u; }
        if (lane < 16) wsum[lane] = bs;
    }
    __syncthreads();
    int pre = (w > 0) ? wsum[w - 1] : 0;
    sv += pre;
    if (i < n) incl[i] = sv;
    if (t == 1023) bsum[blockIdx.x] = sv;   // raw block total
}

// scan3 with folded block-sum prefix
__global__ void k_scan3(const int* __restrict__ incl, const int* __restrict__ bsum,
                        const int* __restrict__ counts,
                        int* __restrict__ offs, int* __restrict__ cursor, int n) {
    __shared__ int pre_s;
    int chunk = blockIdx.x >> 2;            // 256-thr blocks, scan1 blocks = 1024
    if (threadIdx.x == 0) {
        int s = 0;
        for (int j = 0; j < chunk; ++j) s += bsum[j];
        pre_s = s;
    }
    __syncthreads();
    int i = blockIdx.x * 256 + threadIdx.x;
    if (i < n) {
        int v = incl[i] + pre_s;
        offs[i + 1] = v;
        cursor[i] = v - counts[i];
    }
    if (i == 0) offs[0] = 0;
}

__global__ void k_fill(const int* __restrict__ ei, int* __restrict__ cursor,
                       int* __restrict__ esrc, int E, int n) {
    int is64 = detect64(ei, E);
    int i = blockIdx.x * blockDim.x + threadIdx.x;
    if (i >= E + n) return;
    int s, d;
    if (i < E) { s = ei[(size_t)i << is64]; d = ei[(size_t)(E + i) << is64]; }
    else       { s = i - E; d = s; }
    int p = atomicAdd(&cursor[d], 1);
    esrc[p] = s;
}

// ---------------------------------------------------------------------------
// MFMA GEMM, bf16x3 split precision, with fused attention-logit epilogue.
// MOUT=256: block y covers heads 4y..4y+3; wave computes as1/ad1 directly.
// MOUT=128: single head split across waves; partial + atomicAdd.
template <int MOUT>
__global__ __launch_bounds__(256) void k_mm(const float* __restrict__ A,
                                            const ushort_t* __restrict__ Wh,
                                            const ushort_t* __restrict__ Wl,
                                            ushort_t* __restrict__ C,
                                            const float* __restrict__ att_s,
                                            const float* __restrict__ att_d,
                                            float* __restrict__ as_o,
                                            float* __restrict__ ad_o, int n) {
    __shared__ ushort_t Ah[128][40];
    __shared__ ushort_t Al[128][40];
    const int t = threadIdx.x;
    const int lane = t & 63, w = t >> 6;
    const int wr = w >> 1, wc = w & 1;
    const int r0 = blockIdx.x * 128;
    const int srow = t >> 1;
    const int kh = (t & 1) * 16;
    const int arow = r0 + srow;
    const bool rowok = arow < n;

    f4v acc[4][4];
#pragma unroll
    for (int a = 0; a < 4; ++a)
#pragma unroll
        for (int b = 0; b < 4; ++b) { f4v z = {0.f, 0.f, 0.f, 0.f}; acc[a][b] = z; }

    float pre[16];
    const float* abase = &A[(size_t)arow * 256 + kh];
#pragma unroll
    for (int q = 0; q < 4; ++q) {
        float4 v = rowok ? *reinterpret_cast<const float4*>(abase + q * 4)
                         : float4{0.f, 0.f, 0.f, 0.f};
        pre[q * 4 + 0] = v.x; pre[q * 4 + 1] = v.y;
        pre[q * 4 + 2] = v.z; pre[q * 4 + 3] = v.w;
    }

    const int lj = lane & 15, lk = lane >> 4;

    for (int kb = 0; kb < 256; kb += 32) {
        __syncthreads();
#pragma unroll
        for (int q = 0; q < 2; ++q) {
            unsigned int hw[4], lw[4];
#pragma unroll
            for (int p = 0; p < 4; ++p) {
                unsigned int x0 = f2bits(pre[q * 8 + p * 2]);
                unsigned int x1 = f2bits(pre[q * 8 + p * 2 + 1]);
                unsigned int h1b = x1 & 0xffff0000u;
                float lo0 = pre[q * 8 + p * 2] - bits2f(x0 & 0xffff0000u);
                float lo1 = pre[q * 8 + p * 2 + 1] - bits2f(h1b);
                hw[p] = (x0 >> 16) | h1b;
                lw[p] = (f2bits(lo0) >> 16) | (f2bits(lo1) & 0xffff0000u);
            }
            uint4 hv = {hw[0], hw[1], hw[2], hw[3]};
            uint4 lv = {lw[0], lw[1], lw[2], lw[3]};
            *reinterpret_cast<uint4*>(&Ah[srow][kh + q * 8]) = hv;
            *reinterpret_cast<uint4*>(&Al[srow][kh + q * 8]) = lv;
        }
        __syncthreads();
        if (kb < 224) {
            const float* ap = abase + kb + 32;
#pragma unroll
            for (int q = 0; q < 4; ++q) {
                float4 v = rowok ? *reinterpret_cast<const float4*>(ap + q * 4)
                                 : float4{0.f, 0.f, 0.f, 0.f};
                pre[q * 4 + 0] = v.x; pre[q * 4 + 1] = v.y;
                pre[q * 4 + 2] = v.z; pre[q * 4 + 3] = v.w;
            }
        }
        const int kc0 = kb >> 3;
        s8v ah[4], al[4];
#pragma unroll
        for (int mf = 0; mf < 4; ++mf) {
            ah[mf] = *reinterpret_cast<const s8v*>(&Ah[wr * 64 + mf * 16 + lj][lk * 8]);
            al[mf] = *reinterpret_cast<const s8v*>(&Al[wr * 64 + mf * 16 + lj][lk * 8]);
        }
#pragma unroll
        for (int nf = 0; nf < 4; ++nf) {
            int ntile = blockIdx.y * 8 + wc * 4 + nf;
            size_t boff = ((size_t)(ntile * 32 + kc0 + lk) * 16 + lj) * 8;
            s8v bh = *reinterpret_cast<const s8v*>(&Wh[boff]);
            s8v bl = *reinterpret_cast<const s8v*>(&Wl[boff]);
#pragma unroll
            for (int mf = 0; mf < 4; ++mf) {
                acc[mf][nf] = __builtin_amdgcn_mfma_f32_16x16x32_bf16(ah[mf], bh, acc[mf][nf], 0, 0, 0);
                acc[mf][nf] = __builtin_amdgcn_mfma_f32_16x16x32_bf16(ah[mf], bl, acc[mf][nf], 0, 0, 0);
                acc[mf][nf] = __builtin_amdgcn_mfma_f32_16x16x32_bf16(al[mf], bh, acc[mf][nf], 0, 0, 0);
            }
        }
    }

    // C write (bf16)
#pragma unroll
    for (int mf = 0; mf < 4; ++mf) {
        int rr = r0 + wr * 64 + mf * 16 + lk * 4;
#pragma unroll
        for (int nf = 0; nf < 4; ++nf) {
            int cc = blockIdx.y * 128 + wc * 64 + nf * 16 + lj;
#pragma unroll
            for (int r = 0; r < 4; ++r) {
                if (rr + r < n) C[(size_t)(rr + r) * MOUT + cc] = f2bf(acc[mf][nf][r]);
            }
        }
    }

    // fused attention-logit epilogue
    const int colw = (MOUT == 256 ? blockIdx.y * 128 : 0) + wc * 64;
    float asv[4], adv[4];
#pragma unroll
    for (int nf = 0; nf < 4; ++nf) {
        asv[nf] = att_s[colw + nf * 16 + lj];
        adv[nf] = att_d[colw + nf * 16 + lj];
    }
    if (MOUT == 256) {
        int headA = colw >> 5;   // wave covers heads headA, headA+1
#pragma unroll
        for (int mf = 0; mf < 4; ++mf) {
            int rr = r0 + wr * 64 + mf * 16 + lk * 4;
#pragma unroll
            for (int r = 0; r < 4; ++r) {
                float ssA = acc[mf][0][r] * asv[0] + acc[mf][1][r] * asv[1];
                float sdA = acc[mf][0][r] * adv[0] + acc[mf][1][r] * adv[1];
                float ssB = acc[mf][2][r] * asv[2] + acc[mf][3][r] * asv[3];
                float sdB = acc[mf][2][r] * adv[2] + acc[mf][3][r] * adv[3];
#pragma unroll
                for (int o = 1; o < 16; o <<= 1) {
                    ssA += __shfl_xor(ssA, o, 64); sdA += __shfl_xor(sdA, o, 64);
                    ssB += __shfl_xor(ssB, o, 64); sdB += __shfl_xor(sdB, o, 64);
                }
                if (lj == 0 && rr + r < n) {
                    size_t rb = (size_t)(rr + r) * 8;
                    as_o[rb + headA] = ssA;  ad_o[rb + headA] = sdA;
                    as_o[rb + headA + 1] = ssB;  ad_o[rb + headA + 1] = sdB;
                }
            }
        }
    } else {
#pragma unroll
        for (int mf = 0; mf < 4; ++mf) {
            int rr = r0 + wr * 64 + mf * 16 + lk * 4;
#pragma unroll
            for (int r = 0; r < 4; ++r) {
                float ss = acc[mf][0][r] * asv[0] + acc[mf][1][r] * asv[1]
                         + acc[mf][2][r] * asv[2] + acc[mf][3][r] * asv[3];
                float sd = acc[mf][0][r] * adv[0] + acc[mf][1][r] * adv[1]
                         + acc[mf][2][r] * adv[2] + acc[mf][3][r] * adv[3];
#pragma unroll
                for (int o = 1; o < 16; o <<= 1) {
                    ss += __shfl_xor(ss, o, 64); sd += __shfl_xor(sd, o, 64);
                }
                if (lj == 0 && rr + r < n) {
                    atomicAdd(&as_o[rr + r], ss);
                    atomicAdd(&ad_o[rr + r], sd);
                }
            }
        }
    }
}

// ---------------------------------------------------------------------------
// layer-1 aggregation: half-wave per edge; exp once per (edge,head) in phase A.
__global__ __launch_bounds__(128) void k_agg1(const ushort_t* __restrict__ h1,
                                              const float* __restrict__ as1,
                                              const float* __restrict__ ad1,
                                              const int* __restrict__ offs,
                                              const int* __restrict__ esrc,
                                              const float* __restrict__ b1,
                                              float* __restrict__ out1, int n, int tot) {
    int wid = (blockIdx.x * 128 + threadIdx.x) >> 6;
    int lane = threadIdx.x & 63;
    if (wid >= n) return;
    int e0 = offs[wid], e1 = offs[wid + 1];
    int deg = e1 - e0;

    if (deg <= 64) {
        const int l = lane & 31;          // channel-group lane
        const int h = lane >> 5;          // half: edge parity
        const int hd = l >> 2;            // head owning channels l*8..l*8+7
        const int cb = l * 8;

        int ei_idx = e0 + lane;
        int es = esrc[ei_idx < tot ? ei_idx : (tot - 1)];

        const int headA = lane >> 3, g = lane & 7;
        float adnA = ad1[(size_t)wid * 8 + headA];
        float a[8];
#pragma unroll
        for (int k = 0; k < 8; ++k) {
            int i = g + 8 * k;
            int s = __shfl(es, i, 64);
            a[k] = (i < deg) ? as1[(size_t)s * 8 + headA] : -1e30f;
        }
        float mx = a[0];
#pragma unroll
        for (int k = 1; k < 8; ++k) mx = fmaxf(mx, a[k]);
#pragma unroll
        for (int o = 1; o < 8; o <<= 1) mx = fmaxf(mx, __shfl_xor(mx, o, 64));
        float mA = lrelu(mx + adnA);
#pragma unroll
        for (int k = 0; k < 8; ++k)
            a[k] = __expf(lrelu(a[k] + adnA) - mA);   // p, 0 for padding

        float d = 0.f;
        float ac0 = 0.f, ac1 = 0.f, ac2 = 0.f, ac3 = 0.f;
        float ac4 = 0.f, ac5 = 0.f, ac6 = 0.f, ac7 = 0.f;
#pragma unroll
        for (int u = 0; u < 8; ++u) {
            if (8 * u < deg) {
#pragma unroll
                for (int v = 0; v < 4; ++v) {
                    int i = 8 * u + 2 * v + h;
                    int s = __shfl(es, i, 64);
                    float p = __shfl(a[u], hd * 8 + 2 * v + h, 64);
                    if (i < deg) {
                        uint4 hv = *reinterpret_cast<const uint4*>(&h1[(size_t)s * 256 + cb]);
                        d += p;
                        ac0 += p * bits2f(hv.x << 16);
                        ac1 += p * bits2f(hv.x & 0xffff0000u);
                        ac2 += p * bits2f(hv.y << 16);
                        ac3 += p * bits2f(hv.y & 0xffff0000u);
                        ac4 += p * bits2f(hv.z << 16);
                        ac5 += p * bits2f(hv.z & 0xffff0000u);
                        ac6 += p * bits2f(hv.w << 16);
                        ac7 += p * bits2f(hv.w & 0xffff0000u);
                    }
                }
            }
        }
        d   += __shfl_xor(d, 32, 64);
        ac0 += __shfl_xor(ac0, 32, 64); ac1 += __shfl_xor(ac1, 32, 64);
        ac2 += __shfl_xor(ac2, 32, 64); ac3 += __shfl_xor(ac3, 32, 64);
        ac4 += __shfl_xor(ac4, 32, 64); ac5 += __shfl_xor(ac5, 32, 64);
        ac6 += __shfl_xor(ac6, 32, 64); ac7 += __shfl_xor(ac7, 32, 64);
        if (lane < 32) {
            float inv = 1.f / (d + 1e-16f);
            float4 b0 = *reinterpret_cast<const float4*>(&b1[cb]);
            float4 b4 = *reinterpret_cast<const float4*>(&b1[cb + 4]);
            float4 o0, o1;
            o0.x = fmaxf(ac0 * inv + b0.x, 0.f);
            o0.y = fmaxf(ac1 * inv + b0.y, 0.f);
            o0.z = fmaxf(ac2 * inv + b0.z, 0.f);
            o0.w = fmaxf(ac3 * inv + b0.w, 0.f);
            o1.x = fmaxf(ac4 * inv + b4.x, 0.f);
            o1.y = fmaxf(ac5 * inv + b4.y, 0.f);
            o1.z = fmaxf(ac6 * inv + b4.z, 0.f);
            o1.w = fmaxf(ac7 * inv + b4.w, 0.f);
            *reinterpret_cast<float4*>(&out1[(size_t)wid * 256 + cb]) = o0;
            *reinterpret_cast<float4*>(&out1[(size_t)wid * 256 + cb + 4]) = o1;
        }
    } else {
        int head = lane >> 3;
        int g = lane & 7;
        int cb = lane * 4;
        float adn = ad1[(size_t)wid * 8 + head];
        float mx = -1e30f;
        for (int e = e0 + g; e < e1; e += 8)
            mx = fmaxf(mx, as1[(size_t)esrc[e] * 8 + head]);
#pragma unroll
        for (int o = 1; o < 8; o <<= 1) mx = fmaxf(mx, __shfl_xor(mx, o, 64));
        float m = lrelu(mx + adn);
        float d = 0.f, ax = 0.f, ay = 0.f, az = 0.f, aw = 0.f;
        for (int e = e0; e < e1; ++e) {
            int s = esrc[e];
            float p = __expf(lrelu(as1[(size_t)s * 8 + head] + adn) - m);
            ushort4 hv = *reinterpret_cast<const ushort4*>(&h1[(size_t)s * 256 + cb]);
            d += p;
            ax += p * bf2f(hv.x);
            ay += p * bf2f(hv.y);
            az += p * bf2f(hv.z);
            aw += p * bf2f(hv.w);
        }
        float inv = 1.f / (d + 1e-16f);
        float4 bb = *reinterpret_cast<const float4*>(&b1[cb]);
        float4 o;
        o.x = fmaxf(ax * inv + bb.x, 0.f);
        o.y = fmaxf(ay * inv + bb.y, 0.f);
        o.z = fmaxf(az * inv + bb.z, 0.f);
        o.w = fmaxf(aw * inv + bb.w, 0.f);
        *reinterpret_cast<float4*>(&out1[(size_t)wid * 256 + cb]) = o;
    }
}

// layer-2 aggregation: quarter-wave per edge; exp once per edge.
__global__ __launch_bounds__(128) void k_agg2(const ushort_t* __restrict__ h2,
                                              const float* __restrict__ as2,
                                              const float* __restrict__ ad2,
                                              const int* __restrict__ offs,
                                              const int* __restrict__ esrc,
                                              const float* __restrict__ b2,
                                              float* __restrict__ out2, int n, int tot) {
    int wid = (blockIdx.x * 128 + threadIdx.x) >> 6;
    int lane = threadIdx.x & 63;
    if (wid >= n) return;
    float adn = ad2[wid];
    int e0 = offs[wid], e1 = offs[wid + 1];
    int deg = e1 - e0;

    if (deg <= 64) {
        const int l = lane & 15;
        const int q = lane >> 4;
        const int cb = l * 8;

        int ei_idx = e0 + lane;
        int es = esrc[ei_idx < tot ? ei_idx : (tot - 1)];
        float av0 = (lane < deg) ? as2[es] : -1e30f;
        float mx = av0;
#pragma unroll
        for (int o = 1; o < 64; o <<= 1) mx = fmaxf(mx, __shfl_xor(mx, o, 64));
        float m = lrelu(mx + adn);
        float p0 = __expf(lrelu(av0 + adn) - m);   // one exp per edge

        float d = 0.f;
        float ac0 = 0.f, ac1 = 0.f, ac2 = 0.f, ac3 = 0.f;
        float ac4 = 0.f, ac5 = 0.f, ac6 = 0.f, ac7 = 0.f;
#pragma unroll
        for (int u = 0; u < 4; ++u) {
            if (16 * u < deg) {
#pragma unroll
                for (int v = 0; v < 4; ++v) {
                    int i = 16 * u + 4 * v + q;
                    int s = __shfl(es, i, 64);
                    float p = __shfl(p0, i, 64);
                    if (i < deg) {
                        uint4 hv = *reinterpret_cast<const uint4*>(&h2[(size_t)s * 128 + cb]);
                        d += p;
                        ac0 += p * bits2f(hv.x << 16);
                        ac1 += p * bits2f(hv.x & 0xffff0000u);
                        ac2 += p * bits2f(hv.y << 16);
                        ac3 += p * bits2f(hv.y & 0xffff0000u);
                        ac4 += p * bits2f(hv.z << 16);
                        ac5 += p * bits2f(hv.z & 0xffff0000u);
                        ac6 += p * bits2f(hv.w << 16);
                        ac7 += p * bits2f(hv.w & 0xffff0000u);
                    }
                }
            }
        }
#pragma unroll
        for (int o = 16; o <= 32; o <<= 1) {
            d   += __shfl_xor(d, o, 64);
            ac0 += __shfl_xor(ac0, o, 64); ac1 += __shfl_xor(ac1, o, 64);
            ac2 += __shfl_xor(ac2, o, 64); ac3 += __shfl_xor(ac3, o, 64);
            ac4 += __shfl_xor(ac4, o, 64); ac5 += __shfl_xor(ac5, o, 64);
            ac6 += __shfl_xor(ac6, o, 64); ac7 += __shfl_xor(ac7, o, 64);
        }
        if (lane < 16) {
            float inv = 1.f / (d + 1e-16f);
            float4 b0 = *reinterpret_cast<const float4*>(&b2[cb]);
            float4 b4 = *reinterpret_cast<const float4*>(&b2[cb + 4]);
            float4 o0, o1;
            o0.x = fmaxf(ac0 * inv + b0.x, 0.f);
            o0.y = fmaxf(ac1 * inv + b0.y, 0.f);
            o0.z = fmaxf(ac2 * inv + b0.z, 0.f);
            o0.w = fmaxf(ac3 * inv + b0.w, 0.f);
            o1.x = fmaxf(ac4 * inv + b4.x, 0.f);
            o1.y = fmaxf(ac5 * inv + b4.y, 0.f);
            o1.z = fmaxf(ac6 * inv + b4.z, 0.f);
            o1.w = fmaxf(ac7 * inv + b4.w, 0.f);
            *reinterpret_cast<float4*>(&out2[(size_t)wid * 128 + cb]) = o0;
            *reinterpret_cast<float4*>(&out2[(size_t)wid * 128 + cb + 4]) = o1;
        }
    } else {
        int cb = lane * 2;
        float mx = -1e30f;
        for (int e = e0 + lane; e < e1; e += 64)
            mx = fmaxf(mx, as2[esrc[e]]);
#pragma unroll
        for (int o = 1; o < 64; o <<= 1) mx = fmaxf(mx, __shfl_xor(mx, o, 64));
        float m = lrelu(mx + adn);
        float d = 0.f, ax = 0.f, ay = 0.f;
        for (int e = e0; e < e1; ++e) {
            int s = esrc[e];
            float p = __expf(lrelu(as2[s] + adn) - m);
            ushort2 hv = *reinterpret_cast<const ushort2*>(&h2[(size_t)s * 128 + cb]);
            d += p;
            ax += p * bf2f(hv.x);
            ay += p * bf2f(hv.y);
        }
        float inv = 1.f / (d + 1e-16f);
        float o0 = fmaxf(ax * inv + b2[cb], 0.f);
        float o1 = fmaxf(ay * inv + b2[cb + 1], 0.f);
        float2 o = {o0, o1};
        *reinterpret_cast<float2*>(&out2[(size_t)wid * 128 + cb]) = o;
    }
}

// ---------------------------------------------------------------------------
__global__ __launch_bounds__(128) void k_bnstat(const float* __restrict__ out2,
                                                float* __restrict__ bnsum,
                                                float* __restrict__ bnsq, int n) {
    int c = threadIdx.x;
    float s = 0.f, q = 0.f;
    for (int r = blockIdx.x; r < n; r += gridDim.x) {
        float v = out2[(size_t)r * 128 + c];
        s += v;
        q += v * v;
    }
    atomicAdd(&bnsum[c], s);
    atomicAdd(&bnsq[c], q);
}

__global__ __launch_bounds__(256) void k_final(const float* __restrict__ out2,
                                               const float* __restrict__ bnsum,
                                               const float* __restrict__ bnsq,
                                               const float* __restrict__ bng,
                                               const float* __restrict__ bnb,
                                               const float* __restrict__ lng,
                                               const float* __restrict__ lnb,
                                               float* __restrict__ out, int n) {
    int wid = (blockIdx.x * blockDim.x + threadIdx.x) >> 6;
    int lane = threadIdx.x & 63;
    if (wid >= n) return;
    int c0 = lane, c1 = lane + 64;
    float invn = 1.f / (float)n;
    float mu0 = bnsum[c0] * invn, mu1 = bnsum[c1] * invn;
    float v0 = bnsq[c0] * invn - mu0 * mu0;
    float v1 = bnsq[c1] * invn - mu1 * mu1;
    float r0 = rsqrtf(v0 + EPSV), r1 = rsqrtf(v1 + EPSV);
    float x0 = out2[(size_t)wid * 128 + c0];
    float x1 = out2[(size_t)wid * 128 + c1];
    float y0 = (x0 - mu0) * r0 * bng[c0] + bnb[c0];
    float y1 = (x1 - mu1) * r1 * bng[c1] + bnb[c1];
    float s = y0 + y1, q = y0 * y0 + y1 * y1;
#pragma unroll
    for (int o = 1; o < 64; o <<= 1) { s += __shfl_xor(s, o, 64); q += __shfl_xor(q, o, 64); }
    float mu = s * (1.f / 128.f);
    float var = q * (1.f / 128.f) - mu * mu;
    float rr = rsqrtf(var + EPSV);
    out[(size_t)wid * 128 + c0] = (y0 - mu) * rr * lng[c0] + lnb[c0];
    out[(size_t)wid * 128 + c1] = (y1 - mu) * rr * lng[c1] + lnb[c1];
}

// ---------------------------------------------------------------------------
extern "C" void kernel_launch(void* const* d_in, const int* in_sizes, int n_in,
                              void* d_out, int out_size, void* d_ws, size_t ws_size,
                              hipStream_t stream) {
    const float* x    = (const float*)d_in[0];
    const int*   ei   = (const int*)d_in[1];
    const float* W1   = (const float*)d_in[2];
    const float* ats1 = (const float*)d_in[3];
    const float* atd1 = (const float*)d_in[4];
    const float* b1   = (const float*)d_in[5];
    const float* W2   = (const float*)d_in[6];
    const float* ats2 = (const float*)d_in[7];
    const float* atd2 = (const float*)d_in[8];
    const float* b2   = (const float*)d_in[9];
    const float* bng  = (const float*)d_in[10];
    const float* bnb  = (const float*)d_in[11];
    const float* lng  = (const float*)d_in[12];
    const float* lnb  = (const float*)d_in[13];

    const int n = in_sizes[0] / NFEAT;   // 50000
    const int E = in_sizes[1] / 2;       // 800000
    const int tot = E + n;

    auto align = [](size_t v) { return (v + 255) & ~(size_t)255; };
    char* ws = (char*)d_ws;
    size_t off = 0;
    ushort_t* h1 = (ushort_t*)(ws + off); off += align((size_t)n * 256 * 2);
    float* out1 = (float*)(ws + off); off += align((size_t)n * 256 * 4);
    ushort_t* h2 = h1;
    float* out2 = out1;
    float* as1 = (float*)(ws + off); off += align((size_t)n * 8 * 4);
    float* ad1 = (float*)(ws + off); off += align((size_t)n * 8 * 4);
    // zero-region: counts[n] | bnsum[128] | bnsq[128] | as2[n] | ad2[n]
    int* counts = (int*)(ws + off); off += align((size_t)n * 12 + 1024);
    float* bnsum = (float*)(counts + n);
    float* bnsq  = bnsum + 128;
    float* as2   = bnsq + 128;
    float* ad2   = as2 + n;
    int* offs   = (int*)(ws + off); off += align((size_t)(n + 1) * 4);
    int* cursor = (int*)(ws + off); off += align((size_t)n * 4);
    int* esrc   = (int*)(ws + off); off += align((size_t)tot * 4);
    int* incl   = (int*)(ws + off); off += align((size_t)n * 4);
    int* bsum   = (int*)(ws + off); off += align(64 * 4);
    ushort_t* Wh1 = (ushort_t*)(ws + off); off += align((size_t)256 * 256 * 2);
    ushort_t* Wl1 = (ushort_t*)(ws + off); off += align((size_t)256 * 256 * 2);
    ushort_t* Wh2 = (ushort_t*)(ws + off); off += align((size_t)256 * 128 * 2);
    ushort_t* Wl2 = (ushort_t*)(ws + off); off += align((size_t)256 * 128 * 2);

    hipMemsetAsync(counts, 0, (size_t)n * 12 + 1024, stream);

    // fused count + W-pack
    const int cblocks = (tot + 255) / 256;
    const int pblocks = (256 * 256 + 256 * 128 + 255) / 256;
    k_prep<<<cblocks + pblocks, 256, 0, stream>>>(ei, counts, E, n, cblocks,
                                                  W1, W2, Wh1, Wl1, Wh2, Wl2);
    int nsb = (n + 1023) / 1024;
    k_scan1<<<nsb, 1024, 0, stream>>>(counts, incl, bsum, n);
    k_scan3<<<(n + 255) / 256, 256, 0, stream>>>(incl, bsum, counts, offs, cursor, n);
    k_fill<<<(tot + 255) / 256, 256, 0, stream>>>(ei, cursor, esrc, E, n);

    const int gx = (n + 127) / 128;
    // layer 1 (att logits fused into GEMM epilogue)
    k_mm<256><<<dim3(gx, 2), 256, 0, stream>>>(x, Wh1, Wl1, h1, ats1, atd1, as1, ad1, n);
    k_agg1<<<(n + 1) / 2, 128, 0, stream>>>(h1, as1, ad1, offs, esrc, b1, out1, n, tot);

    // layer 2 (att logits fused, atomic partials into zeroed as2/ad2)
    k_mm<128><<<dim3(gx, 1), 256, 0, stream>>>(out1, Wh2, Wl2, h2, ats2, atd2, as2, ad2, n);
    k_agg2<<<(n + 1) / 2, 128, 0, stream>>>(h2, as2, ad2, offs, esrc, b2, out2, n, tot);

    // BN + LN
    k_bnstat<<<512, 128, 0, stream>>>(out2, bnsum, bnsq, n);
    k_final<<<(n + 3) / 4, 256, 0, stream>>>(out2, bnsum, bnsq, bng, bnb, lng, lnb,
                                             (float*)d_out, n);
}

// Round 9
// 339.875 us; speedup vs baseline: 1.1840x; 1.0319x over previous
//
#include <hip/hip_runtime.h>
#include <cstdint>
#include <cstddef>

#define HEADS   8
#define NFEAT   256
#define NOUT    128
#define NEG     0.2f
#define EPSV    1e-5f

typedef unsigned short ushort_t;
typedef __attribute__((ext_vector_type(8))) short s8v;   // 8 bf16 = 4 VGPR
typedef __attribute__((ext_vector_type(4))) float f4v;   // MFMA accum

static __device__ __forceinline__ float lrelu(float x) { return x > 0.f ? x : NEG * x; }

static __device__ __forceinline__ float bf2f(ushort_t u) {
    union { unsigned int i; float f; } v; v.i = ((unsigned int)u) << 16; return v.f;
}
static __device__ __forceinline__ ushort_t f2bf(float f) {
    union { float f; unsigned int i; } v; v.f = f;
    unsigned int x = v.i;
    return (ushort_t)((x + 0x7fff + ((x >> 16) & 1)) >> 16);   // RNE
}
static __device__ __forceinline__ float bits2f(unsigned int u) {
    union { unsigned int i; float f; } v; v.i = u; return v.f;
}
static __device__ __forceinline__ unsigned int f2bits(float f) {
    union { float f; unsigned int i; } v; v.f = f; return v.i;
}

// wave-local int64-vs-int32 detection (deterministic, identical in every wave)
static __device__ __forceinline__ int detect64(const int* __restrict__ ei, int E) {
    int lane = threadIdx.x & 63;
    long idx = 2L * ((long)lane * (E / 64)) + 1;
    int v = ei[idx];
    unsigned long long ball = __ballot(v == 0);
    return (ball == ~0ull) ? 1 : 0;
}

// ---------------------------------------------------------------------------
// fused: edge-count (CSR histogram) + W hi/lo packing (disjoint block ranges)
__global__ void k_prep(const int* __restrict__ ei, int* __restrict__ counts,
                       int E, int n, int cblocks,
                       const float* __restrict__ W1, const float* __restrict__ W2,
                       ushort_t* __restrict__ Wh1, ushort_t* __restrict__ Wl1,
                       ushort_t* __restrict__ Wh2, ushort_t* __restrict__ Wl2) {
    if (blockIdx.x < (unsigned)cblocks) {
        int is64 = detect64(ei, E);
        int i = blockIdx.x * 256 + threadIdx.x;
        if (i < E) {
            int d = ei[(size_t)(E + i) << is64];
            atomicAdd(&counts[d], 1);
        } else if (i < E + n) {
            atomicAdd(&counts[i - E], 1);
        }
    } else {
        int gid = (blockIdx.x - cblocks) * 256 + threadIdx.x;
        const float* W; ushort_t* Wh; ushort_t* Wl; int M;
        if (gid < 256 * 256) { W = W1; Wh = Wh1; Wl = Wl1; M = 256; }
        else { gid -= 256 * 256; if (gid >= 256 * 128) return; W = W2; Wh = Wh2; Wl = Wl2; M = 128; }
        int k = gid / M, nn = gid - k * M;
        int ntile = nn >> 4, j = nn & 15, kc = k >> 3, e = k & 7;
        int p = ((ntile * 32 + kc) * 16 + j) * 8 + e;     // K=256 -> K/8=32
        float v = W[(size_t)k * M + nn];
        ushort_t hi = f2bf(v);
        float r = v - bf2f(hi);
        Wh[p] = hi;
        Wl[p] = f2bf(r);
    }
}

__global__ __launch_bounds__(1024) void k_scan1(const int* __restrict__ counts,
                                                int* __restrict__ incl,
                                                int* __restrict__ bsum, int n) {
    int t = threadIdx.x, i = blockIdx.x * 1024 + t;
    int lane = t & 63, w = t >> 6;
    int v = (i < n) ? counts[i] : 0;
    int sv = v;
#pragma unroll
    for (int o = 1; o < 64; o <<= 1) { int u = __shfl_up(sv, o, 64); if (lane >= o) sv += u; }
    __shared__ int wsum[16];
    if (lane == 63) wsum[w] = sv;
    __syncthreads();
    if (w == 0) {
        int bs = (lane < 16) ? wsum[lane] : 0;
#pragma unroll
        for (int o = 1; o < 16; o <<= 1) { int u = __shfl_up(bs, o, 64); if (lane >= o) bs += u; }
        if (lane < 16) wsum[lane] = bs;
    }
    __syncthreads();
    int pre = (w > 0) ? wsum[w - 1] : 0;
    sv += pre;
    if (i < n) incl[i] = sv;
    if (t == 1023) bsum[blockIdx.x] = sv;   // raw block total
}

// scan3 with folded block-sum prefix
__global__ void k_scan3(const int* __restrict__ incl, const int* __restrict__ bsum,
                        const int* __restrict__ counts,
                        int* __restrict__ offs, int* __restrict__ cursor, int n) {
    __shared__ int pre_s;
    int chunk = blockIdx.x >> 2;            // 256-thr blocks, scan1 blocks = 1024
    if (threadIdx.x == 0) {
        int s = 0;
        for (int j = 0; j < chunk; ++j) s += bsum[j];
        pre_s = s;
    }
    __syncthreads();
    int i = blockIdx.x * 256 + threadIdx.x;
    if (i < n) {
        int v = incl[i] + pre_s;
        offs[i + 1] = v;
        cursor[i] = v - counts[i];
    }
    if (i == 0) offs[0] = 0;
}

__global__ void k_fill(const int* __restrict__ ei, int* __restrict__ cursor,
                       int* __restrict__ esrc, int E, int n) {
    int is64 = detect64(ei, E);
    int i = blockIdx.x * blockDim.x + threadIdx.x;
    if (i >= E + n) return;
    int s, d;
    if (i < E) { s = ei[(size_t)i << is64]; d = ei[(size_t)(E + i) << is64]; }
    else       { s = i - E; d = s; }
    int p = atomicAdd(&cursor[d], 1);
    esrc[p] = s;
}

// ---------------------------------------------------------------------------
// MFMA GEMM, bf16x3 split precision, fused attention-logit epilogue.
// BM=64 x BN=128 tile, 4 waves; wave = 64 rows x 32 cols (acc[4][2], 32 VGPR).
// MOUT=256: wave's 32 cols = exactly one head -> direct as1/ad1 write.
// MOUT=128: single head split across 4 waves; partial + atomicAdd.
template <int MOUT>
__global__ __launch_bounds__(256) void k_mm(const float* __restrict__ A,
                                            const ushort_t* __restrict__ Wh,
                                            const ushort_t* __restrict__ Wl,
                                            ushort_t* __restrict__ C,
                                            const float* __restrict__ att_s,
                                            const float* __restrict__ att_d,
                                            float* __restrict__ as_o,
                                            float* __restrict__ ad_o, int n) {
    __shared__ ushort_t Ah[64][40];
    __shared__ ushort_t Al[64][40];
    const int t = threadIdx.x;
    const int lane = t & 63, w = t >> 6;     // w = column strip 0..3
    const int r0 = blockIdx.x * 64;
    const int srow = t >> 2;                 // staging row 0..63
    const int kh = (t & 3) * 8;              // staging k-offset 0/8/16/24
    const int arow = r0 + srow;
    const bool rowok = arow < n;

    f4v acc[4][2];
#pragma unroll
    for (int a = 0; a < 4; ++a)
#pragma unroll
        for (int b = 0; b < 2; ++b) { f4v z = {0.f, 0.f, 0.f, 0.f}; acc[a][b] = z; }

    float pre[8];
    const float* abase = &A[(size_t)arow * 256 + kh];
#pragma unroll
    for (int q = 0; q < 2; ++q) {
        float4 v = rowok ? *reinterpret_cast<const float4*>(abase + q * 4)
                         : float4{0.f, 0.f, 0.f, 0.f};
        pre[q * 4 + 0] = v.x; pre[q * 4 + 1] = v.y;
        pre[q * 4 + 2] = v.z; pre[q * 4 + 3] = v.w;
    }

    const int lj = lane & 15, lk = lane >> 4;

    for (int kb = 0; kb < 256; kb += 32) {
        __syncthreads();
        {   // convert 8 staged f32 -> hi/lo bf16 (truncation split, exact lo)
            unsigned int hw[4], lw[4];
#pragma unroll
            for (int p = 0; p < 4; ++p) {
                unsigned int x0 = f2bits(pre[p * 2]);
                unsigned int x1 = f2bits(pre[p * 2 + 1]);
                unsigned int h1b = x1 & 0xffff0000u;
                float lo0 = pre[p * 2] - bits2f(x0 & 0xffff0000u);
                float lo1 = pre[p * 2 + 1] - bits2f(h1b);
                hw[p] = (x0 >> 16) | h1b;
                lw[p] = (f2bits(lo0) >> 16) | (f2bits(lo1) & 0xffff0000u);
            }
            uint4 hv = {hw[0], hw[1], hw[2], hw[3]};
            uint4 lv = {lw[0], lw[1], lw[2], lw[3]};
            *reinterpret_cast<uint4*>(&Ah[srow][kh]) = hv;
            *reinterpret_cast<uint4*>(&Al[srow][kh]) = lv;
        }
        __syncthreads();
        if (kb < 224) {
            const float* ap = abase + kb + 32;
#pragma unroll
            for (int q = 0; q < 2; ++q) {
                float4 v = rowok ? *reinterpret_cast<const float4*>(ap + q * 4)
                                 : float4{0.f, 0.f, 0.f, 0.f};
                pre[q * 4 + 0] = v.x; pre[q * 4 + 1] = v.y;
                pre[q * 4 + 2] = v.z; pre[q * 4 + 3] = v.w;
            }
        }
        const int kc0 = kb >> 3;
        s8v ah[4], al[4];
#pragma unroll
        for (int mf = 0; mf < 4; ++mf) {
            ah[mf] = *reinterpret_cast<const s8v*>(&Ah[mf * 16 + lj][lk * 8]);
            al[mf] = *reinterpret_cast<const s8v*>(&Al[mf * 16 + lj][lk * 8]);
        }
#pragma unroll
        for (int nf = 0; nf < 2; ++nf) {
            int ntile = (MOUT == 256 ? blockIdx.y * 8 : 0) + w * 2 + nf;
            size_t boff = ((size_t)(ntile * 32 + kc0 + lk) * 16 + lj) * 8;
            s8v bh = *reinterpret_cast<const s8v*>(&Wh[boff]);
            s8v bl = *reinterpret_cast<const s8v*>(&Wl[boff]);
#pragma unroll
            for (int mf = 0; mf < 4; ++mf) {
                acc[mf][nf] = __builtin_amdgcn_mfma_f32_16x16x32_bf16(ah[mf], bh, acc[mf][nf], 0, 0, 0);
                acc[mf][nf] = __builtin_amdgcn_mfma_f32_16x16x32_bf16(ah[mf], bl, acc[mf][nf], 0, 0, 0);
                acc[mf][nf] = __builtin_amdgcn_mfma_f32_16x16x32_bf16(al[mf], bh, acc[mf][nf], 0, 0, 0);
            }
        }
    }

    const int colw = (MOUT == 256 ? blockIdx.y * 128 : 0) + w * 32;

    // C write (bf16)
#pragma unroll
    for (int mf = 0; mf < 4; ++mf) {
        int rr = r0 + mf * 16 + lk * 4;
#pragma unroll
        for (int nf = 0; nf < 2; ++nf) {
            int cc = colw + nf * 16 + lj;
#pragma unroll
            for (int r = 0; r < 4; ++r) {
                if (rr + r < n) C[(size_t)(rr + r) * MOUT + cc] = f2bf(acc[mf][nf][r]);
            }
        }
    }

    // fused attention-logit epilogue (reduce over this wave's 32 cols)
    float asv[2], adv[2];
#pragma unroll
    for (int nf = 0; nf < 2; ++nf) {
        asv[nf] = att_s[colw + nf * 16 + lj];
        adv[nf] = att_d[colw + nf * 16 + lj];
    }
#pragma unroll
    for (int mf = 0; mf < 4; ++mf) {
        int rr = r0 + mf * 16 + lk * 4;
#pragma unroll
        for (int r = 0; r < 4; ++r) {
            float ss = acc[mf][0][r] * asv[0] + acc[mf][1][r] * asv[1];
            float sd = acc[mf][0][r] * adv[0] + acc[mf][1][r] * adv[1];
#pragma unroll
            for (int o = 1; o < 16; o <<= 1) {
                ss += __shfl_xor(ss, o, 64); sd += __shfl_xor(sd, o, 64);
            }
            if (lj == 0 && rr + r < n) {
                if (MOUT == 256) {
                    int head = (colw >> 5);
                    as_o[(size_t)(rr + r) * 8 + head] = ss;
                    ad_o[(size_t)(rr + r) * 8 + head] = sd;
                } else {
                    atomicAdd(&as_o[rr + r], ss);
                    atomicAdd(&ad_o[rr + r], sd);
                }
            }
        }
    }
}

// ---------------------------------------------------------------------------
// layer-1 aggregation: half-wave per edge; exp once per (edge,head) in phase A.
__global__ __launch_bounds__(128) void k_agg1(const ushort_t* __restrict__ h1,
                                              const float* __restrict__ as1,
                                              const float* __restrict__ ad1,
                                              const int* __restrict__ offs,
                                              const int* __restrict__ esrc,
                                              const float* __restrict__ b1,
                                              float* __restrict__ out1, int n, int tot) {
    int wid = (blockIdx.x * 128 + threadIdx.x) >> 6;
    int lane = threadIdx.x & 63;
    if (wid >= n) return;
    int e0 = offs[wid], e1 = offs[wid + 1];
    int deg = e1 - e0;

    if (deg <= 64) {
        const int l = lane & 31;          // channel-group lane
        const int h = lane >> 5;          // half: edge parity
        const int hd = l >> 2;            // head owning channels l*8..l*8+7
        const int cb = l * 8;

        int ei_idx = e0 + lane;
        int es = esrc[ei_idx < tot ? ei_idx : (tot - 1)];

        const int headA = lane >> 3, g = lane & 7;
        float adnA = ad1[(size_t)wid * 8 + headA];
        float a[8];
#pragma unroll
        for (int k = 0; k < 8; ++k) {
            int i = g + 8 * k;
            int s = __shfl(es, i, 64);
            a[k] = (i < deg) ? as1[(size_t)s * 8 + headA] : -1e30f;
        }
        float mx = a[0];
#pragma unroll
        for (int k = 1; k < 8; ++k) mx = fmaxf(mx, a[k]);
#pragma unroll
        for (int o = 1; o < 8; o <<= 1) mx = fmaxf(mx, __shfl_xor(mx, o, 64));
        float mA = lrelu(mx + adnA);
#pragma unroll
        for (int k = 0; k < 8; ++k)
            a[k] = __expf(lrelu(a[k] + adnA) - mA);   // p, 0 for padding

        float d = 0.f;
        float ac0 = 0.f, ac1 = 0.f, ac2 = 0.f, ac3 = 0.f;
        float ac4 = 0.f, ac5 = 0.f, ac6 = 0.f, ac7 = 0.f;
#pragma unroll
        for (int u = 0; u < 8; ++u) {
            if (8 * u < deg) {
#pragma unroll
                for (int v = 0; v < 4; ++v) {
                    int i = 8 * u + 2 * v + h;
                    int s = __shfl(es, i, 64);
                    float p = __shfl(a[u], hd * 8 + 2 * v + h, 64);
                    if (i < deg) {
                        uint4 hv = *reinterpret_cast<const uint4*>(&h1[(size_t)s * 256 + cb]);
                        d += p;
                        ac0 += p * bits2f(hv.x << 16);
                        ac1 += p * bits2f(hv.x & 0xffff0000u);
                        ac2 += p * bits2f(hv.y << 16);
                        ac3 += p * bits2f(hv.y & 0xffff0000u);
                        ac4 += p * bits2f(hv.z << 16);
                        ac5 += p * bits2f(hv.z & 0xffff0000u);
                        ac6 += p * bits2f(hv.w << 16);
                        ac7 += p * bits2f(hv.w & 0xffff0000u);
                    }
                }
            }
        }
        d   += __shfl_xor(d, 32, 64);
        ac0 += __shfl_xor(ac0, 32, 64); ac1 += __shfl_xor(ac1, 32, 64);
        ac2 += __shfl_xor(ac2, 32, 64); ac3 += __shfl_xor(ac3, 32, 64);
        ac4 += __shfl_xor(ac4, 32, 64); ac5 += __shfl_xor(ac5, 32, 64);
        ac6 += __shfl_xor(ac6, 32, 64); ac7 += __shfl_xor(ac7, 32, 64);
        if (lane < 32) {
            float inv = 1.f / (d + 1e-16f);
            float4 b0 = *reinterpret_cast<const float4*>(&b1[cb]);
            float4 b4 = *reinterpret_cast<const float4*>(&b1[cb + 4]);
            float4 o0, o1;
            o0.x = fmaxf(ac0 * inv + b0.x, 0.f);
            o0.y = fmaxf(ac1 * inv + b0.y, 0.f);
            o0.z = fmaxf(ac2 * inv + b0.z, 0.f);
            o0.w = fmaxf(ac3 * inv + b0.w, 0.f);
            o1.x = fmaxf(ac4 * inv + b4.x, 0.f);
            o1.y = fmaxf(ac5 * inv + b4.y, 0.f);
            o1.z = fmaxf(ac6 * inv + b4.z, 0.f);
            o1.w = fmaxf(ac7 * inv + b4.w, 0.f);
            *reinterpret_cast<float4*>(&out1[(size_t)wid * 256 + cb]) = o0;
            *reinterpret_cast<float4*>(&out1[(size_t)wid * 256 + cb + 4]) = o1;
        }
    } else {
        int head = lane >> 3;
        int g = lane & 7;
        int cb = lane * 4;
        float adn = ad1[(size_t)wid * 8 + head];
        float mx = -1e30f;
        for (int e = e0 + g; e < e1; e += 8)
            mx = fmaxf(mx, as1[(size_t)esrc[e] * 8 + head]);
#pragma unroll
        for (int o = 1; o < 8; o <<= 1) mx = fmaxf(mx, __shfl_xor(mx, o, 64));
        float m = lrelu(mx + adn);
        float d = 0.f, ax = 0.f, ay = 0.f, az = 0.f, aw = 0.f;
        for (int e = e0; e < e1; ++e) {
            int s = esrc[e];
            float p = __expf(lrelu(as1[(size_t)s * 8 + head] + adn) - m);
            ushort4 hv = *reinterpret_cast<const ushort4*>(&h1[(size_t)s * 256 + cb]);
            d += p;
            ax += p * bf2f(hv.x);
            ay += p * bf2f(hv.y);
            az += p * bf2f(hv.z);
            aw += p * bf2f(hv.w);
        }
        float inv = 1.f / (d + 1e-16f);
        float4 bb = *reinterpret_cast<const float4*>(&b1[cb]);
        float4 o;
        o.x = fmaxf(ax * inv + bb.x, 0.f);
        o.y = fmaxf(ay * inv + bb.y, 0.f);
        o.z = fmaxf(az * inv + bb.z, 0.f);
        o.w = fmaxf(aw * inv + bb.w, 0.f);
        *reinterpret_cast<float4*>(&out1[(size_t)wid * 256 + cb]) = o;
    }
}

// layer-2 aggregation: quarter-wave per edge; exp once per edge.
__global__ __launch_bounds__(128) void k_agg2(const ushort_t* __restrict__ h2,
                                              const float* __restrict__ as2,
                                              const float* __restrict__ ad2,
                                              const int* __restrict__ offs,
                                              const int* __restrict__ esrc,
                                              const float* __restrict__ b2,
                                              float* __restrict__ out2, int n, int tot) {
    int wid = (blockIdx.x * 128 + threadIdx.x) >> 6;
    int lane = threadIdx.x & 63;
    if (wid >= n) return;
    float adn = ad2[wid];
    int e0 = offs[wid], e1 = offs[wid + 1];
    int deg = e1 - e0;

    if (deg <= 64) {
        const int l = lane & 15;
        const int q = lane >> 4;
        const int cb = l * 8;

        int ei_idx = e0 + lane;
        int es = esrc[ei_idx < tot ? ei_idx : (tot - 1)];
        float av0 = (lane < deg) ? as2[es] : -1e30f;
        float mx = av0;
#pragma unroll
        for (int o = 1; o < 64; o <<= 1) mx = fmaxf(mx, __shfl_xor(mx, o, 64));
        float m = lrelu(mx + adn);
        float p0 = __expf(lrelu(av0 + adn) - m);   // one exp per edge

        float d = 0.f;
        float ac0 = 0.f, ac1 = 0.f, ac2 = 0.f, ac3 = 0.f;
        float ac4 = 0.f, ac5 = 0.f, ac6 = 0.f, ac7 = 0.f;
#pragma unroll
        for (int u = 0; u < 4; ++u) {
            if (16 * u < deg) {
#pragma unroll
                for (int v = 0; v < 4; ++v) {
                    int i = 16 * u + 4 * v + q;
                    int s = __shfl(es, i, 64);
                    float p = __shfl(p0, i, 64);
                    if (i < deg) {
                        uint4 hv = *reinterpret_cast<const uint4*>(&h2[(size_t)s * 128 + cb]);
                        d += p;
                        ac0 += p * bits2f(hv.x << 16);
                        ac1 += p * bits2f(hv.x & 0xffff0000u);
                        ac2 += p * bits2f(hv.y << 16);
                        ac3 += p * bits2f(hv.y & 0xffff0000u);
                        ac4 += p * bits2f(hv.z << 16);
                        ac5 += p * bits2f(hv.z & 0xffff0000u);
                        ac6 += p * bits2f(hv.w << 16);
                        ac7 += p * bits2f(hv.w & 0xffff0000u);
                    }
                }
            }
        }
#pragma unroll
        for (int o = 16; o <= 32; o <<= 1) {
            d   += __shfl_xor(d, o, 64);
            ac0 += __shfl_xor(ac0, o, 64); ac1 += __shfl_xor(ac1, o, 64);
            ac2 += __shfl_xor(ac2, o, 64); ac3 += __shfl_xor(ac3, o, 64);
            ac4 += __shfl_xor(ac4, o, 64); ac5 += __shfl_xor(ac5, o, 64);
            ac6 += __shfl_xor(ac6, o, 64); ac7 += __shfl_xor(ac7, o, 64);
        }
        if (lane < 16) {
            float inv = 1.f / (d + 1e-16f);
            float4 b0 = *reinterpret_cast<const float4*>(&b2[cb]);
            float4 b4 = *reinterpret_cast<const float4*>(&b2[cb + 4]);
            float4 o0, o1;
            o0.x = fmaxf(ac0 * inv + b0.x, 0.f);
            o0.y = fmaxf(ac1 * inv + b0.y, 0.f);
            o0.z = fmaxf(ac2 * inv + b0.z, 0.f);
            o0.w = fmaxf(ac3 * inv + b0.w, 0.f);
            o1.x = fmaxf(ac4 * inv + b4.x, 0.f);
            o1.y = fmaxf(ac5 * inv + b4.y, 0.f);
            o1.z = fmaxf(ac6 * inv + b4.z, 0.f);
            o1.w = fmaxf(ac7 * inv + b4.w, 0.f);
            *reinterpret_cast<float4*>(&out2[(size_t)wid * 128 + cb]) = o0;
            *reinterpret_cast<float4*>(&out2[(size_t)wid * 128 + cb + 4]) = o1;
        }
    } else {
        int cb = lane * 2;
        float mx = -1e30f;
        for (int e = e0 + lane; e < e1; e += 64)
            mx = fmaxf(mx, as2[esrc[e]]);
#pragma unroll
        for (int o = 1; o < 64; o <<= 1) mx = fmaxf(mx, __shfl_xor(mx, o, 64));
        float m = lrelu(mx + adn);
        float d = 0.f, ax = 0.f, ay = 0.f;
        for (int e = e0; e < e1; ++e) {
            int s = esrc[e];
            float p = __expf(lrelu(as2[s] + adn) - m);
            ushort2 hv = *reinterpret_cast<const ushort2*>(&h2[(size_t)s * 128 + cb]);
            d += p;
            ax += p * bf2f(hv.x);
            ay += p * bf2f(hv.y);
        }
        float inv = 1.f / (d + 1e-16f);
        float o0 = fmaxf(ax * inv + b2[cb], 0.f);
        float o1 = fmaxf(ay * inv + b2[cb + 1], 0.f);
        float2 o = {o0, o1};
        *reinterpret_cast<float2*>(&out2[(size_t)wid * 128 + cb]) = o;
    }
}

// ---------------------------------------------------------------------------
__global__ __launch_bounds__(128) void k_bnstat(const float* __restrict__ out2,
                                                float* __restrict__ bnsum,
                                                float* __restrict__ bnsq, int n) {
    int c = threadIdx.x;
    float s = 0.f, q = 0.f;
    for (int r = blockIdx.x; r < n; r += gridDim.x) {
        float v = out2[(size_t)r * 128 + c];
        s += v;
        q += v * v;
    }
    atomicAdd(&bnsum[c], s);
    atomicAdd(&bnsq[c], q);
}

__global__ __launch_bounds__(256) void k_final(const float* __restrict__ out2,
                                               const float* __restrict__ bnsum,
                                               const float* __restrict__ bnsq,
                                               const float* __restrict__ bng,
                                               const float* __restrict__ bnb,
                                               const float* __restrict__ lng,
                                               const float* __restrict__ lnb,
                                               float* __restrict__ out, int n) {
    int wid = (blockIdx.x * blockDim.x + threadIdx.x) >> 6;
    int lane = threadIdx.x & 63;
    if (wid >= n) return;
    int c0 = lane, c1 = lane + 64;
    float invn = 1.f / (float)n;
    float mu0 = bnsum[c0] * invn, mu1 = bnsum[c1] * invn;
    float v0 = bnsq[c0] * invn - mu0 * mu0;
    float v1 = bnsq[c1] * invn - mu1 * mu1;
    float r0 = rsqrtf(v0 + EPSV), r1 = rsqrtf(v1 + EPSV);
    float x0 = out2[(size_t)wid * 128 + c0];
    float x1 = out2[(size_t)wid * 128 + c1];
    float y0 = (x0 - mu0) * r0 * bng[c0] + bnb[c0];
    float y1 = (x1 - mu1) * r1 * bng[c1] + bnb[c1];
    float s = y0 + y1, q = y0 * y0 + y1 * y1;
#pragma unroll
    for (int o = 1; o < 64; o <<= 1) { s += __shfl_xor(s, o, 64); q += __shfl_xor(q, o, 64); }
    float mu = s * (1.f / 128.f);
    float var = q * (1.f / 128.f) - mu * mu;
    float rr = rsqrtf(var + EPSV);
    out[(size_t)wid * 128 + c0] = (y0 - mu) * rr * lng[c0] + lnb[c0];
    out[(size_t)wid * 128 + c1] = (y1 - mu) * rr * lng[c1] + lnb[c1];
}

// ---------------------------------------------------------------------------
extern "C" void kernel_launch(void* const* d_in, const int* in_sizes, int n_in,
                              void* d_out, int out_size, void* d_ws, size_t ws_size,
                              hipStream_t stream) {
    const float* x    = (const float*)d_in[0];
    const int*   ei   = (const int*)d_in[1];
    const float* W1   = (const float*)d_in[2];
    const float* ats1 = (const float*)d_in[3];
    const float* atd1 = (const float*)d_in[4];
    const float* b1   = (const float*)d_in[5];
    const float* W2   = (const float*)d_in[6];
    const float* ats2 = (const float*)d_in[7];
    const float* atd2 = (const float*)d_in[8];
    const float* b2   = (const float*)d_in[9];
    const float* bng  = (const float*)d_in[10];
    const float* bnb  = (const float*)d_in[11];
    const float* lng  = (const float*)d_in[12];
    const float* lnb  = (const float*)d_in[13];

    const int n = in_sizes[0] / NFEAT;   // 50000
    const int E = in_sizes[1] / 2;       // 800000
    const int tot = E + n;

    auto align = [](size_t v) { return (v + 255) & ~(size_t)255; };
    char* ws = (char*)d_ws;
    size_t off = 0;
    ushort_t* h1 = (ushort_t*)(ws + off); off += align((size_t)n * 256 * 2);
    float* out1 = (float*)(ws + off); off += align((size_t)n * 256 * 4);
    ushort_t* h2 = h1;
    float* out2 = out1;
    float* as1 = (float*)(ws + off); off += align((size_t)n * 8 * 4);
    float* ad1 = (float*)(ws + off); off += align((size_t)n * 8 * 4);
    // zero-region: counts[n] | bnsum[128] | bnsq[128] | as2[n] | ad2[n]
    int* counts = (int*)(ws + off); off += align((size_t)n * 12 + 1024);
    float* bnsum = (float*)(counts + n);
    float* bnsq  = bnsum + 128;
    float* as2   = bnsq + 128;
    float* ad2   = as2 + n;
    int* offs   = (int*)(ws + off); off += align((size_t)(n + 1) * 4);
    int* cursor = (int*)(ws + off); off += align((size_t)n * 4);
    int* esrc   = (int*)(ws + off); off += align((size_t)tot * 4);
    int* incl   = (int*)(ws + off); off += align((size_t)n * 4);
    int* bsum   = (int*)(ws + off); off += align(64 * 4);
    ushort_t* Wh1 = (ushort_t*)(ws + off); off += align((size_t)256 * 256 * 2);
    ushort_t* Wl1 = (ushort_t*)(ws + off); off += align((size_t)256 * 256 * 2);
    ushort_t* Wh2 = (ushort_t*)(ws + off); off += align((size_t)256 * 128 * 2);
    ushort_t* Wl2 = (ushort_t*)(ws + off); off += align((size_t)256 * 128 * 2);

    hipMemsetAsync(counts, 0, (size_t)n * 12 + 1024, stream);

    // fused count + W-pack
    const int cblocks = (tot + 255) / 256;
    const int pblocks = (256 * 256 + 256 * 128 + 255) / 256;
    k_prep<<<cblocks + pblocks, 256, 0, stream>>>(ei, counts, E, n, cblocks,
                                                  W1, W2, Wh1, Wl1, Wh2, Wl2);
    int nsb = (n + 1023) / 1024;
    k_scan1<<<nsb, 1024, 0, stream>>>(counts, incl, bsum, n);
    k_scan3<<<(n + 255) / 256, 256, 0, stream>>>(incl, bsum, counts, offs, cursor, n);
    k_fill<<<(tot + 255) / 256, 256, 0, stream>>>(ei, cursor, esrc, E, n);

    const int gx = (n + 63) / 64;
    // layer 1 (att logits fused into GEMM epilogue)
    k_mm<256><<<dim3(gx, 2), 256, 0, stream>>>(x, Wh1, Wl1, h1, ats1, atd1, as1, ad1, n);
    k_agg1<<<(n + 1) / 2, 128, 0, stream>>>(h1, as1, ad1, offs, esrc, b1, out1, n, tot);

    // layer 2 (att logits fused, atomic partials into zeroed as2/ad2)
    k_mm<128><<<dim3(gx, 1), 256, 0, stream>>>(out1, Wh2, Wl2, h2, ats2, atd2, as2, ad2, n);
    k_agg2<<<(n + 1) / 2, 128, 0, stream>>>(h2, as2, ad2, offs, esrc, b2, out2, n, tot);

    // BN + LN
    k_bnstat<<<512, 128, 0, stream>>>(out2, bnsum, bnsq, n);
    k_final<<<(n + 3) / 4, 256, 0, stream>>>(out2, bnsum, bnsq, bng, bnb, lng, lnb,
                                             (float*)d_out, n);
}

// Round 10
// 324.461 us; speedup vs baseline: 1.2402x; 1.0475x over previous
//
#include <hip/hip_runtime.h>
#include <cstdint>
#include <cstddef>

#define HEADS   8
#define NFEAT   256
#define NOUT    128
#define NEG     0.2f
#define EPSV    1e-5f

typedef unsigned short ushort_t;
typedef __attribute__((ext_vector_type(8))) short s8v;   // 8 bf16 = 4 VGPR
typedef __attribute__((ext_vector_type(4))) float f4v;   // MFMA accum

static __device__ __forceinline__ float lrelu(float x) { return x > 0.f ? x : NEG * x; }

static __device__ __forceinline__ float bf2f(ushort_t u) {
    union { unsigned int i; float f; } v; v.i = ((unsigned int)u) << 16; return v.f;
}
static __device__ __forceinline__ ushort_t f2bf(float f) {
    union { float f; unsigned int i; } v; v.f = f;
    unsigned int x = v.i;
    return (ushort_t)((x + 0x7fff + ((x >> 16) & 1)) >> 16);   // RNE
}
static __device__ __forceinline__ float bits2f(unsigned int u) {
    union { unsigned int i; float f; } v; v.i = u; return v.f;
}
static __device__ __forceinline__ unsigned int f2bits(float f) {
    union { float f; unsigned int i; } v; v.f = f; return v.i;
}

// wave-local int64-vs-int32 detection (deterministic, identical in every wave)
static __device__ __forceinline__ int detect64(const int* __restrict__ ei, int E) {
    int lane = threadIdx.x & 63;
    long idx = 2L * ((long)lane * (E / 64)) + 1;
    int v = ei[idx];
    unsigned long long ball = __ballot(v == 0);
    return (ball == ~0ull) ? 1 : 0;
}

// ---------------------------------------------------------------------------
// fused: edge-count (CSR histogram) + W hi/lo packing (disjoint block ranges)
__global__ void k_prep(const int* __restrict__ ei, int* __restrict__ counts,
                       int E, int n, int cblocks,
                       const float* __restrict__ W1, const float* __restrict__ W2,
                       ushort_t* __restrict__ Wh1, ushort_t* __restrict__ Wl1,
                       ushort_t* __restrict__ Wh2, ushort_t* __restrict__ Wl2) {
    if (blockIdx.x < (unsigned)cblocks) {
        int is64 = detect64(ei, E);
        int i = blockIdx.x * 256 + threadIdx.x;
        if (i < E) {
            int d = ei[(size_t)(E + i) << is64];
            atomicAdd(&counts[d], 1);
        } else if (i < E + n) {
            atomicAdd(&counts[i - E], 1);
        }
    } else {
        int gid = (blockIdx.x - cblocks) * 256 + threadIdx.x;
        const float* W; ushort_t* Wh; ushort_t* Wl; int M;
        if (gid < 256 * 256) { W = W1; Wh = Wh1; Wl = Wl1; M = 256; }
        else { gid -= 256 * 256; if (gid >= 256 * 128) return; W = W2; Wh = Wh2; Wl = Wl2; M = 128; }
        int k = gid / M, nn = gid - k * M;
        int ntile = nn >> 4, j = nn & 15, kc = k >> 3, e = k & 7;
        int p = ((ntile * 32 + kc) * 16 + j) * 8 + e;     // K=256 -> K/8=32
        float v = W[(size_t)k * M + nn];
        ushort_t hi = f2bf(v);
        float r = v - bf2f(hi);
        Wh[p] = hi;
        Wl[p] = f2bf(r);
    }
}

__global__ __launch_bounds__(1024) void k_scan1(const int* __restrict__ counts,
                                                int* __restrict__ incl,
                                                int* __restrict__ bsum, int n) {
    int t = threadIdx.x, i = blockIdx.x * 1024 + t;
    int lane = t & 63, w = t >> 6;
    int v = (i < n) ? counts[i] : 0;
    int sv = v;
#pragma unroll
    for (int o = 1; o < 64; o <<= 1) { int u = __shfl_up(sv, o, 64); if (lane >= o) sv += u; }
    __shared__ int wsum[16];
    if (lane == 63) wsum[w] = sv;
    __syncthreads();
    if (w == 0) {
        int bs = (lane < 16) ? wsum[lane] : 0;
#pragma unroll
        for (int o = 1; o < 16; o <<= 1) { int u = __shfl_up(bs, o, 64); if (lane >= o) bs += u; }
        if (lane < 16) wsum[lane] = bs;
    }
    __syncthreads();
    int pre = (w > 0) ? wsum[w - 1] : 0;
    sv += pre;
    if (i < n) incl[i] = sv;
    if (t == 1023) bsum[blockIdx.x] = sv;   // raw block total
}

// scan3 with folded block-sum prefix
__global__ void k_scan3(const int* __restrict__ incl, const int* __restrict__ bsum,
                        const int* __restrict__ counts,
                        int* __restrict__ offs, int* __restrict__ cursor, int n) {
    __shared__ int pre_s;
    int chunk = blockIdx.x >> 2;            // 256-thr blocks, scan1 blocks = 1024
    if (threadIdx.x == 0) {
        int s = 0;
        for (int j = 0; j < chunk; ++j) s += bsum[j];
        pre_s = s;
    }
    __syncthreads();
    int i = blockIdx.x * 256 + threadIdx.x;
    if (i < n) {
        int v = incl[i] + pre_s;
        offs[i + 1] = v;
        cursor[i] = v - counts[i];
    }
    if (i == 0) offs[0] = 0;
}

__global__ void k_fill(const int* __restrict__ ei, int* __restrict__ cursor,
                       int* __restrict__ esrc, int E, int n) {
    int is64 = detect64(ei, E);
    int i = blockIdx.x * blockDim.x + threadIdx.x;
    if (i >= E + n) return;
    int s, d;
    if (i < E) { s = ei[(size_t)i << is64]; d = ei[(size_t)(E + i) << is64]; }
    else       { s = i - E; d = s; }
    int p = atomicAdd(&cursor[d], 1);
    esrc[p] = s;
}

// ---------------------------------------------------------------------------
// MFMA GEMM v3: bf16x3 split precision, fused att-logit epilogue.
// BM=64 x BN=128, 4 waves, wave = 64x32. Single-barrier double-buffered
// K-loop: A-prefetch + B loads issued at barrier-exit so they complete under
// the MFMAs; barrier drain has nothing outstanding.
template <int MOUT>
__global__ __launch_bounds__(256) void k_mm(const float* __restrict__ A,
                                            const ushort_t* __restrict__ Wh,
                                            const ushort_t* __restrict__ Wl,
                                            ushort_t* __restrict__ C,
                                            const float* __restrict__ att_s,
                                            const float* __restrict__ att_d,
                                            float* __restrict__ as_o,
                                            float* __restrict__ ad_o, int n) {
    __shared__ ushort_t Ah[2][64][40];
    __shared__ ushort_t Al[2][64][40];
    const int t = threadIdx.x;
    const int lane = t & 63, w = t >> 6;     // w = column strip 0..3
    const int r0 = blockIdx.x * 64;
    const int srow = t >> 2;                 // staging row 0..63
    const int kh = (t & 3) * 8;              // staging k-offset 0/8/16/24
    const int arow = r0 + srow;
    const bool rowok = arow < n;
    const int lj = lane & 15, lk = lane >> 4;

    f4v acc[4][2];
#pragma unroll
    for (int a = 0; a < 4; ++a)
#pragma unroll
        for (int b = 0; b < 2; ++b) { f4v z = {0.f, 0.f, 0.f, 0.f}; acc[a][b] = z; }

    const float* abase = &A[(size_t)arow * 256 + kh];
    float pre[8];

    // prologue: stage K-step 0 into buf 0
#pragma unroll
    for (int q = 0; q < 2; ++q) {
        float4 v = rowok ? *reinterpret_cast<const float4*>(abase + q * 4)
                         : float4{0.f, 0.f, 0.f, 0.f};
        pre[q * 4 + 0] = v.x; pre[q * 4 + 1] = v.y;
        pre[q * 4 + 2] = v.z; pre[q * 4 + 3] = v.w;
    }
    {
        unsigned int hw[4], lw[4];
#pragma unroll
        for (int p = 0; p < 4; ++p) {
            unsigned int x0 = f2bits(pre[p * 2]);
            unsigned int x1 = f2bits(pre[p * 2 + 1]);
            unsigned int h1b = x1 & 0xffff0000u;
            float lo0 = pre[p * 2] - bits2f(x0 & 0xffff0000u);
            float lo1 = pre[p * 2 + 1] - bits2f(h1b);
            hw[p] = (x0 >> 16) | h1b;
            lw[p] = (f2bits(lo0) >> 16) | (f2bits(lo1) & 0xffff0000u);
        }
        uint4 hv = {hw[0], hw[1], hw[2], hw[3]};
        uint4 lv = {lw[0], lw[1], lw[2], lw[3]};
        *reinterpret_cast<uint4*>(&Ah[0][srow][kh]) = hv;
        *reinterpret_cast<uint4*>(&Al[0][srow][kh]) = lv;
    }
    __syncthreads();

    for (int kb = 0; kb < 256; kb += 32) {
        const int cur = (kb >> 5) & 1;
        // (1) A-prefetch for next step — issued first, consumed at step end
        if (kb < 224) {
            const float* ap = abase + kb + 32;
#pragma unroll
            for (int q = 0; q < 2; ++q) {
                float4 v = rowok ? *reinterpret_cast<const float4*>(ap + q * 4)
                                 : float4{0.f, 0.f, 0.f, 0.f};
                pre[q * 4 + 0] = v.x; pre[q * 4 + 1] = v.y;
                pre[q * 4 + 2] = v.z; pre[q * 4 + 3] = v.w;
            }
        }
        // (2) B loads (L2) — complete under ds_read + MFMA
        const int kc0 = kb >> 3;
        s8v bh[2], bl[2];
#pragma unroll
        for (int nf = 0; nf < 2; ++nf) {
            int ntile = (MOUT == 256 ? blockIdx.y * 8 : 0) + w * 2 + nf;
            size_t boff = ((size_t)(ntile * 32 + kc0 + lk) * 16 + lj) * 8;
            bh[nf] = *reinterpret_cast<const s8v*>(&Wh[boff]);
            bl[nf] = *reinterpret_cast<const s8v*>(&Wl[boff]);
        }
        // (3) LDS -> A fragments
        s8v ah[4], al[4];
#pragma unroll
        for (int mf = 0; mf < 4; ++mf) {
            ah[mf] = *reinterpret_cast<const s8v*>(&Ah[cur][mf * 16 + lj][lk * 8]);
            al[mf] = *reinterpret_cast<const s8v*>(&Al[cur][mf * 16 + lj][lk * 8]);
        }
        // (4) MFMA
#pragma unroll
        for (int nf = 0; nf < 2; ++nf)
#pragma unroll
            for (int mf = 0; mf < 4; ++mf) {
                acc[mf][nf] = __builtin_amdgcn_mfma_f32_16x16x32_bf16(ah[mf], bh[nf], acc[mf][nf], 0, 0, 0);
                acc[mf][nf] = __builtin_amdgcn_mfma_f32_16x16x32_bf16(ah[mf], bl[nf], acc[mf][nf], 0, 0, 0);
                acc[mf][nf] = __builtin_amdgcn_mfma_f32_16x16x32_bf16(al[mf], bh[nf], acc[mf][nf], 0, 0, 0);
            }
        // (5) convert + stage next step into the other buffer
        if (kb < 224) {
            unsigned int hw[4], lw[4];
#pragma unroll
            for (int p = 0; p < 4; ++p) {
                unsigned int x0 = f2bits(pre[p * 2]);
                unsigned int x1 = f2bits(pre[p * 2 + 1]);
                unsigned int h1b = x1 & 0xffff0000u;
                float lo0 = pre[p * 2] - bits2f(x0 & 0xffff0000u);
                float lo1 = pre[p * 2 + 1] - bits2f(h1b);
                hw[p] = (x0 >> 16) | h1b;
                lw[p] = (f2bits(lo0) >> 16) | (f2bits(lo1) & 0xffff0000u);
            }
            uint4 hv = {hw[0], hw[1], hw[2], hw[3]};
            uint4 lv = {lw[0], lw[1], lw[2], lw[3]};
            *reinterpret_cast<uint4*>(&Ah[cur ^ 1][srow][kh]) = hv;
            *reinterpret_cast<uint4*>(&Al[cur ^ 1][srow][kh]) = lv;
        }
        // (6) single barrier per step
        __syncthreads();
    }

    const int colw = (MOUT == 256 ? blockIdx.y * 128 : 0) + w * 32;

    // C write (bf16)
#pragma unroll
    for (int mf = 0; mf < 4; ++mf) {
        int rr = r0 + mf * 16 + lk * 4;
#pragma unroll
        for (int nf = 0; nf < 2; ++nf) {
            int cc = colw + nf * 16 + lj;
#pragma unroll
            for (int r = 0; r < 4; ++r) {
                if (rr + r < n) C[(size_t)(rr + r) * MOUT + cc] = f2bf(acc[mf][nf][r]);
            }
        }
    }

    // fused attention-logit epilogue (reduce over this wave's 32 cols)
    float asv[2], adv[2];
#pragma unroll
    for (int nf = 0; nf < 2; ++nf) {
        asv[nf] = att_s[colw + nf * 16 + lj];
        adv[nf] = att_d[colw + nf * 16 + lj];
    }
#pragma unroll
    for (int mf = 0; mf < 4; ++mf) {
        int rr = r0 + mf * 16 + lk * 4;
#pragma unroll
        for (int r = 0; r < 4; ++r) {
            float ss = acc[mf][0][r] * asv[0] + acc[mf][1][r] * asv[1];
            float sd = acc[mf][0][r] * adv[0] + acc[mf][1][r] * adv[1];
#pragma unroll
            for (int o = 1; o < 16; o <<= 1) {
                ss += __shfl_xor(ss, o, 64); sd += __shfl_xor(sd, o, 64);
            }
            if (lj == 0 && rr + r < n) {
                if (MOUT == 256) {
                    int head = (colw >> 5);
                    as_o[(size_t)(rr + r) * 8 + head] = ss;
                    ad_o[(size_t)(rr + r) * 8 + head] = sd;
                } else {
                    atomicAdd(&as_o[rr + r], ss);
                    atomicAdd(&ad_o[rr + r], sd);
                }
            }
        }
    }
}

// ---------------------------------------------------------------------------
// layer-1 aggregation: half-wave per edge; exp once per (edge,head) in phase A.
__global__ __launch_bounds__(128) void k_agg1(const ushort_t* __restrict__ h1,
                                              const float* __restrict__ as1,
                                              const float* __restrict__ ad1,
                                              const int* __restrict__ offs,
                                              const int* __restrict__ esrc,
                                              const float* __restrict__ b1,
                                              float* __restrict__ out1, int n, int tot) {
    int wid = (blockIdx.x * 128 + threadIdx.x) >> 6;
    int lane = threadIdx.x & 63;
    if (wid >= n) return;
    int e0 = offs[wid], e1 = offs[wid + 1];
    int deg = e1 - e0;

    if (deg <= 64) {
        const int l = lane & 31;          // channel-group lane
        const int h = lane >> 5;          // half: edge parity
        const int hd = l >> 2;            // head owning channels l*8..l*8+7
        const int cb = l * 8;

        int ei_idx = e0 + lane;
        int es = esrc[ei_idx < tot ? ei_idx : (tot - 1)];

        const int headA = lane >> 3, g = lane & 7;
        float adnA = ad1[(size_t)wid * 8 + headA];
        float a[8];
#pragma unroll
        for (int k = 0; k < 8; ++k) {
            int i = g + 8 * k;
            int s = __shfl(es, i, 64);
            a[k] = (i < deg) ? as1[(size_t)s * 8 + headA] : -1e30f;
        }
        float mx = a[0];
#pragma unroll
        for (int k = 1; k < 8; ++k) mx = fmaxf(mx, a[k]);
#pragma unroll
        for (int o = 1; o < 8; o <<= 1) mx = fmaxf(mx, __shfl_xor(mx, o, 64));
        float mA = lrelu(mx + adnA);
#pragma unroll
        for (int k = 0; k < 8; ++k)
            a[k] = __expf(lrelu(a[k] + adnA) - mA);   // p, 0 for padding

        float d = 0.f;
        float ac0 = 0.f, ac1 = 0.f, ac2 = 0.f, ac3 = 0.f;
        float ac4 = 0.f, ac5 = 0.f, ac6 = 0.f, ac7 = 0.f;
#pragma unroll
        for (int u = 0; u < 8; ++u) {
            if (8 * u < deg) {
#pragma unroll
                for (int v = 0; v < 4; ++v) {
                    int i = 8 * u + 2 * v + h;
                    int s = __shfl(es, i, 64);
                    float p = __shfl(a[u], hd * 8 + 2 * v + h, 64);
                    if (i < deg) {
                        uint4 hv = *reinterpret_cast<const uint4*>(&h1[(size_t)s * 256 + cb]);
                        d += p;
                        ac0 += p * bits2f(hv.x << 16);
                        ac1 += p * bits2f(hv.x & 0xffff0000u);
                        ac2 += p * bits2f(hv.y << 16);
                        ac3 += p * bits2f(hv.y & 0xffff0000u);
                        ac4 += p * bits2f(hv.z << 16);
                        ac5 += p * bits2f(hv.z & 0xffff0000u);
                        ac6 += p * bits2f(hv.w << 16);
                        ac7 += p * bits2f(hv.w & 0xffff0000u);
                    }
                }
            }
        }
        d   += __shfl_xor(d, 32, 64);
        ac0 += __shfl_xor(ac0, 32, 64); ac1 += __shfl_xor(ac1, 32, 64);
        ac2 += __shfl_xor(ac2, 32, 64); ac3 += __shfl_xor(ac3, 32, 64);
        ac4 += __shfl_xor(ac4, 32, 64); ac5 += __shfl_xor(ac5, 32, 64);
        ac6 += __shfl_xor(ac6, 32, 64); ac7 += __shfl_xor(ac7, 32, 64);
        if (lane < 32) {
            float inv = 1.f / (d + 1e-16f);
            float4 b0 = *reinterpret_cast<const float4*>(&b1[cb]);
            float4 b4 = *reinterpret_cast<const float4*>(&b1[cb + 4]);
            float4 o0, o1;
            o0.x = fmaxf(ac0 * inv + b0.x, 0.f);
            o0.y = fmaxf(ac1 * inv + b0.y, 0.f);
            o0.z = fmaxf(ac2 * inv + b0.z, 0.f);
            o0.w = fmaxf(ac3 * inv + b0.w, 0.f);
            o1.x = fmaxf(ac4 * inv + b4.x, 0.f);
            o1.y = fmaxf(ac5 * inv + b4.y, 0.f);
            o1.z = fmaxf(ac6 * inv + b4.z, 0.f);
            o1.w = fmaxf(ac7 * inv + b4.w, 0.f);
            *reinterpret_cast<float4*>(&out1[(size_t)wid * 256 + cb]) = o0;
            *reinterpret_cast<float4*>(&out1[(size_t)wid * 256 + cb + 4]) = o1;
        }
    } else {
        int head = lane >> 3;
        int g = lane & 7;
        int cb = lane * 4;
        float adn = ad1[(size_t)wid * 8 + head];
        float mx = -1e30f;
        for (int e = e0 + g; e < e1; e += 8)
            mx = fmaxf(mx, as1[(size_t)esrc[e] * 8 + head]);
#pragma unroll
        for (int o = 1; o < 8; o <<= 1) mx = fmaxf(mx, __shfl_xor(mx, o, 64));
        float m = lrelu(mx + adn);
        float d = 0.f, ax = 0.f, ay = 0.f, az = 0.f, aw = 0.f;
        for (int e = e0; e < e1; ++e) {
            int s = esrc[e];
            float p = __expf(lrelu(as1[(size_t)s * 8 + head] + adn) - m);
            ushort4 hv = *reinterpret_cast<const ushort4*>(&h1[(size_t)s * 256 + cb]);
            d += p;
            ax += p * bf2f(hv.x);
            ay += p * bf2f(hv.y);
            az += p * bf2f(hv.z);
            aw += p * bf2f(hv.w);
        }
        float inv = 1.f / (d + 1e-16f);
        float4 bb = *reinterpret_cast<const float4*>(&b1[cb]);
        float4 o;
        o.x = fmaxf(ax * inv + bb.x, 0.f);
        o.y = fmaxf(ay * inv + bb.y, 0.f);
        o.z = fmaxf(az * inv + bb.z, 0.f);
        o.w = fmaxf(aw * inv + bb.w, 0.f);
        *reinterpret_cast<float4*>(&out1[(size_t)wid * 256 + cb]) = o;
    }
}

// layer-2 aggregation: quarter-wave per edge; exp once per edge.
__global__ __launch_bounds__(128) void k_agg2(const ushort_t* __restrict__ h2,
                                              const float* __restrict__ as2,
                                              const float* __restrict__ ad2,
                                              const int* __restrict__ offs,
                                              const int* __restrict__ esrc,
                                              const float* __restrict__ b2,
                                              float* __restrict__ out2, int n, int tot) {
    int wid = (blockIdx.x * 128 + threadIdx.x) >> 6;
    int lane = threadIdx.x & 63;
    if (wid >= n) return;
    float adn = ad2[wid];
    int e0 = offs[wid], e1 = offs[wid + 1];
    int deg = e1 - e0;

    if (deg <= 64) {
        const int l = lane & 15;
        const int q = lane >> 4;
        const int cb = l * 8;

        int ei_idx = e0 + lane;
        int es = esrc[ei_idx < tot ? ei_idx : (tot - 1)];
        float av0 = (lane < deg) ? as2[es] : -1e30f;
        float mx = av0;
#pragma unroll
        for (int o = 1; o < 64; o <<= 1) mx = fmaxf(mx, __shfl_xor(mx, o, 64));
        float m = lrelu(mx + adn);
        float p0 = __expf(lrelu(av0 + adn) - m);   // one exp per edge

        float d = 0.f;
        float ac0 = 0.f, ac1 = 0.f, ac2 = 0.f, ac3 = 0.f;
        float ac4 = 0.f, ac5 = 0.f, ac6 = 0.f, ac7 = 0.f;
#pragma unroll
        for (int u = 0; u < 4; ++u) {
            if (16 * u < deg) {
#pragma unroll
                for (int v = 0; v < 4; ++v) {
                    int i = 16 * u + 4 * v + q;
                    int s = __shfl(es, i, 64);
                    float p = __shfl(p0, i, 64);
                    if (i < deg) {
                        uint4 hv = *reinterpret_cast<const uint4*>(&h2[(size_t)s * 128 + cb]);
                        d += p;
                        ac0 += p * bits2f(hv.x << 16);
                        ac1 += p * bits2f(hv.x & 0xffff0000u);
                        ac2 += p * bits2f(hv.y << 16);
                        ac3 += p * bits2f(hv.y & 0xffff0000u);
                        ac4 += p * bits2f(hv.z << 16);
                        ac5 += p * bits2f(hv.z & 0xffff0000u);
                        ac6 += p * bits2f(hv.w << 16);
                        ac7 += p * bits2f(hv.w & 0xffff0000u);
                    }
                }
            }
        }
#pragma unroll
        for (int o = 16; o <= 32; o <<= 1) {
            d   += __shfl_xor(d, o, 64);
            ac0 += __shfl_xor(ac0, o, 64); ac1 += __shfl_xor(ac1, o, 64);
            ac2 += __shfl_xor(ac2, o, 64); ac3 += __shfl_xor(ac3, o, 64);
            ac4 += __shfl_xor(ac4, o, 64); ac5 += __shfl_xor(ac5, o, 64);
            ac6 += __shfl_xor(ac6, o, 64); ac7 += __shfl_xor(ac7, o, 64);
        }
        if (lane < 16) {
            float inv = 1.f / (d + 1e-16f);
            float4 b0 = *reinterpret_cast<const float4*>(&b2[cb]);
            float4 b4 = *reinterpret_cast<const float4*>(&b2[cb + 4]);
            float4 o0, o1;
            o0.x = fmaxf(ac0 * inv + b0.x, 0.f);
            o0.y = fmaxf(ac1 * inv + b0.y, 0.f);
            o0.z = fmaxf(ac2 * inv + b0.z, 0.f);
            o0.w = fmaxf(ac3 * inv + b0.w, 0.f);
            o1.x = fmaxf(ac4 * inv + b4.x, 0.f);
            o1.y = fmaxf(ac5 * inv + b4.y, 0.f);
            o1.z = fmaxf(ac6 * inv + b4.z, 0.f);
            o1.w = fmaxf(ac7 * inv + b4.w, 0.f);
            *reinterpret_cast<float4*>(&out2[(size_t)wid * 128 + cb]) = o0;
            *reinterpret_cast<float4*>(&out2[(size_t)wid * 128 + cb + 4]) = o1;
        }
    } else {
        int cb = lane * 2;
        float mx = -1e30f;
        for (int e = e0 + lane; e < e1; e += 64)
            mx = fmaxf(mx, as2[esrc[e]]);
#pragma unroll
        for (int o = 1; o < 64; o <<= 1) mx = fmaxf(mx, __shfl_xor(mx, o, 64));
        float m = lrelu(mx + adn);
        float d = 0.f, ax = 0.f, ay = 0.f;
        for (int e = e0; e < e1; ++e) {
            int s = esrc[e];
            float p = __expf(lrelu(as2[s] + adn) - m);
            ushort2 hv = *reinterpret_cast<const ushort2*>(&h2[(size_t)s * 128 + cb]);
            d += p;
            ax += p * bf2f(hv.x);
            ay += p * bf2f(hv.y);
        }
        float inv = 1.f / (d + 1e-16f);
        float o0 = fmaxf(ax * inv + b2[cb], 0.f);
        float o1 = fmaxf(ay * inv + b2[cb + 1], 0.f);
        float2 o = {o0, o1};
        *reinterpret_cast<float2*>(&out2[(size_t)wid * 128 + cb]) = o;
    }
}

// ---------------------------------------------------------------------------
__global__ __launch_bounds__(128) void k_bnstat(const float* __restrict__ out2,
                                                float* __restrict__ bnsum,
                                                float* __restrict__ bnsq, int n) {
    int c = threadIdx.x;
    float s = 0.f, q = 0.f;
    for (int r = blockIdx.x; r < n; r += gridDim.x) {
        float v = out2[(size_t)r * 128 + c];
        s += v;
        q += v * v;
    }
    atomicAdd(&bnsum[c], s);
    atomicAdd(&bnsq[c], q);
}

__global__ __launch_bounds__(256) void k_final(const float* __restrict__ out2,
                                               const float* __restrict__ bnsum,
                                               const float* __restrict__ bnsq,
                                               const float* __restrict__ bng,
                                               const float* __restrict__ bnb,
                                               const float* __restrict__ lng,
                                               const float* __restrict__ lnb,
                                               float* __restrict__ out, int n) {
    int wid = (blockIdx.x * blockDim.x + threadIdx.x) >> 6;
    int lane = threadIdx.x & 63;
    if (wid >= n) return;
    int c0 = lane, c1 = lane + 64;
    float invn = 1.f / (float)n;
    float mu0 = bnsum[c0] * invn, mu1 = bnsum[c1] * invn;
    float v0 = bnsq[c0] * invn - mu0 * mu0;
    float v1 = bnsq[c1] * invn - mu1 * mu1;
    float r0 = rsqrtf(v0 + EPSV), r1 = rsqrtf(v1 + EPSV);
    float x0 = out2[(size_t)wid * 128 + c0];
    float x1 = out2[(size_t)wid * 128 + c1];
    float y0 = (x0 - mu0) * r0 * bng[c0] + bnb[c0];
    float y1 = (x1 - mu1) * r1 * bng[c1] + bnb[c1];
    float s = y0 + y1, q = y0 * y0 + y1 * y1;
#pragma unroll
    for (int o = 1; o < 64; o <<= 1) { s += __shfl_xor(s, o, 64); q += __shfl_xor(q, o, 64); }
    float mu = s * (1.f / 128.f);
    float var = q * (1.f / 128.f) - mu * mu;
    float rr = rsqrtf(var + EPSV);
    out[(size_t)wid * 128 + c0] = (y0 - mu) * rr * lng[c0] + lnb[c0];
    out[(size_t)wid * 128 + c1] = (y1 - mu) * rr * lng[c1] + lnb[c1];
}

// ---------------------------------------------------------------------------
extern "C" void kernel_launch(void* const* d_in, const int* in_sizes, int n_in,
                              void* d_out, int out_size, void* d_ws, size_t ws_size,
                              hipStream_t stream) {
    const float* x    = (const float*)d_in[0];
    const int*   ei   = (const int*)d_in[1];
    const float* W1   = (const float*)d_in[2];
    const float* ats1 = (const float*)d_in[3];
    const float* atd1 = (const float*)d_in[4];
    const float* b1   = (const float*)d_in[5];
    const float* W2   = (const float*)d_in[6];
    const float* ats2 = (const float*)d_in[7];
    const float* atd2 = (const float*)d_in[8];
    const float* b2   = (const float*)d_in[9];
    const float* bng  = (const float*)d_in[10];
    const float* bnb  = (const float*)d_in[11];
    const float* lng  = (const float*)d_in[12];
    const float* lnb  = (const float*)d_in[13];

    const int n = in_sizes[0] / NFEAT;   // 50000
    const int E = in_sizes[1] / 2;       // 800000
    const int tot = E + n;

    auto align = [](size_t v) { return (v + 255) & ~(size_t)255; };
    char* ws = (char*)d_ws;
    size_t off = 0;
    ushort_t* h1 = (ushort_t*)(ws + off); off += align((size_t)n * 256 * 2);
    float* out1 = (float*)(ws + off); off += align((size_t)n * 256 * 4);
    ushort_t* h2 = h1;
    float* out2 = out1;
    float* as1 = (float*)(ws + off); off += align((size_t)n * 8 * 4);
    float* ad1 = (float*)(ws + off); off += align((size_t)n * 8 * 4);
    // zero-region: counts[n] | bnsum[128] | bnsq[128] | as2[n] | ad2[n]
    int* counts = (int*)(ws + off); off += align((size_t)n * 12 + 1024);
    float* bnsum = (float*)(counts + n);
    float* bnsq  = bnsum + 128;
    float* as2   = bnsq + 128;
    float* ad2   = as2 + n;
    int* offs   = (int*)(ws + off); off += align((size_t)(n + 1) * 4);
    int* cursor = (int*)(ws + off); off += align((size_t)n * 4);
    int* esrc   = (int*)(ws + off); off += align((size_t)tot * 4);
    int* incl   = (int*)(ws + off); off += align((size_t)n * 4);
    int* bsum   = (int*)(ws + off); off += align(64 * 4);
    ushort_t* Wh1 = (ushort_t*)(ws + off); off += align((size_t)256 * 256 * 2);
    ushort_t* Wl1 = (ushort_t*)(ws + off); off += align((size_t)256 * 256 * 2);
    ushort_t* Wh2 = (ushort_t*)(ws + off); off += align((size_t)256 * 128 * 2);
    ushort_t* Wl2 = (ushort_t*)(ws + off); off += align((size_t)256 * 128 * 2);

    hipMemsetAsync(counts, 0, (size_t)n * 12 + 1024, stream);

    // fused count + W-pack
    const int cblocks = (tot + 255) / 256;
    const int pblocks = (256 * 256 + 256 * 128 + 255) / 256;
    k_prep<<<cblocks + pblocks, 256, 0, stream>>>(ei, counts, E, n, cblocks,
                                                  W1, W2, Wh1, Wl1, Wh2, Wl2);
    int nsb = (n + 1023) / 1024;
    k_scan1<<<nsb, 1024, 0, stream>>>(counts, incl, bsum, n);
    k_scan3<<<(n + 255) / 256, 256, 0, stream>>>(incl, bsum, counts, offs, cursor, n);
    k_fill<<<(tot + 255) / 256, 256, 0, stream>>>(ei, cursor, esrc, E, n);

    const int gx = (n + 63) / 64;
    // layer 1 (att logits fused into GEMM epilogue)
    k_mm<256><<<dim3(gx, 2), 256, 0, stream>>>(x, Wh1, Wl1, h1, ats1, atd1, as1, ad1, n);
    k_agg1<<<(n + 1) / 2, 128, 0, stream>>>(h1, as1, ad1, offs, esrc, b1, out1, n, tot);

    // layer 2 (att logits fused, atomic partials into zeroed as2/ad2)
    k_mm<128><<<dim3(gx, 1), 256, 0, stream>>>(out1, Wh2, Wl2, h2, ats2, atd2, as2, ad2, n);
    k_agg2<<<(n + 1) / 2, 128, 0, stream>>>(h2, as2, ad2, offs, esrc, b2, out2, n, tot);

    // BN + LN
    k_bnstat<<<512, 128, 0, stream>>>(out2, bnsum, bnsq, n);
    k_final<<<(n + 3) / 4, 256, 0, stream>>>(out2, bnsum, bnsq, bng, bnb, lng, lnb,
                                             (float*)d_out, n);
}